// Round 6
// baseline (419.389 us; speedup 1.0000x reference)
//
#include <hip/hip_runtime.h>
#include <hip/hip_fp16.h>
#include <math.h>

// ---------------------------------------------------------------------------
// GAT 2-layer network. fp32 compute; gathered feature matrices stored fp16
// (gather is demand-byte-bound at the vector-load streaming ceiling).
// Bucketed (CAP-slot) edge lists; fill is XCD-aware: each block reads its
// physical XCC_ID and fills only the dst-partition owned by that XCD, so
// scattered bucket writes stay resident in the local 4MB L2.
// N=100000, E=1600000 (+N self-loops), d_in=h1=128, h2=64.
// ---------------------------------------------------------------------------

constexpr int CAP = 48;     // bucket slots per dst (max in-degree ~45 expected)
constexpr int NPART = 8;    // dst partitions == XCDs

__device__ __forceinline__ int xcc_id() {
  int x;
  asm volatile("s_getreg_b32 %0, hwreg(HW_REG_XCC_ID)" : "=s"(x));
  return x & (NPART - 1);
}

// ---------------- bucket fill (XCD-local, dynamic chunk claiming) ----------
__global__ __launch_bounds__(256) void k_fillb(
    const int* __restrict__ srcA, const int* __restrict__ dstA,
    int* __restrict__ cnt, int* __restrict__ seidx,
    int* __restrict__ ovf, int* __restrict__ ovf_cnt,
    int* __restrict__ pwork,
    int E, int N, unsigned pmul, int nchunk, int ovfcap) {
  __shared__ int s_chunk;
  const int p = xcc_id();
  const int tot = E + N;
  const int per = (tot + nchunk - 1) / nchunk;
  for (;;) {
    __syncthreads();
    if (threadIdx.x == 0) s_chunk = atomicAdd(&pwork[p], 1);
    __syncthreads();
    const int c = s_chunk;
    if (c >= nchunk) break;
    const int beg = c * per;
    const int end = min(tot, beg + per);
    for (int e = beg + (int)threadIdx.x; e < end; e += 256) {
      int d = (e < E) ? dstA[e] : (e - E);
      int pe = (int)(((unsigned long long)(unsigned)d * pmul) >> 32);
      pe = min(pe, NPART - 1);
      if (pe != p) continue;
      int s = (e < E) ? srcA[e] : (e - E);   // predicated: only 1/8 of edges
      int r = atomicAdd(&cnt[d], 1);
      if (r < CAP) {
        seidx[(size_t)d * CAP + r] = s;
      } else {
        int o = atomicAdd(ovf_cnt, 1);
        if (o < ovfcap) { ovf[2 * o] = d; ovf[2 * o + 1] = s; }
      }
    }
  }
}

// ---------------- GEMM: XL(fp16) = X @ W, plus a_src/a_dst epilogue ----------
template <int C>
__device__ __forceinline__ void gemm_body(
    const float* __restrict__ X, const float* __restrict__ W,
    const float* __restrict__ atts, const float* __restrict__ attd,
    __half* __restrict__ XLh, float* __restrict__ a_s, float* __restrict__ a_d, int N) {
  constexpr int GK = 128;
  constexpr int ROWS = 64;
  constexpr int KH = (C == 128) ? 64 : 128;     // k-half size
  constexpr int NCG = C / 4;                    // col groups: 32 or 16
  constexpr int RPT = ROWS / (256 / NCG);       // rows/thread: 8 or 4
  __shared__ float sW[KH * C];                  // 32KB
  __shared__ float sXT[GK][ROWS];               // 32KB, transposed X tile
  const int t = threadIdx.x;
  const int cg = t % NCG;
  const int rg = t / NCG;
  float av[4], dv[4];
#pragma unroll
  for (int j = 0; j < 4; ++j) { av[j] = atts[cg * 4 + j]; dv[j] = attd[cg * 4 + j]; }

  for (int r0 = blockIdx.x * ROWS; r0 < N; r0 += gridDim.x * ROWS) {
    __syncthreads();
    {  // stage X^T: lane = row, 4 waves cover k
      const int rl = t & 63;
      const int k0 = (t >> 6) * 32;
      const int r = r0 + rl;
      if (r < N) {
        const float* xr = X + (size_t)r * GK + k0;
#pragma unroll
        for (int j = 0; j < 32; j += 4) {
          float4 v = *(const float4*)(xr + j);
          sXT[k0 + j + 0][rl] = v.x; sXT[k0 + j + 1][rl] = v.y;
          sXT[k0 + j + 2][rl] = v.z; sXT[k0 + j + 3][rl] = v.w;
        }
      } else {
#pragma unroll
        for (int j = 0; j < 32; ++j) sXT[k0 + j][rl] = 0.f;
      }
    }
    float acc[RPT][4];
#pragma unroll
    for (int i = 0; i < RPT; ++i)
#pragma unroll
      for (int j = 0; j < 4; ++j) acc[i][j] = 0.f;

#pragma unroll
    for (int kh = 0; kh < GK / KH; ++kh) {
      __syncthreads();
      for (int i = t * 4; i < KH * C; i += 1024)
        *(float4*)&sW[i] = *(const float4*)&W[(size_t)kh * KH * C + i];
      __syncthreads();
#pragma unroll 4
      for (int k = 0; k < KH; ++k) {
        float4 wv = *(const float4*)&sW[k * C + cg * 4];
        float xr[RPT];
#pragma unroll
        for (int i = 0; i < RPT; i += 4)
          *(float4*)&xr[i] = *(const float4*)&sXT[kh * KH + k][rg * RPT + i];
#pragma unroll
        for (int i = 0; i < RPT; ++i) {
          acc[i][0] = fmaf(xr[i], wv.x, acc[i][0]);
          acc[i][1] = fmaf(xr[i], wv.y, acc[i][1]);
          acc[i][2] = fmaf(xr[i], wv.z, acc[i][2]);
          acc[i][3] = fmaf(xr[i], wv.w, acc[i][3]);
        }
      }
    }
#pragma unroll
    for (int i = 0; i < RPT; ++i) {
      const int r = r0 + rg * RPT + i;
      float ps = acc[i][0] * av[0] + acc[i][1] * av[1] + acc[i][2] * av[2] + acc[i][3] * av[3];
      float pd = acc[i][0] * dv[0] + acc[i][1] * dv[1] + acc[i][2] * dv[2] + acc[i][3] * dv[3];
#pragma unroll
      for (int m = 1; m < NCG; m <<= 1) { ps += __shfl_xor(ps, m); pd += __shfl_xor(pd, m); }
      if (r < N) {
        __half2 p0 = __floats2half2_rn(acc[i][0], acc[i][1]);
        __half2 p1 = __floats2half2_rn(acc[i][2], acc[i][3]);
        uint2 u;
        u.x = *(unsigned*)&p0;
        u.y = *(unsigned*)&p1;
        *(uint2*)&XLh[(size_t)r * C + cg * 4] = u;
        if (cg == 0) { a_s[r] = ps; a_d[r] = pd; }
      }
    }
  }
}

__global__ __launch_bounds__(256) void k_gemm_l1(
    const float* __restrict__ X, const float* __restrict__ W,
    const float* __restrict__ atts, const float* __restrict__ attd,
    __half* __restrict__ XLh, float* __restrict__ a_s, float* __restrict__ a_d, int N) {
  gemm_body<128>(X, W, atts, attd, XLh, a_s, a_d, N);
}
__global__ __launch_bounds__(256) void k_gemm_l2(
    const float* __restrict__ X, const float* __restrict__ W,
    const float* __restrict__ atts, const float* __restrict__ attd,
    __half* __restrict__ XLh, float* __restrict__ a_s, float* __restrict__ a_d, int N) {
  gemm_body<64>(X, W, atts, attd, XLh, a_s, a_d, N);
}

// ---------------- per-dst attention + aggregation (one wave per dst) ----------
template <int C, bool RELU>
__device__ __forceinline__ void aggr_body(
    const __half* __restrict__ XLh, const float* __restrict__ as_,
    const float* __restrict__ ad_, const int* __restrict__ cnt,
    const int* __restrict__ seidx, const int* __restrict__ ovf,
    const int* __restrict__ ovf_cnt, const float* __restrict__ bias,
    float* __restrict__ OUT, int N) {
  constexpr int PL = C / 64;  // cols per lane: 2 (C=128) or 1 (C=64)
  const int lane = threadIdx.x & 63;
  const int wid = threadIdx.x >> 6;
  const int novf = *ovf_cnt;  // 0 in practice
  float bb[PL];
#pragma unroll
  for (int j = 0; j < PL; ++j) bb[j] = bias[lane * PL + j];

  for (int d = blockIdx.x * 4 + wid; d < N; d += gridDim.x * 4) {
    const int cd = cnt[d];
    const int nb = min(cd, CAP);
    const float adst = ad_[d];

    // load my edge (lane i <-> bucket slot i), compute logit
    int sv = 0;
    float vv = -1e30f;
    if (lane < nb) {
      sv = seidx[(size_t)d * CAP + lane];
      float t = as_[sv] + adst;
      vv = t > 0.f ? t : 0.2f * t;
    }
    // wave online (max,sum) butterfly
    float m = vv, s = (lane < nb) ? 1.f : 0.f;
#pragma unroll
    for (int o = 32; o; o >>= 1) {
      float m2 = __shfl_xor(m, o), s2 = __shfl_xor(s, o);
      float M = fmaxf(m, m2);
      s = s * __expf(m - M) + s2 * __expf(m2 - M);
      m = M;
    }
    if (cd > CAP) {  // cold: merge overflow entries into (m,s)
      float mo = -1e30f, so = 0.f;
      for (int i = lane; i < novf; i += 64) {
        if (ovf[2 * i] == d) {
          float t = as_[ovf[2 * i + 1]] + adst;
          t = t > 0.f ? t : 0.2f * t;
          float M = fmaxf(mo, t);
          so = so * __expf(mo - M) + __expf(t - M);
          mo = M;
        }
      }
#pragma unroll
      for (int o = 32; o; o >>= 1) {
        float m2 = __shfl_xor(mo, o), s2 = __shfl_xor(so, o);
        float M = fmaxf(mo, m2);
        so = so * __expf(mo - M) + s2 * __expf(m2 - M);
        mo = M;
      }
      float M = fmaxf(m, mo);
      s = s * __expf(m - M) + so * __expf(mo - M);
      m = M;
    }
    const float inv = 1.f / (s + 1e-16f);
    const float wv = (lane < nb) ? __expf(vv - m) * inv : 0.f;

    // burst-broadcast weighted gather (fp16 rows)
    float acc[PL];
#pragma unroll
    for (int j = 0; j < PL; ++j) acc[j] = 0.f;
    auto body = [&](int j) {
      int sj = __shfl(sv, j);
      float wj = __shfl(wv, j);
      if (PL == 2) {
        __half2 hv = *(const __half2*)(XLh + (size_t)sj * C + lane * 2);
        float2 xv = __half22float2(hv);
        acc[0] = fmaf(wj, xv.x, acc[0]);
        acc[1] = fmaf(wj, xv.y, acc[1]);
      } else {
        acc[0] = fmaf(wj, __half2float(XLh[(size_t)sj * C + lane]), acc[0]);
      }
    };
    int j = 0;
    for (; j + 4 <= nb; j += 4) { body(j); body(j + 1); body(j + 2); body(j + 3); }
    for (; j < nb; ++j) body(j);

    if (cd > CAP) {  // cold: serial overflow gather (wave-uniform)
      for (int i = 0; i < novf; ++i) {
        int od = ovf[2 * i];
        if (od != d) continue;
        int os = ovf[2 * i + 1];
        float t = as_[os] + adst;
        t = t > 0.f ? t : 0.2f * t;
        float wj = __expf(t - m) * inv;
        if (PL == 2) {
          __half2 hv = *(const __half2*)(XLh + (size_t)os * C + lane * 2);
          float2 xv = __half22float2(hv);
          acc[0] = fmaf(wj, xv.x, acc[0]);
          acc[1] = fmaf(wj, xv.y, acc[1]);
        } else {
          acc[0] = fmaf(wj, __half2float(XLh[(size_t)os * C + lane]), acc[0]);
        }
      }
    }

    float o0 = acc[0] + bb[0];
    if (RELU) o0 = o0 > 0.f ? o0 : 0.01f * o0;
    if (PL == 2) {
      float o1 = acc[1] + bb[1];
      if (RELU) o1 = o1 > 0.f ? o1 : 0.01f * o1;
      *(float2*)&OUT[(size_t)d * C + lane * 2] = make_float2(o0, o1);
    } else {
      OUT[(size_t)d * C + lane] = o0;
    }
  }
}

__global__ __launch_bounds__(256) void k_aggr_l1(
    const __half* __restrict__ XLh, const float* __restrict__ as_,
    const float* __restrict__ ad_, const int* __restrict__ cnt,
    const int* __restrict__ seidx, const int* __restrict__ ovf,
    const int* __restrict__ ovf_cnt, const float* __restrict__ bias,
    float* __restrict__ OUT, int N) {
  aggr_body<128, true>(XLh, as_, ad_, cnt, seidx, ovf, ovf_cnt, bias, OUT, N);
}
__global__ __launch_bounds__(256) void k_aggr_l2(
    const __half* __restrict__ XLh, const float* __restrict__ as_,
    const float* __restrict__ ad_, const int* __restrict__ cnt,
    const int* __restrict__ seidx, const int* __restrict__ ovf,
    const int* __restrict__ ovf_cnt, const float* __restrict__ bias,
    float* __restrict__ OUT, int N) {
  aggr_body<64, false>(XLh, as_, ad_, cnt, seidx, ovf, ovf_cnt, bias, OUT, N);
}

// ---------------- column softmax (axis=0) over OUT [N][64] ----------------
// Pre-softmax values are O(1) -> exp without max-subtraction is safe.
__global__ void k_colsum(const float* __restrict__ O, float* __restrict__ csum, int N) {
  __shared__ float sm[4][64];
  int c = threadIdx.x & 63;
  int wv = threadIdx.x >> 6;
  float s = 0.f;
  for (int r = blockIdx.x * 4 + wv; r < N; r += gridDim.x * 4)
    s += __expf(O[(size_t)r * 64 + c]);
  sm[wv][c] = s;
  __syncthreads();
  if (threadIdx.x < 64) {
    float s2 = sm[0][c] + sm[1][c] + sm[2][c] + sm[3][c];
    atomicAdd(&csum[c], s2);
  }
}

__global__ void k_norm(float* __restrict__ O, const float* __restrict__ csum, size_t tot4) {
  for (size_t i = blockIdx.x * (size_t)blockDim.x + threadIdx.x; i < tot4;
       i += (size_t)gridDim.x * blockDim.x) {
    float4 v = ((float4*)O)[i];
    int c0 = (int)((i * 4) & 63);
    float s0 = csum[c0],     s1 = csum[c0 + 1];
    float s2 = csum[c0 + 2], s3 = csum[c0 + 3];
    v.x = __expf(v.x) / s0;
    v.y = __expf(v.y) / s1;
    v.z = __expf(v.z) / s2;
    v.w = __expf(v.w) / s3;
    ((float4*)O)[i] = v;
  }
}

// ---------------------------------------------------------------------------
extern "C" void kernel_launch(void* const* d_in, const int* in_sizes, int n_in,
                              void* d_out, int out_size, void* d_ws, size_t ws_size,
                              hipStream_t stream) {
  const float* x   = (const float*)d_in[0];
  const int*   ei  = (const int*)d_in[1];
  const float* W1  = (const float*)d_in[2];
  const float* as1 = (const float*)d_in[3];
  const float* ad1 = (const float*)d_in[4];
  const float* b1  = (const float*)d_in[5];
  const float* W2  = (const float*)d_in[6];
  const float* as2 = (const float*)d_in[7];
  const float* ad2 = (const float*)d_in[8];
  const float* b2  = (const float*)d_in[9];
  float* out = (float*)d_out;

  const int N = in_sizes[0] / 128;
  const int E = in_sizes[1] / 2;
  const int Etot = E + N;
  const int* srcA = ei;
  const int* dstA = ei + E;

  char* w = (char*)d_ws;
  auto take = [&](size_t bytes) -> void* {
    void* p = (void*)w;
    w += (bytes + 255) & ~(size_t)255;
    return p;
  };
  __half* xlh   = (__half*)take((size_t)N * 128 * 2);  // layer-1 XL (fp16)
  __half* xl2h  = (__half*)take((size_t)N * 64 * 2);   // layer-2 XL (fp16)
  float*  h     = (float*)take((size_t)N * 128 * 4);   // layer-1 output (fp32)
  float*  a_s   = (float*)take((size_t)N * 4);
  float*  a_d   = (float*)take((size_t)N * 4);
  int*    zeroB = (int*)take((size_t)(N + 1 + 64 + 8) * 4); // cnt|ovf_cnt|csum|pwork
  int*    cnt     = zeroB;
  int*    ovf_cnt = zeroB + N;
  float*  csum    = (float*)(zeroB + N + 1);
  int*    pwork   = zeroB + N + 1 + 64;
  int*    seidx = (int*)take((size_t)N * CAP * 4);
  int*    ovf   = (int*)take((size_t)Etot * 2 * 4);

  hipMemsetAsync(zeroB, 0, (size_t)(N + 1 + 64 + 8) * 4, stream);

  const unsigned pmul = (unsigned)(((unsigned long long)NPART << 32) / (unsigned)N);
  const int nchunk = 1024;
  k_fillb<<<2048, 256, 0, stream>>>(srcA, dstA, cnt, seidx, ovf, ovf_cnt, pwork,
                                    E, N, pmul, nchunk, Etot);

  const int gb = (N + 63) / 64;
  k_gemm_l1<<<gb, 256, 0, stream>>>(x, W1, as1, ad1, xlh, a_s, a_d, N);
  k_aggr_l1<<<8192, 256, 0, stream>>>(xlh, a_s, a_d, cnt, seidx, ovf, ovf_cnt, b1, h, N);
  k_gemm_l2<<<gb, 256, 0, stream>>>(h, W2, as2, ad2, xl2h, a_s, a_d, N);
  k_aggr_l2<<<8192, 256, 0, stream>>>(xl2h, a_s, a_d, cnt, seidx, ovf, ovf_cnt, b2, out, N);

  k_colsum<<<1024, 256, 0, stream>>>(out, csum, N);
  const size_t tot4 = (size_t)N * 64 / 4;
  k_norm<<<2048, 256, 0, stream>>>(out, csum, tot4);
}

// Round 7
// 370.865 us; speedup vs baseline: 1.1308x; 1.1308x over previous
//
#include <hip/hip_runtime.h>
#include <hip/hip_fp16.h>
#include <math.h>

// ---------------------------------------------------------------------------
// GAT 2-layer network. fp32 compute; gathered feature matrices stored fp16
// (gather is demand-byte-bound at the vector-load streaming ceiling).
// Edge->bucket build is a two-phase binned fill: phase A bins edges into 64
// dst-range partitions with LDS histograms + tail appends (line-dense writes,
// no partial-line HBM RMW); phase B scatters each partition into its 393KB
// bucket window (L2-resident, dense buckets).
// N=100000, E=1600000 (+N self-loops), d_in=h1=128, h2=64.
// ---------------------------------------------------------------------------

constexpr int CAP = 48;       // bucket slots per dst (max in-degree ~45 expected)
constexpr int PFILL = 64;     // fill partitions (dst ranges)
constexpr int PCAP = 33000;   // entries per partition (avg 26.6K, +39 sigma)
constexpr int CHUNK = 2048;   // edges per phase-A block-chunk
constexpr int SUBB = 4;       // blocks per partition in phase B

// ---------------- phase A: bin edges into 64 dst-range partitions ----------
__global__ __launch_bounds__(256) void k_part(
    const int* __restrict__ srcA, const int* __restrict__ dstA,
    int* __restrict__ pcur, uint2* __restrict__ parts,
    int* __restrict__ ovf, int* __restrict__ ovf_cnt,
    int E, int N, unsigned pmul, int nch, int ovfcap) {
  __shared__ int hist[PFILL];
  __shared__ int base[PFILL];
  const int tot = E + N;
  for (int c = blockIdx.x; c < nch; c += gridDim.x) {
    if (threadIdx.x < PFILL) hist[threadIdx.x] = 0;
    __syncthreads();
    const int beg = c * CHUNK;
    int pp[8], rr[8], ss[8], dd[8];
#pragma unroll
    for (int j = 0; j < 8; ++j) {
      int e = beg + j * 256 + (int)threadIdx.x;
      int d = -1, s = 0;
      if (e < tot) {
        if (e < E) { d = dstA[e]; s = srcA[e]; } else { d = s = e - E; }
      }
      dd[j] = d; ss[j] = s;
      int p = -1;
      if (d >= 0) {
        p = (int)(((unsigned long long)(unsigned)d * pmul) >> 32);
        if (p >= PFILL) p = PFILL - 1;
      }
      pp[j] = p;
      rr[j] = (p >= 0) ? atomicAdd(&hist[p], 1) : 0;
    }
    __syncthreads();
    if (threadIdx.x < PFILL)
      base[threadIdx.x] = atomicAdd(&pcur[threadIdx.x], hist[threadIdx.x]);
    __syncthreads();
#pragma unroll
    for (int j = 0; j < 8; ++j) {
      int p = pp[j];
      if (p < 0) continue;
      int pos = base[p] + rr[j];
      if (pos < PCAP) {
        parts[(size_t)p * PCAP + pos] = make_uint2((unsigned)ss[j], (unsigned)dd[j]);
      } else {  // partition overflow (essentially impossible): ovf fallback
        int o = atomicAdd(ovf_cnt, 1);
        if (o < ovfcap) { ovf[2 * o] = dd[j]; ovf[2 * o + 1] = ss[j]; }
      }
    }
    __syncthreads();  // hist/base reused next chunk
  }
}

// ---------------- phase B: scatter partition entries into buckets ----------
__global__ __launch_bounds__(256) void k_place(
    const uint2* __restrict__ parts, const int* __restrict__ pcur,
    int* __restrict__ cnt, int* __restrict__ seidx,
    int* __restrict__ ovf, int* __restrict__ ovf_cnt, int ovfcap) {
  const int p = blockIdx.x / SUBB;
  const int sub = blockIdx.x % SUBB;
  const int n = min(pcur[p], PCAP);
  const uint2* pe = parts + (size_t)p * PCAP;
  for (int i = sub * 256 + (int)threadIdx.x; i < n; i += SUBB * 256) {
    uint2 e = pe[i];
    int d = (int)e.y, s = (int)e.x;
    int r = atomicAdd(&cnt[d], 1);
    if (r < CAP) {
      seidx[(size_t)d * CAP + r] = s;
    } else {
      int o = atomicAdd(ovf_cnt, 1);
      if (o < ovfcap) { ovf[2 * o] = d; ovf[2 * o + 1] = s; }
    }
  }
}

// ---------------- GEMM: XL(fp16) = X @ W, plus a_src/a_dst epilogue ----------
template <int C>
__device__ __forceinline__ void gemm_body(
    const float* __restrict__ X, const float* __restrict__ W,
    const float* __restrict__ atts, const float* __restrict__ attd,
    __half* __restrict__ XLh, float* __restrict__ a_s, float* __restrict__ a_d, int N) {
  constexpr int GK = 128;
  constexpr int ROWS = 64;
  constexpr int KH = (C == 128) ? 64 : 128;     // k-half size
  constexpr int NCG = C / 4;                    // col groups: 32 or 16
  constexpr int RPT = ROWS / (256 / NCG);       // rows/thread: 8 or 4
  __shared__ float sW[KH * C];                  // 32KB
  __shared__ float sXT[GK][ROWS];               // 32KB, transposed X tile
  const int t = threadIdx.x;
  const int cg = t % NCG;
  const int rg = t / NCG;
  float av[4], dv[4];
#pragma unroll
  for (int j = 0; j < 4; ++j) { av[j] = atts[cg * 4 + j]; dv[j] = attd[cg * 4 + j]; }

  for (int r0 = blockIdx.x * ROWS; r0 < N; r0 += gridDim.x * ROWS) {
    __syncthreads();
    {  // stage X^T: lane = row, 4 waves cover k
      const int rl = t & 63;
      const int k0 = (t >> 6) * 32;
      const int r = r0 + rl;
      if (r < N) {
        const float* xr = X + (size_t)r * GK + k0;
#pragma unroll
        for (int j = 0; j < 32; j += 4) {
          float4 v = *(const float4*)(xr + j);
          sXT[k0 + j + 0][rl] = v.x; sXT[k0 + j + 1][rl] = v.y;
          sXT[k0 + j + 2][rl] = v.z; sXT[k0 + j + 3][rl] = v.w;
        }
      } else {
#pragma unroll
        for (int j = 0; j < 32; ++j) sXT[k0 + j][rl] = 0.f;
      }
    }
    float acc[RPT][4];
#pragma unroll
    for (int i = 0; i < RPT; ++i)
#pragma unroll
      for (int j = 0; j < 4; ++j) acc[i][j] = 0.f;

#pragma unroll
    for (int kh = 0; kh < GK / KH; ++kh) {
      __syncthreads();
      for (int i = t * 4; i < KH * C; i += 1024)
        *(float4*)&sW[i] = *(const float4*)&W[(size_t)kh * KH * C + i];
      __syncthreads();
#pragma unroll 4
      for (int k = 0; k < KH; ++k) {
        float4 wv = *(const float4*)&sW[k * C + cg * 4];
        float xr[RPT];
#pragma unroll
        for (int i = 0; i < RPT; i += 4)
          *(float4*)&xr[i] = *(const float4*)&sXT[kh * KH + k][rg * RPT + i];
#pragma unroll
        for (int i = 0; i < RPT; ++i) {
          acc[i][0] = fmaf(xr[i], wv.x, acc[i][0]);
          acc[i][1] = fmaf(xr[i], wv.y, acc[i][1]);
          acc[i][2] = fmaf(xr[i], wv.z, acc[i][2]);
          acc[i][3] = fmaf(xr[i], wv.w, acc[i][3]);
        }
      }
    }
#pragma unroll
    for (int i = 0; i < RPT; ++i) {
      const int r = r0 + rg * RPT + i;
      float ps = acc[i][0] * av[0] + acc[i][1] * av[1] + acc[i][2] * av[2] + acc[i][3] * av[3];
      float pd = acc[i][0] * dv[0] + acc[i][1] * dv[1] + acc[i][2] * dv[2] + acc[i][3] * dv[3];
#pragma unroll
      for (int m = 1; m < NCG; m <<= 1) { ps += __shfl_xor(ps, m); pd += __shfl_xor(pd, m); }
      if (r < N) {
        __half2 p0 = __floats2half2_rn(acc[i][0], acc[i][1]);
        __half2 p1 = __floats2half2_rn(acc[i][2], acc[i][3]);
        uint2 u;
        u.x = *(unsigned*)&p0;
        u.y = *(unsigned*)&p1;
        *(uint2*)&XLh[(size_t)r * C + cg * 4] = u;
        if (cg == 0) { a_s[r] = ps; a_d[r] = pd; }
      }
    }
  }
}

__global__ __launch_bounds__(256) void k_gemm_l1(
    const float* __restrict__ X, const float* __restrict__ W,
    const float* __restrict__ atts, const float* __restrict__ attd,
    __half* __restrict__ XLh, float* __restrict__ a_s, float* __restrict__ a_d, int N) {
  gemm_body<128>(X, W, atts, attd, XLh, a_s, a_d, N);
}
__global__ __launch_bounds__(256) void k_gemm_l2(
    const float* __restrict__ X, const float* __restrict__ W,
    const float* __restrict__ atts, const float* __restrict__ attd,
    __half* __restrict__ XLh, float* __restrict__ a_s, float* __restrict__ a_d, int N) {
  gemm_body<64>(X, W, atts, attd, XLh, a_s, a_d, N);
}

// ---------------- per-dst attention + aggregation (one wave per dst) ----------
template <int C, bool RELU>
__device__ __forceinline__ void aggr_body(
    const __half* __restrict__ XLh, const float* __restrict__ as_,
    const float* __restrict__ ad_, const int* __restrict__ cnt,
    const int* __restrict__ seidx, const int* __restrict__ ovf,
    const int* __restrict__ ovf_cnt, const float* __restrict__ bias,
    float* __restrict__ OUT, int N) {
  constexpr int PL = C / 64;  // cols per lane: 2 (C=128) or 1 (C=64)
  const int lane = threadIdx.x & 63;
  const int wid = threadIdx.x >> 6;
  const int novf = *ovf_cnt;  // 0 in practice
  float bb[PL];
#pragma unroll
  for (int j = 0; j < PL; ++j) bb[j] = bias[lane * PL + j];

  for (int d = blockIdx.x * 4 + wid; d < N; d += gridDim.x * 4) {
    const int cd = cnt[d];
    const int nb = min(cd, CAP);
    const float adst = ad_[d];
    const bool cold = (cd > CAP) || (novf > 0);

    // load my edge (lane i <-> bucket slot i), compute logit
    int sv = 0;
    float vv = -1e30f;
    if (lane < nb) {
      sv = seidx[(size_t)d * CAP + lane];
      float t = as_[sv] + adst;
      vv = t > 0.f ? t : 0.2f * t;
    }
    // wave online (max,sum) butterfly
    float m = vv, s = (lane < nb) ? 1.f : 0.f;
#pragma unroll
    for (int o = 32; o; o >>= 1) {
      float m2 = __shfl_xor(m, o), s2 = __shfl_xor(s, o);
      float M = fmaxf(m, m2);
      s = s * __expf(m - M) + s2 * __expf(m2 - M);
      m = M;
    }
    if (cold) {  // cold: merge overflow entries into (m,s)
      float mo = -1e30f, so = 0.f;
      for (int i = lane; i < novf; i += 64) {
        if (ovf[2 * i] == d) {
          float t = as_[ovf[2 * i + 1]] + adst;
          t = t > 0.f ? t : 0.2f * t;
          float M = fmaxf(mo, t);
          so = so * __expf(mo - M) + __expf(t - M);
          mo = M;
        }
      }
#pragma unroll
      for (int o = 32; o; o >>= 1) {
        float m2 = __shfl_xor(mo, o), s2 = __shfl_xor(so, o);
        float M = fmaxf(mo, m2);
        so = so * __expf(mo - M) + s2 * __expf(m2 - M);
        mo = M;
      }
      float M = fmaxf(m, mo);
      s = s * __expf(m - M) + so * __expf(mo - M);
      m = M;
    }
    const float inv = 1.f / (s + 1e-16f);
    const float wv = (lane < nb) ? __expf(vv - m) * inv : 0.f;

    // burst-broadcast weighted gather (fp16 rows)
    float acc[PL];
#pragma unroll
    for (int j = 0; j < PL; ++j) acc[j] = 0.f;
    auto body = [&](int j) {
      int sj = __shfl(sv, j);
      float wj = __shfl(wv, j);
      if (PL == 2) {
        __half2 hv = *(const __half2*)(XLh + (size_t)sj * C + lane * 2);
        float2 xv = __half22float2(hv);
        acc[0] = fmaf(wj, xv.x, acc[0]);
        acc[1] = fmaf(wj, xv.y, acc[1]);
      } else {
        acc[0] = fmaf(wj, __half2float(XLh[(size_t)sj * C + lane]), acc[0]);
      }
    };
    int j = 0;
    for (; j + 4 <= nb; j += 4) { body(j); body(j + 1); body(j + 2); body(j + 3); }
    for (; j < nb; ++j) body(j);

    if (cold) {  // cold: serial overflow gather (wave-uniform)
      for (int i = 0; i < novf; ++i) {
        int od = ovf[2 * i];
        if (od != d) continue;
        int os = ovf[2 * i + 1];
        float t = as_[os] + adst;
        t = t > 0.f ? t : 0.2f * t;
        float wj = __expf(t - m) * inv;
        if (PL == 2) {
          __half2 hv = *(const __half2*)(XLh + (size_t)os * C + lane * 2);
          float2 xv = __half22float2(hv);
          acc[0] = fmaf(wj, xv.x, acc[0]);
          acc[1] = fmaf(wj, xv.y, acc[1]);
        } else {
          acc[0] = fmaf(wj, __half2float(XLh[(size_t)os * C + lane]), acc[0]);
        }
      }
    }

    float o0 = acc[0] + bb[0];
    if (RELU) o0 = o0 > 0.f ? o0 : 0.01f * o0;
    if (PL == 2) {
      float o1 = acc[1] + bb[1];
      if (RELU) o1 = o1 > 0.f ? o1 : 0.01f * o1;
      *(float2*)&OUT[(size_t)d * C + lane * 2] = make_float2(o0, o1);
    } else {
      OUT[(size_t)d * C + lane] = o0;
    }
  }
}

__global__ __launch_bounds__(256) void k_aggr_l1(
    const __half* __restrict__ XLh, const float* __restrict__ as_,
    const float* __restrict__ ad_, const int* __restrict__ cnt,
    const int* __restrict__ seidx, const int* __restrict__ ovf,
    const int* __restrict__ ovf_cnt, const float* __restrict__ bias,
    float* __restrict__ OUT, int N) {
  aggr_body<128, true>(XLh, as_, ad_, cnt, seidx, ovf, ovf_cnt, bias, OUT, N);
}
__global__ __launch_bounds__(256) void k_aggr_l2(
    const __half* __restrict__ XLh, const float* __restrict__ as_,
    const float* __restrict__ ad_, const int* __restrict__ cnt,
    const int* __restrict__ seidx, const int* __restrict__ ovf,
    const int* __restrict__ ovf_cnt, const float* __restrict__ bias,
    float* __restrict__ OUT, int N) {
  aggr_body<64, false>(XLh, as_, ad_, cnt, seidx, ovf, ovf_cnt, bias, OUT, N);
}

// ---------------- column softmax (axis=0) over OUT [N][64] ----------------
// Pre-softmax values are O(1) -> exp without max-subtraction is safe.
__global__ void k_colsum(const float* __restrict__ O, float* __restrict__ csum, int N) {
  __shared__ float sm[4][64];
  int c = threadIdx.x & 63;
  int wv = threadIdx.x >> 6;
  float s = 0.f;
  for (int r = blockIdx.x * 4 + wv; r < N; r += gridDim.x * 4)
    s += __expf(O[(size_t)r * 64 + c]);
  sm[wv][c] = s;
  __syncthreads();
  if (threadIdx.x < 64) {
    float s2 = sm[0][c] + sm[1][c] + sm[2][c] + sm[3][c];
    atomicAdd(&csum[c], s2);
  }
}

__global__ void k_norm(float* __restrict__ O, const float* __restrict__ csum, size_t tot4) {
  for (size_t i = blockIdx.x * (size_t)blockDim.x + threadIdx.x; i < tot4;
       i += (size_t)gridDim.x * blockDim.x) {
    float4 v = ((float4*)O)[i];
    int c0 = (int)((i * 4) & 63);
    float s0 = csum[c0],     s1 = csum[c0 + 1];
    float s2 = csum[c0 + 2], s3 = csum[c0 + 3];
    v.x = __expf(v.x) / s0;
    v.y = __expf(v.y) / s1;
    v.z = __expf(v.z) / s2;
    v.w = __expf(v.w) / s3;
    ((float4*)O)[i] = v;
  }
}

// ---------------------------------------------------------------------------
extern "C" void kernel_launch(void* const* d_in, const int* in_sizes, int n_in,
                              void* d_out, int out_size, void* d_ws, size_t ws_size,
                              hipStream_t stream) {
  const float* x   = (const float*)d_in[0];
  const int*   ei  = (const int*)d_in[1];
  const float* W1  = (const float*)d_in[2];
  const float* as1 = (const float*)d_in[3];
  const float* ad1 = (const float*)d_in[4];
  const float* b1  = (const float*)d_in[5];
  const float* W2  = (const float*)d_in[6];
  const float* as2 = (const float*)d_in[7];
  const float* ad2 = (const float*)d_in[8];
  const float* b2  = (const float*)d_in[9];
  float* out = (float*)d_out;

  const int N = in_sizes[0] / 128;
  const int E = in_sizes[1] / 2;
  const int Etot = E + N;
  const int* srcA = ei;
  const int* dstA = ei + E;

  char* w = (char*)d_ws;
  auto take = [&](size_t bytes) -> void* {
    void* p = (void*)w;
    w += (bytes + 255) & ~(size_t)255;
    return p;
  };
  __half* xlh   = (__half*)take((size_t)N * 128 * 2);  // layer-1 XL (fp16)
  __half* xl2h  = (__half*)take((size_t)N * 64 * 2);   // layer-2 XL (fp16)
  float*  h     = (float*)take((size_t)N * 128 * 4);   // layer-1 output (fp32)
  float*  a_s   = (float*)take((size_t)N * 4);
  float*  a_d   = (float*)take((size_t)N * 4);
  int*    zeroB = (int*)take((size_t)(N + 1 + 64 + PFILL) * 4); // cnt|ovf_cnt|csum|pcur
  int*    cnt     = zeroB;
  int*    ovf_cnt = zeroB + N;
  float*  csum    = (float*)(zeroB + N + 1);
  int*    pcur    = zeroB + N + 1 + 64;
  int*    seidx = (int*)take((size_t)N * CAP * 4);
  int*    ovf   = (int*)take((size_t)Etot * 2 * 4);
  uint2*  parts = (uint2*)take((size_t)PFILL * PCAP * 8);

  hipMemsetAsync(zeroB, 0, (size_t)(N + 1 + 64 + PFILL) * 4, stream);

  const unsigned pmul = (unsigned)(((unsigned long long)PFILL << 32) / (unsigned)N);
  const int nch = (Etot + CHUNK - 1) / CHUNK;
  k_part<<<nch, 256, 0, stream>>>(srcA, dstA, pcur, parts, ovf, ovf_cnt,
                                  E, N, pmul, nch, Etot);
  k_place<<<PFILL * SUBB, 256, 0, stream>>>(parts, pcur, cnt, seidx, ovf, ovf_cnt, Etot);

  const int gb = (N + 63) / 64;
  k_gemm_l1<<<gb, 256, 0, stream>>>(x, W1, as1, ad1, xlh, a_s, a_d, N);
  k_aggr_l1<<<8192, 256, 0, stream>>>(xlh, a_s, a_d, cnt, seidx, ovf, ovf_cnt, b1, h, N);
  k_gemm_l2<<<gb, 256, 0, stream>>>(h, W2, as2, ad2, xl2h, a_s, a_d, N);
  k_aggr_l2<<<8192, 256, 0, stream>>>(xl2h, a_s, a_d, cnt, seidx, ovf, ovf_cnt, b2, out, N);

  k_colsum<<<1024, 256, 0, stream>>>(out, csum, N);
  const size_t tot4 = (size_t)N * 64 / 4;
  k_norm<<<2048, 256, 0, stream>>>(out, csum, tot4);
}

// Round 8
// 325.684 us; speedup vs baseline: 1.2877x; 1.1387x over previous
//
#include <hip/hip_runtime.h>
#include <hip/hip_fp16.h>
#include <math.h>

// ---------------------------------------------------------------------------
// GAT 2-layer network. fp32 compute; gathered feature matrices stored fp16.
// Edge build: phase A bins edges into 256 fixed-width dst partitions (LDS
// histogram + tail append); k_pscan prefix-sums partition counts; k_place
// counting-sorts each partition IN LDS and streams a dense CSR out (no
// scattered global stores anywhere -> no partial-line HBM write RMW).
// N=100000, E=1600000 (+N self-loops), d_in=h1=128, h2=64.
// ---------------------------------------------------------------------------

constexpr int NPARTS = 256;   // fixed-width dst partitions
constexpr int PCAP = 8192;    // entries per partition (avg 6640, +19 sigma)
constexpr int CHUNK = 4096;   // edges per phase-A block-chunk
constexpr int DPPMAX = 400;   // max dsts per partition (ceil(100000/256)=391)

// ---------------- phase A: bin edges into partitions ----------------
__global__ __launch_bounds__(256) void k_part(
    const int* __restrict__ srcA, const int* __restrict__ dstA,
    int* __restrict__ pcur, uint2* __restrict__ parts,
    int* __restrict__ ovf, int* __restrict__ ovf_cnt,
    int E, int N, int DPP, int nch, int ovfcap) {
  __shared__ int hist[NPARTS];
  __shared__ int base[NPARTS];
  const int tot = E + N;
  for (int c = blockIdx.x; c < nch; c += gridDim.x) {
    hist[threadIdx.x] = 0;
    __syncthreads();
    const int beg = c * CHUNK;
    int pp[16], rr[16], ss[16], dd[16];
#pragma unroll
    for (int j = 0; j < 16; ++j) {
      int e = beg + j * 256 + (int)threadIdx.x;
      int d = -1, s = 0;
      if (e < tot) {
        if (e < E) { d = dstA[e]; s = srcA[e]; } else { d = s = e - E; }
      }
      dd[j] = d; ss[j] = s;
      int p = (d >= 0) ? (d / DPP) : -1;
      pp[j] = p;
      rr[j] = (p >= 0) ? atomicAdd(&hist[p], 1) : 0;
    }
    __syncthreads();
    base[threadIdx.x] = atomicAdd(&pcur[threadIdx.x], hist[threadIdx.x]);
    __syncthreads();
#pragma unroll
    for (int j = 0; j < 16; ++j) {
      int p = pp[j];
      if (p < 0) continue;
      int pos = base[p] + rr[j];
      if (pos < PCAP) {
        parts[(size_t)p * PCAP + pos] = make_uint2((unsigned)ss[j], (unsigned)dd[j]);
      } else {  // partition overflow (essentially impossible): ovf fallback
        int o = atomicAdd(ovf_cnt, 1);
        if (o < ovfcap) { ovf[2 * o] = dd[j]; ovf[2 * o + 1] = ss[j]; }
      }
    }
    __syncthreads();  // hist/base reused next chunk
  }
}

// ---------------- prefix scan over partition counts ----------------
__global__ __launch_bounds__(256) void k_pscan(const int* __restrict__ pcur,
                                               int* __restrict__ pbase) {
  __shared__ int sc[NPARTS];
  int t = threadIdx.x;
  int v = min(pcur[t], PCAP);
  sc[t] = v;
  __syncthreads();
  for (int o = 1; o < NPARTS; o <<= 1) {
    int x = (t >= o) ? sc[t - o] : 0;
    __syncthreads();
    sc[t] += x;
    __syncthreads();
  }
  pbase[t + 1] = sc[t];
  if (t == 0) pbase[0] = 0;
}

// ---------------- phase B: LDS counting-sort -> dense CSR ----------------
__global__ __launch_bounds__(256) void k_place(
    const uint2* __restrict__ parts, const int* __restrict__ pbase,
    int* __restrict__ rowptr, int* __restrict__ seidx,
    int N, int DPP, int nparts) {
  __shared__ int l_cnt[DPPMAX];
  __shared__ int l_off[DPPMAX];
  __shared__ int l_out[PCAP];      // 32KB
  const int p = blockIdx.x;
  const int t = threadIdx.x;
  const int d0 = p * DPP;
  const int ndst = min(DPP, N - d0);
  const int base = pbase[p];
  const int n = pbase[p + 1] - base;
  const uint2* pe = parts + (size_t)p * PCAP;

  for (int i = t; i < ndst; i += 256) l_cnt[i] = 0;
  __syncthreads();
  for (int i = t; i < n; i += 256) {           // count (parts -> L2-hot)
    uint2 e = pe[i];
    atomicAdd(&l_cnt[(int)e.y - d0], 1);
  }
  __syncthreads();
  if (t == 0) {                                 // serial exclusive scan (~391)
    int run = 0;
    for (int i = 0; i < ndst; ++i) { l_off[i] = run; run += l_cnt[i]; }
  }
  __syncthreads();
  for (int i = t; i < ndst; i += 256) {
    rowptr[d0 + i] = base + l_off[i];
    l_cnt[i] = l_off[i];                        // reuse as cursor
  }
  if (p == nparts - 1 && t == 0) rowptr[N] = base + n;
  __syncthreads();
  for (int i = t; i < n; i += 256) {            // place (LDS scatter)
    uint2 e = pe[i];
    int pos = atomicAdd(&l_cnt[(int)e.y - d0], 1);
    l_out[pos] = (int)e.x;
  }
  __syncthreads();
  for (int i = t; i < n; i += 256)              // dense coalesced write-out
    seidx[base + i] = l_out[i];
}

// ---------------- GEMM: XL(fp16) = X @ W, plus a_src/a_dst epilogue ----------
template <int C>
__device__ __forceinline__ void gemm_body(
    const float* __restrict__ X, const float* __restrict__ W,
    const float* __restrict__ atts, const float* __restrict__ attd,
    __half* __restrict__ XLh, float* __restrict__ a_s, float* __restrict__ a_d, int N) {
  constexpr int GK = 128;
  constexpr int ROWS = 64;
  constexpr int KH = (C == 128) ? 64 : 128;     // k-half size
  constexpr int NCG = C / 4;                    // col groups: 32 or 16
  constexpr int RPT = ROWS / (256 / NCG);       // rows/thread: 8 or 4
  __shared__ float sW[KH * C];                  // 32KB
  __shared__ float sXT[GK][ROWS];               // 32KB, transposed X tile
  const int t = threadIdx.x;
  const int cg = t % NCG;
  const int rg = t / NCG;
  float av[4], dv[4];
#pragma unroll
  for (int j = 0; j < 4; ++j) { av[j] = atts[cg * 4 + j]; dv[j] = attd[cg * 4 + j]; }

  for (int r0 = blockIdx.x * ROWS; r0 < N; r0 += gridDim.x * ROWS) {
    __syncthreads();
    {  // stage X^T: lane = row, 4 waves cover k
      const int rl = t & 63;
      const int k0 = (t >> 6) * 32;
      const int r = r0 + rl;
      if (r < N) {
        const float* xr = X + (size_t)r * GK + k0;
#pragma unroll
        for (int j = 0; j < 32; j += 4) {
          float4 v = *(const float4*)(xr + j);
          sXT[k0 + j + 0][rl] = v.x; sXT[k0 + j + 1][rl] = v.y;
          sXT[k0 + j + 2][rl] = v.z; sXT[k0 + j + 3][rl] = v.w;
        }
      } else {
#pragma unroll
        for (int j = 0; j < 32; ++j) sXT[k0 + j][rl] = 0.f;
      }
    }
    float acc[RPT][4];
#pragma unroll
    for (int i = 0; i < RPT; ++i)
#pragma unroll
      for (int j = 0; j < 4; ++j) acc[i][j] = 0.f;

#pragma unroll
    for (int kh = 0; kh < GK / KH; ++kh) {
      __syncthreads();
      for (int i = t * 4; i < KH * C; i += 1024)
        *(float4*)&sW[i] = *(const float4*)&W[(size_t)kh * KH * C + i];
      __syncthreads();
#pragma unroll 4
      for (int k = 0; k < KH; ++k) {
        float4 wv = *(const float4*)&sW[k * C + cg * 4];
        float xr[RPT];
#pragma unroll
        for (int i = 0; i < RPT; i += 4)
          *(float4*)&xr[i] = *(const float4*)&sXT[kh * KH + k][rg * RPT + i];
#pragma unroll
        for (int i = 0; i < RPT; ++i) {
          acc[i][0] = fmaf(xr[i], wv.x, acc[i][0]);
          acc[i][1] = fmaf(xr[i], wv.y, acc[i][1]);
          acc[i][2] = fmaf(xr[i], wv.z, acc[i][2]);
          acc[i][3] = fmaf(xr[i], wv.w, acc[i][3]);
        }
      }
    }
#pragma unroll
    for (int i = 0; i < RPT; ++i) {
      const int r = r0 + rg * RPT + i;
      float ps = acc[i][0] * av[0] + acc[i][1] * av[1] + acc[i][2] * av[2] + acc[i][3] * av[3];
      float pd = acc[i][0] * dv[0] + acc[i][1] * dv[1] + acc[i][2] * dv[2] + acc[i][3] * dv[3];
#pragma unroll
      for (int m = 1; m < NCG; m <<= 1) { ps += __shfl_xor(ps, m); pd += __shfl_xor(pd, m); }
      if (r < N) {
        __half2 p0 = __floats2half2_rn(acc[i][0], acc[i][1]);
        __half2 p1 = __floats2half2_rn(acc[i][2], acc[i][3]);
        uint2 u;
        u.x = *(unsigned*)&p0;
        u.y = *(unsigned*)&p1;
        *(uint2*)&XLh[(size_t)r * C + cg * 4] = u;
        if (cg == 0) { a_s[r] = ps; a_d[r] = pd; }
      }
    }
  }
}

__global__ __launch_bounds__(256) void k_gemm_l1(
    const float* __restrict__ X, const float* __restrict__ W,
    const float* __restrict__ atts, const float* __restrict__ attd,
    __half* __restrict__ XLh, float* __restrict__ a_s, float* __restrict__ a_d, int N) {
  gemm_body<128>(X, W, atts, attd, XLh, a_s, a_d, N);
}
__global__ __launch_bounds__(256) void k_gemm_l2(
    const float* __restrict__ X, const float* __restrict__ W,
    const float* __restrict__ atts, const float* __restrict__ attd,
    __half* __restrict__ XLh, float* __restrict__ a_s, float* __restrict__ a_d, int N) {
  gemm_body<64>(X, W, atts, attd, XLh, a_s, a_d, N);
}

// ---------------- per-dst attention + aggregation (one wave per dst) ----------
// CSR: edges for dst d at seidx[rowptr[d]..rowptr[d+1]). Fast single-burst
// path for deg<=64; chunked fallback is fully correct for any degree.
template <int C, bool RELU>
__device__ __forceinline__ void aggr_body(
    const __half* __restrict__ XLh, const float* __restrict__ as_,
    const float* __restrict__ ad_, const int* __restrict__ rowptr,
    const int* __restrict__ seidx, const int* __restrict__ ovf,
    const int* __restrict__ ovf_cnt, const float* __restrict__ bias,
    float* __restrict__ OUT, int N) {
  constexpr int PL = C / 64;  // cols per lane: 2 (C=128) or 1 (C=64)
  const int lane = threadIdx.x & 63;
  const int wid = threadIdx.x >> 6;
  const int novf = *ovf_cnt;  // 0 in practice
  float bb[PL];
#pragma unroll
  for (int j = 0; j < PL; ++j) bb[j] = bias[lane * PL + j];

  for (int d = blockIdx.x * 4 + wid; d < N; d += gridDim.x * 4) {
    const int beg = rowptr[d], end = rowptr[d + 1];
    const int nb = end - beg;
    const float adst = ad_[d];

    float m, s;
    int sv = 0; float vv = -1e30f;
    if (nb <= 64) {
      // fast: one edge per lane, logit kept in register
      if (lane < nb) {
        sv = seidx[beg + lane];
        float t = as_[sv] + adst;
        vv = t > 0.f ? t : 0.2f * t;
      }
      m = vv; s = (lane < nb) ? 1.f : 0.f;
    } else {
      // general: lane-strided online (max,sum)
      m = -1e30f; s = 0.f;
      for (int i = beg + lane; i < end; i += 64) {
        int s2 = seidx[i];
        float t = as_[s2] + adst;
        t = t > 0.f ? t : 0.2f * t;
        float M = fmaxf(m, t);
        s = s * __expf(m - M) + __expf(t - M);
        m = M;
      }
    }
#pragma unroll
    for (int o = 32; o; o >>= 1) {
      float m2 = __shfl_xor(m, o), s2 = __shfl_xor(s, o);
      float M = fmaxf(m, m2);
      s = s * __expf(m - M) + s2 * __expf(m2 - M);
      m = M;
    }
    if (novf > 0) {  // cold: merge overflow entries into (m,s)
      float mo = -1e30f, so = 0.f;
      for (int i = lane; i < novf; i += 64) {
        if (ovf[2 * i] == d) {
          float t = as_[ovf[2 * i + 1]] + adst;
          t = t > 0.f ? t : 0.2f * t;
          float M = fmaxf(mo, t);
          so = so * __expf(mo - M) + __expf(t - M);
          mo = M;
        }
      }
#pragma unroll
      for (int o = 32; o; o >>= 1) {
        float m2 = __shfl_xor(mo, o), s2 = __shfl_xor(so, o);
        float M = fmaxf(mo, m2);
        so = so * __expf(mo - M) + s2 * __expf(m2 - M);
        mo = M;
      }
      float M = fmaxf(m, mo);
      s = s * __expf(m - M) + so * __expf(mo - M);
      m = M;
    }
    const float inv = 1.f / (s + 1e-16f);

    // burst-broadcast weighted gather (fp16 rows)
    float acc[PL];
#pragma unroll
    for (int j = 0; j < PL; ++j) acc[j] = 0.f;

    if (nb <= 64) {
      const float wv = (lane < nb) ? __expf(vv - m) * inv : 0.f;
      auto body = [&](int j) {
        int sj = __shfl(sv, j);
        float wj = __shfl(wv, j);
        if (PL == 2) {
          __half2 hv = *(const __half2*)(XLh + (size_t)sj * C + lane * 2);
          float2 xv = __half22float2(hv);
          acc[0] = fmaf(wj, xv.x, acc[0]);
          acc[1] = fmaf(wj, xv.y, acc[1]);
        } else {
          acc[0] = fmaf(wj, __half2float(XLh[(size_t)sj * C + lane]), acc[0]);
        }
      };
      int j = 0;
      for (; j + 4 <= nb; j += 4) { body(j); body(j + 1); body(j + 2); body(j + 3); }
      for (; j < nb; ++j) body(j);
    } else {
      for (int i0 = beg; i0 < end; i0 += 64) {
        const int nc = min(64, end - i0);
        int sc = 0; float wc = 0.f;
        if (lane < nc) {
          sc = seidx[i0 + lane];
          float t = as_[sc] + adst;
          t = t > 0.f ? t : 0.2f * t;
          wc = __expf(t - m) * inv;
        }
        for (int j = 0; j < nc; ++j) {
          int sj = __shfl(sc, j);
          float wj = __shfl(wc, j);
          if (PL == 2) {
            __half2 hv = *(const __half2*)(XLh + (size_t)sj * C + lane * 2);
            float2 xv = __half22float2(hv);
            acc[0] = fmaf(wj, xv.x, acc[0]);
            acc[1] = fmaf(wj, xv.y, acc[1]);
          } else {
            acc[0] = fmaf(wj, __half2float(XLh[(size_t)sj * C + lane]), acc[0]);
          }
        }
      }
    }

    if (novf > 0) {  // cold: serial overflow gather (wave-uniform)
      for (int i = 0; i < novf; ++i) {
        int od = ovf[2 * i];
        if (od != d) continue;
        int os = ovf[2 * i + 1];
        float t = as_[os] + adst;
        t = t > 0.f ? t : 0.2f * t;
        float wj = __expf(t - m) * inv;
        if (PL == 2) {
          __half2 hv = *(const __half2*)(XLh + (size_t)os * C + lane * 2);
          float2 xv = __half22float2(hv);
          acc[0] = fmaf(wj, xv.x, acc[0]);
          acc[1] = fmaf(wj, xv.y, acc[1]);
        } else {
          acc[0] = fmaf(wj, __half2float(XLh[(size_t)os * C + lane]), acc[0]);
        }
      }
    }

    float o0 = acc[0] + bb[0];
    if (RELU) o0 = o0 > 0.f ? o0 : 0.01f * o0;
    if (PL == 2) {
      float o1 = acc[1] + bb[1];
      if (RELU) o1 = o1 > 0.f ? o1 : 0.01f * o1;
      *(float2*)&OUT[(size_t)d * C + lane * 2] = make_float2(o0, o1);
    } else {
      OUT[(size_t)d * C + lane] = o0;
    }
  }
}

__global__ __launch_bounds__(256) void k_aggr_l1(
    const __half* __restrict__ XLh, const float* __restrict__ as_,
    const float* __restrict__ ad_, const int* __restrict__ rowptr,
    const int* __restrict__ seidx, const int* __restrict__ ovf,
    const int* __restrict__ ovf_cnt, const float* __restrict__ bias,
    float* __restrict__ OUT, int N) {
  aggr_body<128, true>(XLh, as_, ad_, rowptr, seidx, ovf, ovf_cnt, bias, OUT, N);
}
__global__ __launch_bounds__(256) void k_aggr_l2(
    const __half* __restrict__ XLh, const float* __restrict__ as_,
    const float* __restrict__ ad_, const int* __restrict__ rowptr,
    const int* __restrict__ seidx, const int* __restrict__ ovf,
    const int* __restrict__ ovf_cnt, const float* __restrict__ bias,
    float* __restrict__ OUT, int N) {
  aggr_body<64, false>(XLh, as_, ad_, rowptr, seidx, ovf, ovf_cnt, bias, OUT, N);
}

// ---------------- column softmax (axis=0) over OUT [N][64] ----------------
// Pre-softmax values are O(1) -> exp without max-subtraction is safe.
__global__ void k_colsum(const float* __restrict__ O, float* __restrict__ csum, int N) {
  __shared__ float sm[4][64];
  int c = threadIdx.x & 63;
  int wv = threadIdx.x >> 6;
  float s = 0.f;
  for (int r = blockIdx.x * 4 + wv; r < N; r += gridDim.x * 4)
    s += __expf(O[(size_t)r * 64 + c]);
  sm[wv][c] = s;
  __syncthreads();
  if (threadIdx.x < 64) {
    float s2 = sm[0][c] + sm[1][c] + sm[2][c] + sm[3][c];
    atomicAdd(&csum[c], s2);
  }
}

__global__ void k_norm(float* __restrict__ O, const float* __restrict__ csum, size_t tot4) {
  for (size_t i = blockIdx.x * (size_t)blockDim.x + threadIdx.x; i < tot4;
       i += (size_t)gridDim.x * blockDim.x) {
    float4 v = ((float4*)O)[i];
    int c0 = (int)((i * 4) & 63);
    float s0 = csum[c0],     s1 = csum[c0 + 1];
    float s2 = csum[c0 + 2], s3 = csum[c0 + 3];
    v.x = __expf(v.x) / s0;
    v.y = __expf(v.y) / s1;
    v.z = __expf(v.z) / s2;
    v.w = __expf(v.w) / s3;
    ((float4*)O)[i] = v;
  }
}

// ---------------------------------------------------------------------------
extern "C" void kernel_launch(void* const* d_in, const int* in_sizes, int n_in,
                              void* d_out, int out_size, void* d_ws, size_t ws_size,
                              hipStream_t stream) {
  const float* x   = (const float*)d_in[0];
  const int*   ei  = (const int*)d_in[1];
  const float* W1  = (const float*)d_in[2];
  const float* as1 = (const float*)d_in[3];
  const float* ad1 = (const float*)d_in[4];
  const float* b1  = (const float*)d_in[5];
  const float* W2  = (const float*)d_in[6];
  const float* as2 = (const float*)d_in[7];
  const float* ad2 = (const float*)d_in[8];
  const float* b2  = (const float*)d_in[9];
  float* out = (float*)d_out;

  const int N = in_sizes[0] / 128;
  const int E = in_sizes[1] / 2;
  const int Etot = E + N;
  const int* srcA = ei;
  const int* dstA = ei + E;
  const int DPP = (N + NPARTS - 1) / NPARTS;          // 391
  const int nparts = (N + DPP - 1) / DPP;             // 256

  char* w = (char*)d_ws;
  auto take = [&](size_t bytes) -> void* {
    void* p = (void*)w;
    w += (bytes + 255) & ~(size_t)255;
    return p;
  };
  __half* xlh   = (__half*)take((size_t)N * 128 * 2);  // layer-1 XL (fp16)
  __half* xl2h  = (__half*)take((size_t)N * 64 * 2);   // layer-2 XL (fp16)
  float*  h     = (float*)take((size_t)N * 128 * 4);   // layer-1 output (fp32)
  float*  a_s   = (float*)take((size_t)N * 4);
  float*  a_d   = (float*)take((size_t)N * 4);
  int*    zeroB = (int*)take((size_t)(1 + 64 + NPARTS) * 4); // ovf_cnt|csum|pcur
  int*    ovf_cnt = zeroB;
  float*  csum    = (float*)(zeroB + 1);
  int*    pcur    = zeroB + 1 + 64;
  int*    pbase  = (int*)take((size_t)(NPARTS + 1) * 4);
  int*    rowptr = (int*)take((size_t)(N + 1) * 4);
  int*    seidx  = (int*)take((size_t)Etot * 4);
  int*    ovf    = (int*)take((size_t)Etot * 2 * 4);
  uint2*  parts  = (uint2*)take((size_t)NPARTS * PCAP * 8);

  hipMemsetAsync(zeroB, 0, (size_t)(1 + 64 + NPARTS) * 4, stream);

  const int nch = (Etot + CHUNK - 1) / CHUNK;
  k_part<<<nch, 256, 0, stream>>>(srcA, dstA, pcur, parts, ovf, ovf_cnt,
                                  E, N, DPP, nch, Etot);
  k_pscan<<<1, NPARTS, 0, stream>>>(pcur, pbase);
  k_place<<<nparts, 256, 0, stream>>>(parts, pbase, rowptr, seidx, N, DPP, nparts);

  const int gb = (N + 63) / 64;
  k_gemm_l1<<<gb, 256, 0, stream>>>(x, W1, as1, ad1, xlh, a_s, a_d, N);
  k_aggr_l1<<<8192, 256, 0, stream>>>(xlh, a_s, a_d, rowptr, seidx, ovf, ovf_cnt, b1, h, N);
  k_gemm_l2<<<gb, 256, 0, stream>>>(h, W2, as2, ad2, xl2h, a_s, a_d, N);
  k_aggr_l2<<<8192, 256, 0, stream>>>(xl2h, a_s, a_d, rowptr, seidx, ovf, ovf_cnt, b2, out, N);

  k_colsum<<<1024, 256, 0, stream>>>(out, csum, N);
  const size_t tot4 = (size_t)N * 64 / 4;
  k_norm<<<2048, 256, 0, stream>>>(out, csum, tot4);
}

// Round 9
// 268.635 us; speedup vs baseline: 1.5612x; 1.2124x over previous
//
#include <hip/hip_runtime.h>
#include <hip/hip_fp16.h>
#include <math.h>

// ---------------------------------------------------------------------------
// GAT 2-layer network. MFMA fp16 GEMMs (fp32 accum); fp16 gathered features;
// max-free edge softmax (logits bounded -> exp-direct is exact same alpha);
// CSR built via binned counting-sort (no scattered global stores).
// N=100000, E=1600000 (+N self-loops), d_in=h1=128, h2=64.
// ---------------------------------------------------------------------------

constexpr int NPARTS = 256;   // fixed-width dst partitions
constexpr int PCAP = 8192;    // entries per partition (avg 6640, +19 sigma)
constexpr int CHUNK = 4096;   // edges per phase-A block-chunk
constexpr int DPPMAX = 400;   // max dsts per partition

typedef _Float16 f16x8 __attribute__((ext_vector_type(8)));
typedef float f32x4 __attribute__((ext_vector_type(4)));

// ---------------- phase A: bin edges into partitions ----------------
__global__ __launch_bounds__(256) void k_part(
    const int* __restrict__ srcA, const int* __restrict__ dstA,
    int* __restrict__ pcur, uint2* __restrict__ parts,
    int* __restrict__ ovf, int* __restrict__ ovf_cnt,
    int E, int N, int DPP, int nch, int ovfcap) {
  __shared__ int hist[NPARTS];
  __shared__ int base[NPARTS];
  const int tot = E + N;
  for (int c = blockIdx.x; c < nch; c += gridDim.x) {
    hist[threadIdx.x] = 0;
    __syncthreads();
    const int beg = c * CHUNK;
    int pp[16], rr[16], ss[16], dd[16];
#pragma unroll
    for (int j = 0; j < 16; ++j) {
      int e = beg + j * 256 + (int)threadIdx.x;
      int d = -1, s = 0;
      if (e < tot) {
        if (e < E) { d = dstA[e]; s = srcA[e]; } else { d = s = e - E; }
      }
      dd[j] = d; ss[j] = s;
      int p = (d >= 0) ? (d / DPP) : -1;
      pp[j] = p;
      rr[j] = (p >= 0) ? atomicAdd(&hist[p], 1) : 0;
    }
    __syncthreads();
    base[threadIdx.x] = atomicAdd(&pcur[threadIdx.x], hist[threadIdx.x]);
    __syncthreads();
#pragma unroll
    for (int j = 0; j < 16; ++j) {
      int p = pp[j];
      if (p < 0) continue;
      int pos = base[p] + rr[j];
      if (pos < PCAP) {
        parts[(size_t)p * PCAP + pos] = make_uint2((unsigned)ss[j], (unsigned)dd[j]);
      } else {
        int o = atomicAdd(ovf_cnt, 1);
        if (o < ovfcap) { ovf[2 * o] = dd[j]; ovf[2 * o + 1] = ss[j]; }
      }
    }
    __syncthreads();
  }
}

// ---------------- prefix scan over partition counts ----------------
__global__ __launch_bounds__(256) void k_pscan(const int* __restrict__ pcur,
                                               int* __restrict__ pbase) {
  __shared__ int sc[NPARTS];
  int t = threadIdx.x;
  int v = min(pcur[t], PCAP);
  sc[t] = v;
  __syncthreads();
  for (int o = 1; o < NPARTS; o <<= 1) {
    int x = (t >= o) ? sc[t - o] : 0;
    __syncthreads();
    sc[t] += x;
    __syncthreads();
  }
  pbase[t + 1] = sc[t];
  if (t == 0) pbase[0] = 0;
}

// ---------------- phase B: LDS counting-sort -> dense CSR ----------------
__global__ __launch_bounds__(256) void k_place(
    const uint2* __restrict__ parts, const int* __restrict__ pbase,
    int* __restrict__ rowptr, int* __restrict__ seidx,
    int N, int DPP, int nparts) {
  __shared__ int l_cnt[DPPMAX];
  __shared__ int l_off[DPPMAX];
  __shared__ int l_out[PCAP];      // 32KB
  const int p = blockIdx.x;
  const int t = threadIdx.x;
  const int d0 = p * DPP;
  const int ndst = min(DPP, N - d0);
  const int base = pbase[p];
  const int n = pbase[p + 1] - base;
  const uint2* pe = parts + (size_t)p * PCAP;

  for (int i = t; i < ndst; i += 256) l_cnt[i] = 0;
  __syncthreads();
  for (int i = t; i < n; i += 256) {
    uint2 e = pe[i];
    atomicAdd(&l_cnt[(int)e.y - d0], 1);
  }
  __syncthreads();
  if (t == 0) {
    int run = 0;
    for (int i = 0; i < ndst; ++i) { l_off[i] = run; run += l_cnt[i]; }
  }
  __syncthreads();
  for (int i = t; i < ndst; i += 256) {
    rowptr[d0 + i] = base + l_off[i];
    l_cnt[i] = l_off[i];
  }
  if (p == nparts - 1 && t == 0) rowptr[N] = base + n;
  __syncthreads();
  for (int i = t; i < n; i += 256) {
    uint2 e = pe[i];
    int pos = atomicAdd(&l_cnt[(int)e.y - d0], 1);
    l_out[pos] = (int)e.x;
  }
  __syncthreads();
  for (int i = t; i < n; i += 256)
    seidx[base + i] = l_out[i];
}

// ---------------- W fragment prep (fp16, MFMA-B layout, linear) ----------
// Wf[((cb*4+kk)*64+lane)*8+j] = W[(kk*32 + (lane>>4)*8 + j)*C + cb*16 + (lane&15)]
__global__ __launch_bounds__(256) void k_wprep(
    const float* __restrict__ W1, const float* __restrict__ W2,
    _Float16* __restrict__ Wf1, _Float16* __restrict__ Wf2) {
  int t = blockIdx.x * blockDim.x + threadIdx.x;
  int stride = gridDim.x * blockDim.x;
  for (int i = t; i < 8 * 4 * 64 * 8; i += stride) {   // W1: 128x128, NCB=8
    int j = i & 7, l = (i >> 3) & 63, kk = (i >> 9) & 3, cb = i >> 11;
    int k = kk * 32 + (l >> 4) * 8 + j, c = cb * 16 + (l & 15);
    Wf1[i] = (_Float16)W1[k * 128 + c];
  }
  for (int i = t; i < 4 * 4 * 64 * 8; i += stride) {   // W2: 128x64, NCB=4
    int j = i & 7, l = (i >> 3) & 63, kk = (i >> 9) & 3, cb = i >> 11;
    int k = kk * 32 + (l >> 4) * 8 + j, c = cb * 16 + (l & 15);
    Wf2[i] = (_Float16)W2[k * 64 + c];
  }
}

// ---------------- MFMA GEMM: XL(fp16) = X @ W + fused a_src/a_dst ---------
// 4 waves/block, 16 rows/wave, K=128 via 4x mfma_f32_16x16x32_f16.
// A loaded directly from global (coalesced 32B/lane), B frags L1-hot.
template <int C>
__device__ __forceinline__ void gemm_mfma_body(
    const float* __restrict__ X, const _Float16* __restrict__ Wf,
    const float* __restrict__ atts, const float* __restrict__ attd,
    __half* __restrict__ XLh, float* __restrict__ a_s, float* __restrict__ a_d,
    int N) {
  constexpr int NCB = C / 16;
  const int lane = threadIdx.x & 63;
  const int wv = threadIdx.x >> 6;
  const int r0 = blockIdx.x * 64 + wv * 16;     // wave's 16-row tile
  const int arow = lane & 15;
  const int grp = lane >> 4;
  const int r = r0 + arow;
  const int rsafe = (r < N) ? r : (N - 1);

  float av[NCB], dv[NCB];
#pragma unroll
  for (int cb = 0; cb < NCB; ++cb) {
    av[cb] = atts[cb * 16 + arow];   // arow == (lane&15) == C/D col-in-block
    dv[cb] = attd[cb * 16 + arow];
  }

  // A fragments: lane holds X[rsafe][kk*32 + grp*8 + j], j=0..7 (fp32->fp16)
  f16x8 af[4];
  const float* xr = X + (size_t)rsafe * 128 + grp * 8;
#pragma unroll
  for (int kk = 0; kk < 4; ++kk) {
    float4 u0 = *(const float4*)(xr + kk * 32);
    float4 u1 = *(const float4*)(xr + kk * 32 + 4);
    af[kk][0] = (_Float16)u0.x; af[kk][1] = (_Float16)u0.y;
    af[kk][2] = (_Float16)u0.z; af[kk][3] = (_Float16)u0.w;
    af[kk][4] = (_Float16)u1.x; af[kk][5] = (_Float16)u1.y;
    af[kk][6] = (_Float16)u1.z; af[kk][7] = (_Float16)u1.w;
  }

  float ps[4] = {0.f, 0.f, 0.f, 0.f};
  float pd[4] = {0.f, 0.f, 0.f, 0.f};

#pragma unroll
  for (int cb = 0; cb < NCB; ++cb) {
    f32x4 acc = {0.f, 0.f, 0.f, 0.f};
#pragma unroll
    for (int kk = 0; kk < 4; ++kk) {
      f16x8 bf = *(const f16x8*)(Wf + ((size_t)(cb * 4 + kk) * 64 + lane) * 8);
      acc = __builtin_amdgcn_mfma_f32_16x16x32_f16(af[kk], bf, acc, 0, 0, 0);
    }
    const int ocol = cb * 16 + arow;             // C/D: col = lane&15
#pragma unroll
    for (int i = 0; i < 4; ++i) {                // C/D: row = grp*4 + i
      const int orow = r0 + grp * 4 + i;
      if (orow < N) XLh[(size_t)orow * C + ocol] = (__half)(_Float16)acc[i];
      ps[i] = fmaf(acc[i], av[cb], ps[i]);
      pd[i] = fmaf(acc[i], dv[cb], pd[i]);
    }
  }
  // reduce dots across the 16 col-lanes
#pragma unroll
  for (int m = 1; m < 16; m <<= 1) {
#pragma unroll
    for (int i = 0; i < 4; ++i) {
      ps[i] += __shfl_xor(ps[i], m);
      pd[i] += __shfl_xor(pd[i], m);
    }
  }
  if (arow == 0) {
#pragma unroll
    for (int i = 0; i < 4; ++i) {
      const int orow = r0 + grp * 4 + i;
      if (orow < N) { a_s[orow] = ps[i]; a_d[orow] = pd[i]; }
    }
  }
}

__global__ __launch_bounds__(256) void k_gemm_l1(
    const float* __restrict__ X, const _Float16* __restrict__ Wf,
    const float* __restrict__ atts, const float* __restrict__ attd,
    __half* __restrict__ XLh, float* __restrict__ a_s, float* __restrict__ a_d,
    int N) {
  gemm_mfma_body<128>(X, Wf, atts, attd, XLh, a_s, a_d, N);
}
__global__ __launch_bounds__(256) void k_gemm_l2(
    const float* __restrict__ X, const _Float16* __restrict__ Wf,
    const float* __restrict__ atts, const float* __restrict__ attd,
    __half* __restrict__ XLh, float* __restrict__ a_s, float* __restrict__ a_d,
    int N) {
  gemm_mfma_body<64>(X, Wf, atts, attd, XLh, a_s, a_d, N);
}

// ---------------- per-dst attention + aggregation (one wave per dst) ----------
// Max-free softmax: logits = leaky(a_s+a_d) bounded (|.|<~4) -> exp-direct
// gives IDENTICAL alpha to the ref's shifted softmax.
template <int C, bool RELU>
__device__ __forceinline__ void aggr_body(
    const __half* __restrict__ XLh, const float* __restrict__ as_,
    const float* __restrict__ ad_, const int* __restrict__ rowptr,
    const int* __restrict__ seidx, const int* __restrict__ ovf,
    const int* __restrict__ ovf_cnt, const float* __restrict__ bias,
    float* __restrict__ OUT, int N) {
  constexpr int PL = C / 64;  // cols per lane: 2 (C=128) or 1 (C=64)
  const int lane = threadIdx.x & 63;
  const int wid = threadIdx.x >> 6;
  const int novf = *ovf_cnt;  // 0 in practice
  float bb[PL];
#pragma unroll
  for (int j = 0; j < PL; ++j) bb[j] = bias[lane * PL + j];

  for (int d = blockIdx.x * 4 + wid; d < N; d += gridDim.x * 4) {
    const int beg = rowptr[d], end = rowptr[d + 1];
    const int nb = end - beg;
    const float adst = ad_[d];

    float s;
    int sv = 0; float ev = 0.f;
    if (nb <= 64) {
      if (lane < nb) {
        sv = seidx[beg + lane];
        float t = as_[sv] + adst;
        t = t > 0.f ? t : 0.2f * t;
        ev = __expf(t);
      }
      s = ev;
    } else {
      s = 0.f;
      for (int i = beg + lane; i < end; i += 64) {
        int s2 = seidx[i];
        float t = as_[s2] + adst;
        t = t > 0.f ? t : 0.2f * t;
        s += __expf(t);
      }
    }
#pragma unroll
    for (int o = 32; o; o >>= 1) s += __shfl_xor(s, o);

    if (novf > 0) {  // cold: merge overflow entries into s
      float so = 0.f;
      for (int i = lane; i < novf; i += 64) {
        if (ovf[2 * i] == d) {
          float t = as_[ovf[2 * i + 1]] + adst;
          t = t > 0.f ? t : 0.2f * t;
          so += __expf(t);
        }
      }
#pragma unroll
      for (int o = 32; o; o >>= 1) so += __shfl_xor(so, o);
      s += so;
    }
    const float inv = 1.f / (s + 1e-16f);

    // burst-broadcast weighted gather (fp16 rows)
    float acc[PL];
#pragma unroll
    for (int j = 0; j < PL; ++j) acc[j] = 0.f;

    if (nb <= 64) {
      const float wv = ev * inv;
      auto body = [&](int j) {
        int sj = __shfl(sv, j);
        float wj = __shfl(wv, j);
        if (PL == 2) {
          __half2 hv = *(const __half2*)(XLh + (size_t)sj * C + lane * 2);
          float2 xv = __half22float2(hv);
          acc[0] = fmaf(wj, xv.x, acc[0]);
          acc[1] = fmaf(wj, xv.y, acc[1]);
        } else {
          acc[0] = fmaf(wj, __half2float(XLh[(size_t)sj * C + lane]), acc[0]);
        }
      };
      int j = 0;
      for (; j + 4 <= nb; j += 4) { body(j); body(j + 1); body(j + 2); body(j + 3); }
      for (; j < nb; ++j) body(j);
    } else {
      for (int i0 = beg; i0 < end; i0 += 64) {
        const int nc = min(64, end - i0);
        int sc = 0; float wc = 0.f;
        if (lane < nc) {
          sc = seidx[i0 + lane];
          float t = as_[sc] + adst;
          t = t > 0.f ? t : 0.2f * t;
          wc = __expf(t) * inv;
        }
        for (int j = 0; j < nc; ++j) {
          int sj = __shfl(sc, j);
          float wj = __shfl(wc, j);
          if (PL == 2) {
            __half2 hv = *(const __half2*)(XLh + (size_t)sj * C + lane * 2);
            float2 xv = __half22float2(hv);
            acc[0] = fmaf(wj, xv.x, acc[0]);
            acc[1] = fmaf(wj, xv.y, acc[1]);
          } else {
            acc[0] = fmaf(wj, __half2float(XLh[(size_t)sj * C + lane]), acc[0]);
          }
        }
      }
    }

    if (novf > 0) {  // cold: serial overflow gather (wave-uniform)
      for (int i = 0; i < novf; ++i) {
        int od = ovf[2 * i];
        if (od != d) continue;
        int os = ovf[2 * i + 1];
        float t = as_[os] + adst;
        t = t > 0.f ? t : 0.2f * t;
        float wj = __expf(t) * inv;
        if (PL == 2) {
          __half2 hv = *(const __half2*)(XLh + (size_t)os * C + lane * 2);
          float2 xv = __half22float2(hv);
          acc[0] = fmaf(wj, xv.x, acc[0]);
          acc[1] = fmaf(wj, xv.y, acc[1]);
        } else {
          acc[0] = fmaf(wj, __half2float(XLh[(size_t)os * C + lane]), acc[0]);
        }
      }
    }

    float o0 = acc[0] + bb[0];
    if (RELU) o0 = o0 > 0.f ? o0 : 0.01f * o0;
    if (PL == 2) {
      float o1 = acc[1] + bb[1];
      if (RELU) o1 = o1 > 0.f ? o1 : 0.01f * o1;
      *(float2*)&OUT[(size_t)d * C + lane * 2] = make_float2(o0, o1);
    } else {
      OUT[(size_t)d * C + lane] = o0;
    }
  }
}

__global__ __launch_bounds__(256) void k_aggr_l1(
    const __half* __restrict__ XLh, const float* __restrict__ as_,
    const float* __restrict__ ad_, const int* __restrict__ rowptr,
    const int* __restrict__ seidx, const int* __restrict__ ovf,
    const int* __restrict__ ovf_cnt, const float* __restrict__ bias,
    float* __restrict__ OUT, int N) {
  aggr_body<128, true>(XLh, as_, ad_, rowptr, seidx, ovf, ovf_cnt, bias, OUT, N);
}
__global__ __launch_bounds__(256) void k_aggr_l2(
    const __half* __restrict__ XLh, const float* __restrict__ as_,
    const float* __restrict__ ad_, const int* __restrict__ rowptr,
    const int* __restrict__ seidx, const int* __restrict__ ovf,
    const int* __restrict__ ovf_cnt, const float* __restrict__ bias,
    float* __restrict__ OUT, int N) {
  aggr_body<64, false>(XLh, as_, ad_, rowptr, seidx, ovf, ovf_cnt, bias, OUT, N);
}

// ---------------- column softmax (axis=0) over OUT [N][64] ----------------
__global__ void k_colsum(const float* __restrict__ O, float* __restrict__ csum, int N) {
  __shared__ float sm[4][64];
  int c = threadIdx.x & 63;
  int wv = threadIdx.x >> 6;
  float s = 0.f;
  for (int r = blockIdx.x * 4 + wv; r < N; r += gridDim.x * 4)
    s += __expf(O[(size_t)r * 64 + c]);
  sm[wv][c] = s;
  __syncthreads();
  if (threadIdx.x < 64) {
    float s2 = sm[0][c] + sm[1][c] + sm[2][c] + sm[3][c];
    atomicAdd(&csum[c], s2);
  }
}

__global__ void k_norm(float* __restrict__ O, const float* __restrict__ csum, size_t tot4) {
  for (size_t i = blockIdx.x * (size_t)blockDim.x + threadIdx.x; i < tot4;
       i += (size_t)gridDim.x * blockDim.x) {
    float4 v = ((float4*)O)[i];
    int c0 = (int)((i * 4) & 63);
    float s0 = csum[c0],     s1 = csum[c0 + 1];
    float s2 = csum[c0 + 2], s3 = csum[c0 + 3];
    v.x = __expf(v.x) / s0;
    v.y = __expf(v.y) / s1;
    v.z = __expf(v.z) / s2;
    v.w = __expf(v.w) / s3;
    ((float4*)O)[i] = v;
  }
}

// ---------------------------------------------------------------------------
extern "C" void kernel_launch(void* const* d_in, const int* in_sizes, int n_in,
                              void* d_out, int out_size, void* d_ws, size_t ws_size,
                              hipStream_t stream) {
  const float* x   = (const float*)d_in[0];
  const int*   ei  = (const int*)d_in[1];
  const float* W1  = (const float*)d_in[2];
  const float* as1 = (const float*)d_in[3];
  const float* ad1 = (const float*)d_in[4];
  const float* b1  = (const float*)d_in[5];
  const float* W2  = (const float*)d_in[6];
  const float* as2 = (const float*)d_in[7];
  const float* ad2 = (const float*)d_in[8];
  const float* b2  = (const float*)d_in[9];
  float* out = (float*)d_out;

  const int N = in_sizes[0] / 128;
  const int E = in_sizes[1] / 2;
  const int Etot = E + N;
  const int* srcA = ei;
  const int* dstA = ei + E;
  const int DPP = (N + NPARTS - 1) / NPARTS;          // 391
  const int nparts = (N + DPP - 1) / DPP;             // 256

  char* w = (char*)d_ws;
  auto take = [&](size_t bytes) -> void* {
    void* p = (void*)w;
    w += (bytes + 255) & ~(size_t)255;
    return p;
  };
  __half*    xlh   = (__half*)take((size_t)N * 128 * 2);  // layer-1 XL (fp16)
  __half*    xl2h  = (__half*)take((size_t)N * 64 * 2);   // layer-2 XL (fp16)
  float*     h     = (float*)take((size_t)N * 128 * 4);   // layer-1 output (fp32)
  float*     a_s   = (float*)take((size_t)N * 4);
  float*     a_d   = (float*)take((size_t)N * 4);
  int*       zeroB = (int*)take((size_t)(1 + 64 + NPARTS) * 4); // ovf_cnt|csum|pcur
  int*       ovf_cnt = zeroB;
  float*     csum    = (float*)(zeroB + 1);
  int*       pcur    = zeroB + 1 + 64;
  int*       pbase  = (int*)take((size_t)(NPARTS + 1) * 4);
  int*       rowptr = (int*)take((size_t)(N + 1) * 4);
  int*       seidx  = (int*)take((size_t)Etot * 4);
  int*       ovf    = (int*)take((size_t)Etot * 2 * 4);
  uint2*     parts  = (uint2*)take((size_t)NPARTS * PCAP * 8);
  _Float16*  wf1    = (_Float16*)take((size_t)8 * 4 * 64 * 8 * 2);
  _Float16*  wf2    = (_Float16*)take((size_t)4 * 4 * 64 * 8 * 2);

  hipMemsetAsync(zeroB, 0, (size_t)(1 + 64 + NPARTS) * 4, stream);

  const int nch = (Etot + CHUNK - 1) / CHUNK;
  k_part<<<nch, 256, 0, stream>>>(srcA, dstA, pcur, parts, ovf, ovf_cnt,
                                  E, N, DPP, nch, Etot);
  k_wprep<<<32, 256, 0, stream>>>(W1, W2, wf1, wf2);
  k_pscan<<<1, NPARTS, 0, stream>>>(pcur, pbase);
  k_place<<<nparts, 256, 0, stream>>>(parts, pbase, rowptr, seidx, N, DPP, nparts);

  const int gb = (N + 63) / 64;
  k_gemm_l1<<<gb, 256, 0, stream>>>(x, wf1, as1, ad1, xlh, a_s, a_d, N);
  k_aggr_l1<<<8192, 256, 0, stream>>>(xlh, a_s, a_d, rowptr, seidx, ovf, ovf_cnt, b1, h, N);
  k_gemm_l2<<<gb, 256, 0, stream>>>(h, wf2, as2, ad2, xl2h, a_s, a_d, N);
  k_aggr_l2<<<8192, 256, 0, stream>>>(xl2h, a_s, a_d, rowptr, seidx, ovf, ovf_cnt, b2, out, N);

  k_colsum<<<1024, 256, 0, stream>>>(out, csum, N);
  const size_t tot4 = (size_t)N * 64 / 4;
  k_norm<<<2048, 256, 0, stream>>>(out, csum, tot4);
}

// Round 10
// 242.271 us; speedup vs baseline: 1.7311x; 1.1088x over previous
//
#include <hip/hip_runtime.h>
#include <hip/hip_fp16.h>
#include <math.h>

// ---------------------------------------------------------------------------
// GAT 2-layer network. MFMA fp16 GEMMs (fp32 accum); fp16 gathered features;
// max-free edge softmax; CSR via binned counting-sort. Fused kernels:
//  K1=[edge binning || W fragment prep], K2=[gemm_l1 || CSR place(+scan)],
//  aggr_l2 fuses the column-softmax sum (8-replica atomics).
// N=100000, E=1600000 (+N self-loops), d_in=h1=128, h2=64.
// ---------------------------------------------------------------------------

constexpr int NPARTS = 256;   // fixed-width dst partitions
constexpr int PCAP = 8192;    // entries per partition (avg 6640, +19 sigma)
constexpr int CHUNK = 4096;   // edges per phase-A block-chunk
constexpr int DPPMAX = 400;   // max dsts per partition

typedef _Float16 f16x8 __attribute__((ext_vector_type(8)));
typedef float f32x4 __attribute__((ext_vector_type(4)));

__device__ __forceinline__ int bcasti(int v, int j) {
  return __builtin_amdgcn_readlane(v, j);
}
__device__ __forceinline__ float bcastf(float v, int j) {
  return __uint_as_float((unsigned)__builtin_amdgcn_readlane((int)__float_as_uint(v), j));
}

// ---------------- K1: edge binning (blocks < nch) || W-prep (last 8) --------
__global__ __launch_bounds__(256) void k_build1(
    const int* __restrict__ srcA, const int* __restrict__ dstA,
    int* __restrict__ pcur, uint2* __restrict__ parts,
    int* __restrict__ ovf, int* __restrict__ ovf_cnt,
    const float* __restrict__ W1, const float* __restrict__ W2,
    _Float16* __restrict__ Wf1, _Float16* __restrict__ Wf2,
    int E, int N, int DPP, int nch, int ovfcap) {
  if ((int)blockIdx.x >= nch) {
    // W fragment prep:
    // Wf[((cb*4+kk)*64+l)*8+j] = W[(kk*32+(l>>4)*8+j)*C + cb*16 + (l&15)]
    int t = ((int)blockIdx.x - nch) * 256 + (int)threadIdx.x;
    const int stride = 8 * 256;
    for (int i = t; i < 8 * 4 * 64 * 8; i += stride) {
      int j = i & 7, l = (i >> 3) & 63, kk = (i >> 9) & 3, cb = i >> 11;
      int k = kk * 32 + (l >> 4) * 8 + j, c = cb * 16 + (l & 15);
      Wf1[i] = (_Float16)W1[k * 128 + c];
    }
    for (int i = t; i < 4 * 4 * 64 * 8; i += stride) {
      int j = i & 7, l = (i >> 3) & 63, kk = (i >> 9) & 3, cb = i >> 11;
      int k = kk * 32 + (l >> 4) * 8 + j, c = cb * 16 + (l & 15);
      Wf2[i] = (_Float16)W2[k * 64 + c];
    }
    return;
  }
  __shared__ int hist[NPARTS];
  __shared__ int base[NPARTS];
  const int tot = E + N;
  const int c = blockIdx.x;
  hist[threadIdx.x] = 0;
  __syncthreads();
  const int beg = c * CHUNK;
  int pp[16], rr[16], ss[16], dd[16];
#pragma unroll
  for (int j = 0; j < 16; ++j) {
    int e = beg + j * 256 + (int)threadIdx.x;
    int d = -1, s = 0;
    if (e < tot) {
      if (e < E) { d = dstA[e]; s = srcA[e]; } else { d = s = e - E; }
    }
    dd[j] = d; ss[j] = s;
    int p = (d >= 0) ? (d / DPP) : -1;
    pp[j] = p;
    rr[j] = (p >= 0) ? atomicAdd(&hist[p], 1) : 0;
  }
  __syncthreads();
  base[threadIdx.x] = atomicAdd(&pcur[threadIdx.x], hist[threadIdx.x]);
  __syncthreads();
#pragma unroll
  for (int j = 0; j < 16; ++j) {
    int p = pp[j];
    if (p < 0) continue;
    int pos = base[p] + rr[j];
    if (pos < PCAP) {
      parts[(size_t)p * PCAP + pos] = make_uint2((unsigned)ss[j], (unsigned)dd[j]);
    } else {
      int o = atomicAdd(ovf_cnt, 1);
      if (o < ovfcap) { ovf[2 * o] = dd[j]; ovf[2 * o + 1] = ss[j]; }
    }
  }
}

// ---------------- MFMA GEMM body (16 rows/wave, K=128) ----------------------
template <int C>
__device__ __forceinline__ void gemm_mfma_body(
    const float* __restrict__ X, const _Float16* __restrict__ Wf,
    const float* __restrict__ atts, const float* __restrict__ attd,
    __half* __restrict__ XLh, float* __restrict__ a_s, float* __restrict__ a_d,
    int N, int bid) {
  constexpr int NCB = C / 16;
  const int lane = threadIdx.x & 63;
  const int wv = threadIdx.x >> 6;
  const int r0 = bid * 64 + wv * 16;
  const int arow = lane & 15;
  const int grp = lane >> 4;
  const int r = r0 + arow;
  const int rsafe = (r < N) ? r : (N - 1);

  float av[NCB], dv[NCB];
#pragma unroll
  for (int cb = 0; cb < NCB; ++cb) {
    av[cb] = atts[cb * 16 + arow];
    dv[cb] = attd[cb * 16 + arow];
  }

  f16x8 af[4];
  const float* xr = X + (size_t)rsafe * 128 + grp * 8;
#pragma unroll
  for (int kk = 0; kk < 4; ++kk) {
    float4 u0 = *(const float4*)(xr + kk * 32);
    float4 u1 = *(const float4*)(xr + kk * 32 + 4);
    af[kk][0] = (_Float16)u0.x; af[kk][1] = (_Float16)u0.y;
    af[kk][2] = (_Float16)u0.z; af[kk][3] = (_Float16)u0.w;
    af[kk][4] = (_Float16)u1.x; af[kk][5] = (_Float16)u1.y;
    af[kk][6] = (_Float16)u1.z; af[kk][7] = (_Float16)u1.w;
  }

  float ps[4] = {0.f, 0.f, 0.f, 0.f};
  float pd[4] = {0.f, 0.f, 0.f, 0.f};

#pragma unroll
  for (int cb = 0; cb < NCB; ++cb) {
    f32x4 acc = {0.f, 0.f, 0.f, 0.f};
#pragma unroll
    for (int kk = 0; kk < 4; ++kk) {
      f16x8 bf = *(const f16x8*)(Wf + ((size_t)(cb * 4 + kk) * 64 + lane) * 8);
      acc = __builtin_amdgcn_mfma_f32_16x16x32_f16(af[kk], bf, acc, 0, 0, 0);
    }
    const int ocol = cb * 16 + arow;
#pragma unroll
    for (int i = 0; i < 4; ++i) {
      const int orow = r0 + grp * 4 + i;
      if (orow < N) XLh[(size_t)orow * C + ocol] = (__half)(_Float16)acc[i];
      ps[i] = fmaf(acc[i], av[cb], ps[i]);
      pd[i] = fmaf(acc[i], dv[cb], pd[i]);
    }
  }
#pragma unroll
  for (int m = 1; m < 16; m <<= 1) {
#pragma unroll
    for (int i = 0; i < 4; ++i) {
      ps[i] += __shfl_xor(ps[i], m);
      pd[i] += __shfl_xor(pd[i], m);
    }
  }
  if (arow == 0) {
#pragma unroll
    for (int i = 0; i < 4; ++i) {
      const int orow = r0 + grp * 4 + i;
      if (orow < N) { a_s[orow] = ps[i]; a_d[orow] = pd[i]; }
    }
  }
}

// ---------------- K2: gemm_l1 (blocks < gb) || CSR place+scan (last 256) ----
struct PlaceSmem {
  int sc[NPARTS];
  int l_cnt[DPPMAX];
  int l_off[DPPMAX];
  int l_out[PCAP];
};

__global__ __launch_bounds__(256) void k_gemm1_place(
    const float* __restrict__ X, const _Float16* __restrict__ Wf,
    const float* __restrict__ atts, const float* __restrict__ attd,
    __half* __restrict__ XLh, float* __restrict__ a_s, float* __restrict__ a_d,
    int N, const uint2* __restrict__ parts, const int* __restrict__ pcur,
    int* __restrict__ rowptr, int* __restrict__ seidx,
    int DPP, int nparts, int gb) {
  __shared__ PlaceSmem sm;
  if ((int)blockIdx.x < gb) {
    gemm_mfma_body<128>(X, Wf, atts, attd, XLh, a_s, a_d, N, blockIdx.x);
    return;
  }
  const int p = (int)blockIdx.x - gb;
  const int t = threadIdx.x;
  // inline scan of partition counts
  sm.sc[t] = min(pcur[t], PCAP);
  __syncthreads();
  for (int o = 1; o < NPARTS; o <<= 1) {
    int x = (t >= o) ? sm.sc[t - o] : 0;
    __syncthreads();
    sm.sc[t] += x;
    __syncthreads();
  }
  const int base = (p == 0) ? 0 : sm.sc[p - 1];
  const int n = sm.sc[p] - base;
  const int d0 = p * DPP;
  const int ndst = min(DPP, N - d0);
  const uint2* pe = parts + (size_t)p * PCAP;

  for (int i = t; i < ndst; i += 256) sm.l_cnt[i] = 0;
  __syncthreads();
  for (int i = t; i < n; i += 256) {
    uint2 e = pe[i];
    atomicAdd(&sm.l_cnt[(int)e.y - d0], 1);
  }
  __syncthreads();
  if (t == 0) {
    int run = 0;
    for (int i = 0; i < ndst; ++i) { sm.l_off[i] = run; run += sm.l_cnt[i]; }
  }
  __syncthreads();
  for (int i = t; i < ndst; i += 256) {
    rowptr[d0 + i] = base + sm.l_off[i];
    sm.l_cnt[i] = sm.l_off[i];
  }
  if (p == nparts - 1 && t == 0) rowptr[N] = sm.sc[nparts - 1];
  __syncthreads();
  for (int i = t; i < n; i += 256) {
    uint2 e = pe[i];
    int pos = atomicAdd(&sm.l_cnt[(int)e.y - d0], 1);
    sm.l_out[pos] = (int)e.x;
  }
  __syncthreads();
  for (int i = t; i < n; i += 256)
    seidx[base + i] = sm.l_out[i];
}

__global__ __launch_bounds__(256) void k_gemm_l2(
    const float* __restrict__ X, const _Float16* __restrict__ Wf,
    const float* __restrict__ atts, const float* __restrict__ attd,
    __half* __restrict__ XLh, float* __restrict__ a_s, float* __restrict__ a_d,
    int N) {
  gemm_mfma_body<64>(X, Wf, atts, attd, XLh, a_s, a_d, N, blockIdx.x);
}

// ---------------- aggr layer 1 (C=128): readlane broadcast gather -----------
__global__ __launch_bounds__(256) void k_aggr_l1(
    const __half* __restrict__ XLh, const float* __restrict__ as_,
    const float* __restrict__ ad_, const int* __restrict__ rowptr,
    const int* __restrict__ seidx, const int* __restrict__ ovf,
    const int* __restrict__ ovf_cnt, const float* __restrict__ bias,
    float* __restrict__ OUT, int N) {
  constexpr int C = 128;
  const int lane = threadIdx.x & 63;
  const int wid = threadIdx.x >> 6;
  const int novf = *ovf_cnt;  // 0 in practice
  const float bb0 = bias[lane * 2], bb1 = bias[lane * 2 + 1];

  for (int d = blockIdx.x * 4 + wid; d < N; d += gridDim.x * 4) {
    const int beg = rowptr[d], end = rowptr[d + 1];
    const int nb = end - beg;
    const float adst = ad_[d];

    float s;
    int sv = 0; float ev = 0.f;
    if (nb <= 64) {
      if (lane < nb) {
        sv = seidx[beg + lane];
        float t = as_[sv] + adst;
        t = t > 0.f ? t : 0.2f * t;
        ev = __expf(t);
      }
      s = ev;
    } else {
      s = 0.f;
      for (int i = beg + lane; i < end; i += 64) {
        int s2 = seidx[i];
        float t = as_[s2] + adst;
        t = t > 0.f ? t : 0.2f * t;
        s += __expf(t);
      }
    }
#pragma unroll
    for (int o = 32; o; o >>= 1) s += __shfl_xor(s, o);

    if (novf > 0) {
      float so = 0.f;
      for (int i = lane; i < novf; i += 64) {
        if (ovf[2 * i] == d) {
          float t = as_[ovf[2 * i + 1]] + adst;
          t = t > 0.f ? t : 0.2f * t;
          so += __expf(t);
        }
      }
#pragma unroll
      for (int o = 32; o; o >>= 1) so += __shfl_xor(so, o);
      s += so;
    }
    const float inv = 1.f / (s + 1e-16f);

    float2 acc = make_float2(0.f, 0.f);
    if (nb <= 64) {
      const float wv = ev * inv;
      auto body = [&](int j) {
        int sj = bcasti(sv, j);       // -> SGPR: scalar addr + saddr load
        float wj = bcastf(wv, j);
        const __half2* rp = (const __half2*)(XLh + (size_t)sj * C) + lane;
        float2 xv = __half22float2(*rp);
        acc.x = fmaf(wj, xv.x, acc.x);
        acc.y = fmaf(wj, xv.y, acc.y);
      };
      int j = 0;
      for (; j + 4 <= nb; j += 4) { body(j); body(j + 1); body(j + 2); body(j + 3); }
      for (; j < nb; ++j) body(j);
    } else {
      for (int i0 = beg; i0 < end; i0 += 64) {
        const int nc = min(64, end - i0);
        int sc = 0; float wc = 0.f;
        if (lane < nc) {
          sc = seidx[i0 + lane];
          float t = as_[sc] + adst;
          t = t > 0.f ? t : 0.2f * t;
          wc = __expf(t) * inv;
        }
        for (int j = 0; j < nc; ++j) {
          int sj = bcasti(sc, j);
          float wj = bcastf(wc, j);
          const __half2* rp = (const __half2*)(XLh + (size_t)sj * C) + lane;
          float2 xv = __half22float2(*rp);
          acc.x = fmaf(wj, xv.x, acc.x);
          acc.y = fmaf(wj, xv.y, acc.y);
        }
      }
    }

    if (novf > 0) {
      for (int i = 0; i < novf; ++i) {
        if (ovf[2 * i] != d) continue;
        int os = ovf[2 * i + 1];
        float t = as_[os] + adst;
        t = t > 0.f ? t : 0.2f * t;
        float wj = __expf(t) * inv;
        const __half2* rp = (const __half2*)(XLh + (size_t)os * C) + lane;
        float2 xv = __half22float2(*rp);
        acc.x = fmaf(wj, xv.x, acc.x);
        acc.y = fmaf(wj, xv.y, acc.y);
      }
    }

    float o0 = acc.x + bb0;
    float o1 = acc.y + bb1;
    o0 = o0 > 0.f ? o0 : 0.01f * o0;   // leaky relu between layers
    o1 = o1 > 0.f ? o1 : 0.01f * o1;
    *(float2*)&OUT[(size_t)d * C + lane * 2] = make_float2(o0, o1);
  }
}

// ---------------- aggr layer 2 (C=64): dual-edge + fused column sums --------
__global__ __launch_bounds__(256) void k_aggr2(
    const __half* __restrict__ XLh, const float* __restrict__ as_,
    const float* __restrict__ ad_, const int* __restrict__ rowptr,
    const int* __restrict__ seidx, const int* __restrict__ ovf,
    const int* __restrict__ ovf_cnt, const float* __restrict__ bias,
    float* __restrict__ OUT, float* __restrict__ csum8, int N) {
  constexpr int C = 64;
  const int lane = threadIdx.x & 63;
  const int wid = threadIdx.x >> 6;
  const int grp = lane >> 5;         // half-wave group: which edge of the pair
  const int l5 = lane & 31;          // covers cols 2*l5, 2*l5+1
  const int novf = *ovf_cnt;
  const float bb0 = bias[2 * l5], bb1 = bias[2 * l5 + 1];
  float cs0 = 0.f, cs1 = 0.f;        // fused column exp-sums (lanes 0-31)

  for (int d = blockIdx.x * 4 + wid; d < N; d += gridDim.x * 4) {
    const int beg = rowptr[d], end = rowptr[d + 1];
    const int nb = end - beg;
    const float adst = ad_[d];

    if (nb <= 64) {
      int sv = 0; float ev = 0.f;
      if (lane < nb) {
        sv = seidx[beg + lane];
        float t = as_[sv] + adst;
        t = t > 0.f ? t : 0.2f * t;
        ev = __expf(t);
      }
      float s = ev;
#pragma unroll
      for (int o = 32; o; o >>= 1) s += __shfl_xor(s, o);
      if (novf > 0) {
        float so = 0.f;
        for (int i = lane; i < novf; i += 64) {
          if (ovf[2 * i] == d) {
            float t = as_[ovf[2 * i + 1]] + adst;
            t = t > 0.f ? t : 0.2f * t;
            so += __expf(t);
          }
        }
#pragma unroll
        for (int o = 32; o; o >>= 1) so += __shfl_xor(so, o);
        s += so;
      }
      const float inv = 1.f / (s + 1e-16f);
      const float wv = ev * inv;

      float ax = 0.f, ay = 0.f;
      const int nsteps = (nb + 1) >> 1;
      for (int j = 0; j < nsteps; ++j) {
        int sl = 2 * j + grp;            // group g takes edge 2j+g
        int sj = __shfl(sv, sl);
        float wj = __shfl(wv, sl);
        const __half2* rp = (const __half2*)(XLh + (size_t)sj * C) + l5;
        float2 xv = __half22float2(*rp);
        ax = fmaf(wj, xv.x, ax);
        ay = fmaf(wj, xv.y, ay);
      }
      ax += __shfl_xor(ax, 32);          // merge the two edge-groups
      ay += __shfl_xor(ay, 32);

      if (novf > 0) {                    // cold path, post-merge (both halves same)
        for (int i = 0; i < novf; ++i) {
          if (ovf[2 * i] != d) continue;
          int os = ovf[2 * i + 1];
          float t = as_[os] + adst;
          t = t > 0.f ? t : 0.2f * t;
          float wj = __expf(t) * inv;
          const __half2* rp = (const __half2*)(XLh + (size_t)os * C) + l5;
          float2 xv = __half22float2(*rp);
          ax = fmaf(wj, xv.x, ax);
          ay = fmaf(wj, xv.y, ay);
        }
      }
      if (grp == 0) {
        float o0 = ax + bb0;
        float o1 = ay + bb1;
        *(float2*)&OUT[(size_t)d * C + 2 * l5] = make_float2(o0, o1);
        cs0 += __expf(o0);
        cs1 += __expf(o1);
      }
    } else {
      // rare fallback (deg > 64): single-col layout
      float s = 0.f;
      for (int i = beg + lane; i < end; i += 64) {
        int s2 = seidx[i];
        float t = as_[s2] + adst;
        t = t > 0.f ? t : 0.2f * t;
        s += __expf(t);
      }
#pragma unroll
      for (int o = 32; o; o >>= 1) s += __shfl_xor(s, o);
      const float inv = 1.f / (s + 1e-16f);
      float acc0 = 0.f;
      for (int i0 = beg; i0 < end; i0 += 64) {
        const int nc = min(64, end - i0);
        int sc = 0; float wc = 0.f;
        if (lane < nc) {
          sc = seidx[i0 + lane];
          float t = as_[sc] + adst;
          t = t > 0.f ? t : 0.2f * t;
          wc = __expf(t) * inv;
        }
        for (int j = 0; j < nc; ++j) {
          int sj = bcasti(sc, j);
          float wj = bcastf(wc, j);
          acc0 = fmaf(wj, __half2float(XLh[(size_t)sj * C + lane]), acc0);
        }
      }
      float o0 = acc0 + bias[lane];
      OUT[(size_t)d * C + lane] = o0;
      atomicAdd(&csum8[(d & 7) * 64 + lane], __expf(o0));
    }
  }

  // block-level reduce of fused column sums -> one atomic per col per block
  __shared__ float csA[4][64];
  if (grp == 0) { csA[wid][2 * l5] = cs0; csA[wid][2 * l5 + 1] = cs1; }
  __syncthreads();
  if (threadIdx.x < 64) {
    float tot = csA[0][threadIdx.x] + csA[1][threadIdx.x] +
                csA[2][threadIdx.x] + csA[3][threadIdx.x];
    if (tot != 0.f)
      atomicAdd(&csum8[((int)blockIdx.x & 7) * 64 + (int)threadIdx.x], tot);
  }
}

// ---------------- normalize: OUT = exp(OUT)/colsum ----------------
__global__ void k_norm(float* __restrict__ O, const float* __restrict__ csum8,
                       size_t tot4) {
  __shared__ float cs[64];
  if (threadIdx.x < 64) {
    float s = 0.f;
#pragma unroll
    for (int r = 0; r < 8; ++r) s += csum8[r * 64 + (int)threadIdx.x];
    cs[threadIdx.x] = s;
  }
  __syncthreads();
  for (size_t i = blockIdx.x * (size_t)blockDim.x + threadIdx.x; i < tot4;
       i += (size_t)gridDim.x * blockDim.x) {
    float4 v = ((float4*)O)[i];
    int c0 = (int)((i * 4) & 63);
    v.x = __expf(v.x) / cs[c0];
    v.y = __expf(v.y) / cs[c0 + 1];
    v.z = __expf(v.z) / cs[c0 + 2];
    v.w = __expf(v.w) / cs[c0 + 3];
    ((float4*)O)[i] = v;
  }
}

// ---------------------------------------------------------------------------
extern "C" void kernel_launch(void* const* d_in, const int* in_sizes, int n_in,
                              void* d_out, int out_size, void* d_ws, size_t ws_size,
                              hipStream_t stream) {
  const float* x   = (const float*)d_in[0];
  const int*   ei  = (const int*)d_in[1];
  const float* W1  = (const float*)d_in[2];
  const float* as1 = (const float*)d_in[3];
  const float* ad1 = (const float*)d_in[4];
  const float* b1  = (const float*)d_in[5];
  const float* W2  = (const float*)d_in[6];
  const float* as2 = (const float*)d_in[7];
  const float* ad2 = (const float*)d_in[8];
  const float* b2  = (const float*)d_in[9];
  float* out = (float*)d_out;

  const int N = in_sizes[0] / 128;
  const int E = in_sizes[1] / 2;
  const int Etot = E + N;
  const int* srcA = ei;
  const int* dstA = ei + E;
  const int DPP = (N + NPARTS - 1) / NPARTS;          // 391
  const int nparts = (N + DPP - 1) / DPP;             // 256

  char* w = (char*)d_ws;
  auto take = [&](size_t bytes) -> void* {
    void* p = (void*)w;
    w += (bytes + 255) & ~(size_t)255;
    return p;
  };
  __half*    xlh   = (__half*)take((size_t)N * 128 * 2);  // layer-1 XL (fp16)
  __half*    xl2h  = (__half*)take((size_t)N * 64 * 2);   // layer-2 XL (fp16)
  float*     h     = (float*)take((size_t)N * 128 * 4);   // layer-1 output (fp32)
  float*     a_s   = (float*)take((size_t)N * 4);
  float*     a_d   = (float*)take((size_t)N * 4);
  int*       zeroB = (int*)take((size_t)(1 + NPARTS + 512) * 4); // ovf_cnt|pcur|csum8
  int*       ovf_cnt = zeroB;
  int*       pcur    = zeroB + 1;
  float*     csum8   = (float*)(zeroB + 1 + NPARTS);
  int*       rowptr = (int*)take((size_t)(N + 1) * 4);
  int*       seidx  = (int*)take((size_t)Etot * 4);
  int*       ovf    = (int*)take((size_t)Etot * 2 * 4);
  uint2*     parts  = (uint2*)take((size_t)NPARTS * PCAP * 8);
  _Float16*  wf1    = (_Float16*)take((size_t)8 * 4 * 64 * 8 * 2);
  _Float16*  wf2    = (_Float16*)take((size_t)4 * 4 * 64 * 8 * 2);

  hipMemsetAsync(zeroB, 0, (size_t)(1 + NPARTS + 512) * 4, stream);

  const int nch = (Etot + CHUNK - 1) / CHUNK;
  const int gb = (N + 63) / 64;

  k_build1<<<nch + 8, 256, 0, stream>>>(srcA, dstA, pcur, parts, ovf, ovf_cnt,
                                        W1, W2, wf1, wf2, E, N, DPP, nch, Etot);
  k_gemm1_place<<<gb + NPARTS, 256, 0, stream>>>(
      x, wf1, as1, ad1, xlh, a_s, a_d, N, parts, pcur, rowptr, seidx,
      DPP, nparts, gb);
  k_aggr_l1<<<8192, 256, 0, stream>>>(xlh, a_s, a_d, rowptr, seidx, ovf, ovf_cnt,
                                      b1, h, N);
  k_gemm_l2<<<gb, 256, 0, stream>>>(h, wf2, as2, ad2, xl2h, a_s, a_d, N);
  k_aggr2<<<4096, 256, 0, stream>>>(xl2h, a_s, a_d, rowptr, seidx, ovf, ovf_cnt,
                                    b2, out, csum8, N);
  const size_t tot4 = (size_t)N * 64 / 4;
  k_norm<<<2048, 256, 0, stream>>>(out, csum8, tot4);
}

// Round 11
// 234.818 us; speedup vs baseline: 1.7860x; 1.0317x over previous
//
#include <hip/hip_runtime.h>
#include <hip/hip_fp16.h>
#include <math.h>

// ---------------------------------------------------------------------------
// GAT 2-layer network. MFMA fp16 GEMMs (fp32 accum); fp16 gathered features;
// max-free edge softmax; CSR via binned counting-sort. Fused kernels:
//  K1=[edge binning || W fragment prep], K2=[gemm_l1 || CSR place(+scan)],
//  aggr2 fuses the column-softmax sum (8-replica atomics).
// N=100000, E=1600000 (+N self-loops), d_in=h1=128, h2=64.
// ---------------------------------------------------------------------------

constexpr int NPARTS = 256;   // fixed-width dst partitions
constexpr int PCAP = 8192;    // entries per partition (avg 6640, +19 sigma)
constexpr int CHUNK = 4096;   // edges per phase-A block-chunk
constexpr int DPPMAX = 400;   // max dsts per partition

typedef _Float16 f16x8 __attribute__((ext_vector_type(8)));
typedef float f32x4 __attribute__((ext_vector_type(4)));

__device__ __forceinline__ int bcasti(int v, int j) {
  return __builtin_amdgcn_readlane(v, j);
}
__device__ __forceinline__ float bcastf(float v, int j) {
  return __uint_as_float((unsigned)__builtin_amdgcn_readlane((int)__float_as_uint(v), j));
}

// ---------------- K1: edge binning (blocks < nch) || W-prep (last 8) --------
__global__ __launch_bounds__(256) void k_build1(
    const int* __restrict__ srcA, const int* __restrict__ dstA,
    int* __restrict__ pcur, uint2* __restrict__ parts,
    int* __restrict__ ovf, int* __restrict__ ovf_cnt,
    const float* __restrict__ W1, const float* __restrict__ W2,
    _Float16* __restrict__ Wf1, _Float16* __restrict__ Wf2,
    int E, int N, int DPP, int nch, int ovfcap) {
  if ((int)blockIdx.x >= nch) {
    // W fragment prep:
    // Wf[((cb*4+kk)*64+l)*8+j] = W[(kk*32+(l>>4)*8+j)*C + cb*16 + (l&15)]
    int t = ((int)blockIdx.x - nch) * 256 + (int)threadIdx.x;
    const int stride = 8 * 256;
    for (int i = t; i < 8 * 4 * 64 * 8; i += stride) {
      int j = i & 7, l = (i >> 3) & 63, kk = (i >> 9) & 3, cb = i >> 11;
      int k = kk * 32 + (l >> 4) * 8 + j, c = cb * 16 + (l & 15);
      Wf1[i] = (_Float16)W1[k * 128 + c];
    }
    for (int i = t; i < 4 * 4 * 64 * 8; i += stride) {
      int j = i & 7, l = (i >> 3) & 63, kk = (i >> 9) & 3, cb = i >> 11;
      int k = kk * 32 + (l >> 4) * 8 + j, c = cb * 16 + (l & 15);
      Wf2[i] = (_Float16)W2[k * 64 + c];
    }
    return;
  }
  __shared__ int hist[NPARTS];
  __shared__ int base[NPARTS];
  const int tot = E + N;
  const int c = blockIdx.x;
  hist[threadIdx.x] = 0;
  __syncthreads();
  const int beg = c * CHUNK;
  int pp[16], rr[16], ss[16], dd[16];
#pragma unroll
  for (int j = 0; j < 16; ++j) {
    int e = beg + j * 256 + (int)threadIdx.x;
    int d = -1, s = 0;
    if (e < tot) {
      if (e < E) { d = dstA[e]; s = srcA[e]; } else { d = s = e - E; }
    }
    dd[j] = d; ss[j] = s;
    int p = (d >= 0) ? (d / DPP) : -1;
    pp[j] = p;
    rr[j] = (p >= 0) ? atomicAdd(&hist[p], 1) : 0;
  }
  __syncthreads();
  base[threadIdx.x] = atomicAdd(&pcur[threadIdx.x], hist[threadIdx.x]);
  __syncthreads();
#pragma unroll
  for (int j = 0; j < 16; ++j) {
    int p = pp[j];
    if (p < 0) continue;
    int pos = base[p] + rr[j];
    if (pos < PCAP) {
      parts[(size_t)p * PCAP + pos] = make_uint2((unsigned)ss[j], (unsigned)dd[j]);
    } else {
      int o = atomicAdd(ovf_cnt, 1);
      if (o < ovfcap) { ovf[2 * o] = dd[j]; ovf[2 * o + 1] = ss[j]; }
    }
  }
}

// ---------------- MFMA GEMM body (16 rows/wave, K=128) ----------------------
template <int C>
__device__ __forceinline__ void gemm_mfma_body(
    const float* __restrict__ X, const _Float16* __restrict__ Wf,
    const float* __restrict__ atts, const float* __restrict__ attd,
    __half* __restrict__ XLh, float* __restrict__ a_s, float* __restrict__ a_d,
    int N, int bid) {
  constexpr int NCB = C / 16;
  const int lane = threadIdx.x & 63;
  const int wv = threadIdx.x >> 6;
  const int r0 = bid * 64 + wv * 16;
  const int arow = lane & 15;
  const int grp = lane >> 4;
  const int r = r0 + arow;
  const int rsafe = (r < N) ? r : (N - 1);

  float av[NCB], dv[NCB];
#pragma unroll
  for (int cb = 0; cb < NCB; ++cb) {
    av[cb] = atts[cb * 16 + arow];
    dv[cb] = attd[cb * 16 + arow];
  }

  f16x8 af[4];
  const float* xr = X + (size_t)rsafe * 128 + grp * 8;
#pragma unroll
  for (int kk = 0; kk < 4; ++kk) {
    float4 u0 = *(const float4*)(xr + kk * 32);
    float4 u1 = *(const float4*)(xr + kk * 32 + 4);
    af[kk][0] = (_Float16)u0.x; af[kk][1] = (_Float16)u0.y;
    af[kk][2] = (_Float16)u0.z; af[kk][3] = (_Float16)u0.w;
    af[kk][4] = (_Float16)u1.x; af[kk][5] = (_Float16)u1.y;
    af[kk][6] = (_Float16)u1.z; af[kk][7] = (_Float16)u1.w;
  }

  float ps[4] = {0.f, 0.f, 0.f, 0.f};
  float pd[4] = {0.f, 0.f, 0.f, 0.f};

#pragma unroll
  for (int cb = 0; cb < NCB; ++cb) {
    f32x4 acc = {0.f, 0.f, 0.f, 0.f};
#pragma unroll
    for (int kk = 0; kk < 4; ++kk) {
      f16x8 bf = *(const f16x8*)(Wf + ((size_t)(cb * 4 + kk) * 64 + lane) * 8);
      acc = __builtin_amdgcn_mfma_f32_16x16x32_f16(af[kk], bf, acc, 0, 0, 0);
    }
    const int ocol = cb * 16 + arow;
#pragma unroll
    for (int i = 0; i < 4; ++i) {
      const int orow = r0 + grp * 4 + i;
      if (orow < N) XLh[(size_t)orow * C + ocol] = (__half)(_Float16)acc[i];
      ps[i] = fmaf(acc[i], av[cb], ps[i]);
      pd[i] = fmaf(acc[i], dv[cb], pd[i]);
    }
  }
#pragma unroll
  for (int m = 1; m < 16; m <<= 1) {
#pragma unroll
    for (int i = 0; i < 4; ++i) {
      ps[i] += __shfl_xor(ps[i], m);
      pd[i] += __shfl_xor(pd[i], m);
    }
  }
  if (arow == 0) {
#pragma unroll
    for (int i = 0; i < 4; ++i) {
      const int orow = r0 + grp * 4 + i;
      if (orow < N) { a_s[orow] = ps[i]; a_d[orow] = pd[i]; }
    }
  }
}

// ---------------- K2: gemm_l1 (blocks < gb) || CSR place+scan (last 256) ----
struct PlaceSmem {
  int sc[NPARTS];
  int l_cnt[DPPMAX];
  int l_off[DPPMAX];
  int l_out[PCAP];
};

__global__ __launch_bounds__(256) void k_gemm1_place(
    const float* __restrict__ X, const _Float16* __restrict__ Wf,
    const float* __restrict__ atts, const float* __restrict__ attd,
    __half* __restrict__ XLh, float* __restrict__ a_s, float* __restrict__ a_d,
    int N, const uint2* __restrict__ parts, const int* __restrict__ pcur,
    int* __restrict__ rowptr, int* __restrict__ seidx,
    int DPP, int nparts, int gb) {
  __shared__ PlaceSmem sm;
  if ((int)blockIdx.x < gb) {
    gemm_mfma_body<128>(X, Wf, atts, attd, XLh, a_s, a_d, N, blockIdx.x);
    return;
  }
  const int p = (int)blockIdx.x - gb;
  const int t = threadIdx.x;
  // inline scan of partition counts
  sm.sc[t] = min(pcur[t], PCAP);
  __syncthreads();
  for (int o = 1; o < NPARTS; o <<= 1) {
    int x = (t >= o) ? sm.sc[t - o] : 0;
    __syncthreads();
    sm.sc[t] += x;
    __syncthreads();
  }
  const int base = (p == 0) ? 0 : sm.sc[p - 1];
  const int n = sm.sc[p] - base;
  const int d0 = p * DPP;
  const int ndst = min(DPP, N - d0);
  const uint2* pe = parts + (size_t)p * PCAP;

  for (int i = t; i < ndst; i += 256) sm.l_cnt[i] = 0;
  __syncthreads();
  for (int i = t; i < n; i += 256) {
    uint2 e = pe[i];
    atomicAdd(&sm.l_cnt[(int)e.y - d0], 1);
  }
  __syncthreads();
  if (t == 0) {
    int run = 0;
    for (int i = 0; i < ndst; ++i) { sm.l_off[i] = run; run += sm.l_cnt[i]; }
  }
  __syncthreads();
  for (int i = t; i < ndst; i += 256) {
    rowptr[d0 + i] = base + sm.l_off[i];
    sm.l_cnt[i] = sm.l_off[i];
  }
  if (p == nparts - 1 && t == 0) rowptr[N] = sm.sc[nparts - 1];
  __syncthreads();
  for (int i = t; i < n; i += 256) {
    uint2 e = pe[i];
    int pos = atomicAdd(&sm.l_cnt[(int)e.y - d0], 1);
    sm.l_out[pos] = (int)e.x;
  }
  __syncthreads();
  for (int i = t; i < n; i += 256)
    seidx[base + i] = sm.l_out[i];
}

__global__ __launch_bounds__(256) void k_gemm_l2(
    const float* __restrict__ X, const _Float16* __restrict__ Wf,
    const float* __restrict__ atts, const float* __restrict__ attd,
    __half* __restrict__ XLh, float* __restrict__ a_s, float* __restrict__ a_d,
    int N) {
  gemm_mfma_body<64>(X, Wf, atts, attd, XLh, a_s, a_d, N, blockIdx.x);
}

// ---------------- aggr layer 1 (C=128): readlane broadcast gather -----------
__global__ __launch_bounds__(256) void k_aggr_l1(
    const __half* __restrict__ XLh, const float* __restrict__ as_,
    const float* __restrict__ ad_, const int* __restrict__ rowptr,
    const int* __restrict__ seidx, const int* __restrict__ ovf,
    const int* __restrict__ ovf_cnt, const float* __restrict__ bias,
    float* __restrict__ OUT, int N) {
  constexpr int C = 128;
  const int lane = threadIdx.x & 63;
  const int wid = threadIdx.x >> 6;
  const int novf = *ovf_cnt;  // 0 in practice
  const float bb0 = bias[lane * 2], bb1 = bias[lane * 2 + 1];

  for (int d = blockIdx.x * 4 + wid; d < N; d += gridDim.x * 4) {
    const int beg = rowptr[d], end = rowptr[d + 1];
    const int nb = end - beg;
    const float adst = ad_[d];

    float s;
    int sv = 0; float ev = 0.f;
    if (nb <= 64) {
      if (lane < nb) {
        sv = seidx[beg + lane];
        float t = as_[sv] + adst;
        t = t > 0.f ? t : 0.2f * t;
        ev = __expf(t);
      }
      s = ev;
    } else {
      s = 0.f;
      for (int i = beg + lane; i < end; i += 64) {
        int s2 = seidx[i];
        float t = as_[s2] + adst;
        t = t > 0.f ? t : 0.2f * t;
        s += __expf(t);
      }
    }
#pragma unroll
    for (int o = 32; o; o >>= 1) s += __shfl_xor(s, o);

    if (novf > 0) {
      float so = 0.f;
      for (int i = lane; i < novf; i += 64) {
        if (ovf[2 * i] == d) {
          float t = as_[ovf[2 * i + 1]] + adst;
          t = t > 0.f ? t : 0.2f * t;
          so += __expf(t);
        }
      }
#pragma unroll
      for (int o = 32; o; o >>= 1) so += __shfl_xor(so, o);
      s += so;
    }
    const float inv = 1.f / (s + 1e-16f);

    float2 acc = make_float2(0.f, 0.f);
    if (nb <= 64) {
      const float wv = ev * inv;
      auto body = [&](int j) {
        int sj = bcasti(sv, j);       // -> SGPR: scalar addr + saddr load
        float wj = bcastf(wv, j);
        const __half2* rp = (const __half2*)(XLh + (size_t)sj * C) + lane;
        float2 xv = __half22float2(*rp);
        acc.x = fmaf(wj, xv.x, acc.x);
        acc.y = fmaf(wj, xv.y, acc.y);
      };
      int j = 0;
      for (; j + 4 <= nb; j += 4) { body(j); body(j + 1); body(j + 2); body(j + 3); }
      for (; j < nb; ++j) body(j);
    } else {
      for (int i0 = beg; i0 < end; i0 += 64) {
        const int nc = min(64, end - i0);
        int sc = 0; float wc = 0.f;
        if (lane < nc) {
          sc = seidx[i0 + lane];
          float t = as_[sc] + adst;
          t = t > 0.f ? t : 0.2f * t;
          wc = __expf(t) * inv;
        }
        for (int j = 0; j < nc; ++j) {
          int sj = bcasti(sc, j);
          float wj = bcastf(wc, j);
          const __half2* rp = (const __half2*)(XLh + (size_t)sj * C) + lane;
          float2 xv = __half22float2(*rp);
          acc.x = fmaf(wj, xv.x, acc.x);
          acc.y = fmaf(wj, xv.y, acc.y);
        }
      }
    }

    if (novf > 0) {
      for (int i = 0; i < novf; ++i) {
        if (ovf[2 * i] != d) continue;
        int os = ovf[2 * i + 1];
        float t = as_[os] + adst;
        t = t > 0.f ? t : 0.2f * t;
        float wj = __expf(t) * inv;
        const __half2* rp = (const __half2*)(XLh + (size_t)os * C) + lane;
        float2 xv = __half22float2(*rp);
        acc.x = fmaf(wj, xv.x, acc.x);
        acc.y = fmaf(wj, xv.y, acc.y);
      }
    }

    float o0 = acc.x + bb0;
    float o1 = acc.y + bb1;
    o0 = o0 > 0.f ? o0 : 0.01f * o0;   // leaky relu between layers
    o1 = o1 > 0.f ? o1 : 0.01f * o1;
    *(float2*)&OUT[(size_t)d * C + lane * 2] = make_float2(o0, o1);
  }
}

// -------- aggr layer 2 (C=64): readlane gather + fused column sums ---------
__global__ __launch_bounds__(256) void k_aggr2(
    const __half* __restrict__ XLh, const float* __restrict__ as_,
    const float* __restrict__ ad_, const int* __restrict__ rowptr,
    const int* __restrict__ seidx, const int* __restrict__ ovf,
    const int* __restrict__ ovf_cnt, const float* __restrict__ bias,
    float* __restrict__ OUT, float* __restrict__ csum8, int N) {
  constexpr int C = 64;
  const int lane = threadIdx.x & 63;
  const int wid = threadIdx.x >> 6;
  const int novf = *ovf_cnt;
  const float bb = bias[lane];
  float cs = 0.f;                      // fused column exp-sum (lane owns col)

  for (int d = blockIdx.x * 4 + wid; d < N; d += gridDim.x * 4) {
    const int beg = rowptr[d], end = rowptr[d + 1];
    const int nb = end - beg;
    const float adst = ad_[d];

    float s;
    int sv = 0; float ev = 0.f;
    if (nb <= 64) {
      if (lane < nb) {
        sv = seidx[beg + lane];
        float t = as_[sv] + adst;
        t = t > 0.f ? t : 0.2f * t;
        ev = __expf(t);
      }
      s = ev;
    } else {
      s = 0.f;
      for (int i = beg + lane; i < end; i += 64) {
        int s2 = seidx[i];
        float t = as_[s2] + adst;
        t = t > 0.f ? t : 0.2f * t;
        s += __expf(t);
      }
    }
#pragma unroll
    for (int o = 32; o; o >>= 1) s += __shfl_xor(s, o);

    if (novf > 0) {
      float so = 0.f;
      for (int i = lane; i < novf; i += 64) {
        if (ovf[2 * i] == d) {
          float t = as_[ovf[2 * i + 1]] + adst;
          t = t > 0.f ? t : 0.2f * t;
          so += __expf(t);
        }
      }
#pragma unroll
      for (int o = 32; o; o >>= 1) so += __shfl_xor(so, o);
      s += so;
    }
    const float inv = 1.f / (s + 1e-16f);

    float acc0 = 0.f;
    if (nb <= 64) {
      const float wv = ev * inv;
      auto body = [&](int j) {
        int sj = bcasti(sv, j);
        float wj = bcastf(wv, j);
        acc0 = fmaf(wj, __half2float(XLh[(size_t)sj * C + lane]), acc0);
      };
      int j = 0;
      for (; j + 4 <= nb; j += 4) { body(j); body(j + 1); body(j + 2); body(j + 3); }
      for (; j < nb; ++j) body(j);
    } else {
      for (int i0 = beg; i0 < end; i0 += 64) {
        const int nc = min(64, end - i0);
        int sc = 0; float wc = 0.f;
        if (lane < nc) {
          sc = seidx[i0 + lane];
          float t = as_[sc] + adst;
          t = t > 0.f ? t : 0.2f * t;
          wc = __expf(t) * inv;
        }
        for (int j = 0; j < nc; ++j) {
          int sj = bcasti(sc, j);
          float wj = bcastf(wc, j);
          acc0 = fmaf(wj, __half2float(XLh[(size_t)sj * C + lane]), acc0);
        }
      }
    }

    if (novf > 0) {
      for (int i = 0; i < novf; ++i) {
        if (ovf[2 * i] != d) continue;
        int os = ovf[2 * i + 1];
        float t = as_[os] + adst;
        t = t > 0.f ? t : 0.2f * t;
        float wj = __expf(t) * inv;
        acc0 = fmaf(wj, __half2float(XLh[(size_t)os * C + lane]), acc0);
      }
    }

    float o0 = acc0 + bb;
    OUT[(size_t)d * C + lane] = o0;
    cs += __expf(o0);
  }

  // block-level reduce of fused column sums -> one atomic per col per block
  __shared__ float csA[4][64];
  csA[wid][lane] = cs;
  __syncthreads();
  if (threadIdx.x < 64) {
    float tot = csA[0][threadIdx.x] + csA[1][threadIdx.x] +
                csA[2][threadIdx.x] + csA[3][threadIdx.x];
    if (tot != 0.f)
      atomicAdd(&csum8[((int)blockIdx.x & 7) * 64 + (int)threadIdx.x], tot);
  }
}

// ---------------- normalize: OUT = exp(OUT)/colsum ----------------
__global__ void k_norm(float* __restrict__ O, const float* __restrict__ csum8,
                       size_t tot4) {
  __shared__ float cs[64];
  if (threadIdx.x < 64) {
    float s = 0.f;
#pragma unroll
    for (int r = 0; r < 8; ++r) s += csum8[r * 64 + (int)threadIdx.x];
    cs[threadIdx.x] = s;
  }
  __syncthreads();
  for (size_t i = blockIdx.x * (size_t)blockDim.x + threadIdx.x; i < tot4;
       i += (size_t)gridDim.x * blockDim.x) {
    float4 v = ((float4*)O)[i];
    int c0 = (int)((i * 4) & 63);
    v.x = __expf(v.x) / cs[c0];
    v.y = __expf(v.y) / cs[c0 + 1];
    v.z = __expf(v.z) / cs[c0 + 2];
    v.w = __expf(v.w) / cs[c0 + 3];
    ((float4*)O)[i] = v;
  }
}

// ---------------------------------------------------------------------------
extern "C" void kernel_launch(void* const* d_in, const int* in_sizes, int n_in,
                              void* d_out, int out_size, void* d_ws, size_t ws_size,
                              hipStream_t stream) {
  const float* x   = (const float*)d_in[0];
  const int*   ei  = (const int*)d_in[1];
  const float* W1  = (const float*)d_in[2];
  const float* as1 = (const float*)d_in[3];
  const float* ad1 = (const float*)d_in[4];
  const float* b1  = (const float*)d_in[5];
  const float* W2  = (const float*)d_in[6];
  const float* as2 = (const float*)d_in[7];
  const float* ad2 = (const float*)d_in[8];
  const float* b2  = (const float*)d_in[9];
  float* out = (float*)d_out;

  const int N = in_sizes[0] / 128;
  const int E = in_sizes[1] / 2;
  const int Etot = E + N;
  const int* srcA = ei;
  const int* dstA = ei + E;
  const int DPP = (N + NPARTS - 1) / NPARTS;          // 391
  const int nparts = (N + DPP - 1) / DPP;             // 256

  char* w = (char*)d_ws;
  auto take = [&](size_t bytes) -> void* {
    void* p = (void*)w;
    w += (bytes + 255) & ~(size_t)255;
    return p;
  };
  __half*    xlh   = (__half*)take((size_t)N * 128 * 2);  // layer-1 XL (fp16)
  __half*    xl2h  = (__half*)take((size_t)N * 64 * 2);   // layer-2 XL (fp16)
  float*     h     = (float*)take((size_t)N * 128 * 4);   // layer-1 output (fp32)
  float*     a_s   = (float*)take((size_t)N * 4);
  float*     a_d   = (float*)take((size_t)N * 4);
  int*       zeroB = (int*)take((size_t)(1 + NPARTS + 512) * 4); // ovf_cnt|pcur|csum8
  int*       ovf_cnt = zeroB;
  int*       pcur    = zeroB + 1;
  float*     csum8   = (float*)(zeroB + 1 + NPARTS);
  int*       rowptr = (int*)take((size_t)(N + 1) * 4);
  int*       seidx  = (int*)take((size_t)Etot * 4);
  int*       ovf    = (int*)take((size_t)Etot * 2 * 4);
  uint2*     parts  = (uint2*)take((size_t)NPARTS * PCAP * 8);
  _Float16*  wf1    = (_Float16*)take((size_t)8 * 4 * 64 * 8 * 2);
  _Float16*  wf2    = (_Float16*)take((size_t)4 * 4 * 64 * 8 * 2);

  hipMemsetAsync(zeroB, 0, (size_t)(1 + NPARTS + 512) * 4, stream);

  const int nch = (Etot + CHUNK - 1) / CHUNK;
  const int gb = (N + 63) / 64;

  k_build1<<<nch + 8, 256, 0, stream>>>(srcA, dstA, pcur, parts, ovf, ovf_cnt,
                                        W1, W2, wf1, wf2, E, N, DPP, nch, Etot);
  k_gemm1_place<<<gb + NPARTS, 256, 0, stream>>>(
      x, wf1, as1, ad1, xlh, a_s, a_d, N, parts, pcur, rowptr, seidx,
      DPP, nparts, gb);
  k_aggr_l1<<<8192, 256, 0, stream>>>(xlh, a_s, a_d, rowptr, seidx, ovf, ovf_cnt,
                                      b1, h, N);
  k_gemm_l2<<<gb, 256, 0, stream>>>(h, wf2, as2, ad2, xl2h, a_s, a_d, N);
  k_aggr2<<<8192, 256, 0, stream>>>(xl2h, a_s, a_d, rowptr, seidx, ovf, ovf_cnt,
                                    b2, out, csum8, N);
  const size_t tot4 = (size_t)N * 64 / 4;
  k_norm<<<2048, 256, 0, stream>>>(out, csum8, tot4);
}

// Round 12
// 225.305 us; speedup vs baseline: 1.8614x; 1.0422x over previous
//
#include <hip/hip_runtime.h>
#include <hip/hip_fp16.h>
#include <math.h>

// ---------------------------------------------------------------------------
// GAT 2-layer network. MFMA fp16 GEMMs (fp32 accum); fp16 gathered features;
// max-free edge softmax; CSR via binned counting-sort. Dual-edge gathers:
// two edges' (src,weight) broadcast via uniform readlane (SGPR), half-wave
// selects its edge with one cndmask -> 8B/lane loads, no bpermute.
// h stored fp16 (gemm_l2 rounds to fp16 anyway -> zero extra error).
// N=100000, E=1600000 (+N self-loops), d_in=h1=128, h2=64.
// ---------------------------------------------------------------------------

constexpr int NPARTS = 256;   // fixed-width dst partitions
constexpr int PCAP = 8192;    // entries per partition (avg 6640, +19 sigma)
constexpr int CHUNK = 4096;   // edges per phase-A block-chunk
constexpr int DPPMAX = 400;   // max dsts per partition

typedef _Float16 f16x8 __attribute__((ext_vector_type(8)));
typedef float f32x4 __attribute__((ext_vector_type(4)));

__device__ __forceinline__ int bcasti(int v, int j) {
  return __builtin_amdgcn_readlane(v, j);
}
__device__ __forceinline__ float bcastf(float v, int j) {
  return __uint_as_float((unsigned)__builtin_amdgcn_readlane((int)__float_as_uint(v), j));
}

// ---------------- K1: edge binning (blocks < nch) || W-prep (last 8) --------
__global__ __launch_bounds__(256) void k_build1(
    const int* __restrict__ srcA, const int* __restrict__ dstA,
    int* __restrict__ pcur, uint2* __restrict__ parts,
    int* __restrict__ ovf, int* __restrict__ ovf_cnt,
    const float* __restrict__ W1, const float* __restrict__ W2,
    _Float16* __restrict__ Wf1, _Float16* __restrict__ Wf2,
    int E, int N, int DPP, int nch, int ovfcap) {
  if ((int)blockIdx.x >= nch) {
    int t = ((int)blockIdx.x - nch) * 256 + (int)threadIdx.x;
    const int stride = 8 * 256;
    for (int i = t; i < 8 * 4 * 64 * 8; i += stride) {
      int j = i & 7, l = (i >> 3) & 63, kk = (i >> 9) & 3, cb = i >> 11;
      int k = kk * 32 + (l >> 4) * 8 + j, c = cb * 16 + (l & 15);
      Wf1[i] = (_Float16)W1[k * 128 + c];
    }
    for (int i = t; i < 4 * 4 * 64 * 8; i += stride) {
      int j = i & 7, l = (i >> 3) & 63, kk = (i >> 9) & 3, cb = i >> 11;
      int k = kk * 32 + (l >> 4) * 8 + j, c = cb * 16 + (l & 15);
      Wf2[i] = (_Float16)W2[k * 64 + c];
    }
    return;
  }
  __shared__ int hist[NPARTS];
  __shared__ int base[NPARTS];
  const int tot = E + N;
  const int c = blockIdx.x;
  hist[threadIdx.x] = 0;
  __syncthreads();
  const int beg = c * CHUNK;
  int pp[16], rr[16], ss[16], dd[16];
#pragma unroll
  for (int j = 0; j < 16; ++j) {
    int e = beg + j * 256 + (int)threadIdx.x;
    int d = -1, s = 0;
    if (e < tot) {
      if (e < E) { d = dstA[e]; s = srcA[e]; } else { d = s = e - E; }
    }
    dd[j] = d; ss[j] = s;
    int p = (d >= 0) ? (d / DPP) : -1;
    pp[j] = p;
    rr[j] = (p >= 0) ? atomicAdd(&hist[p], 1) : 0;
  }
  __syncthreads();
  base[threadIdx.x] = atomicAdd(&pcur[threadIdx.x], hist[threadIdx.x]);
  __syncthreads();
#pragma unroll
  for (int j = 0; j < 16; ++j) {
    int p = pp[j];
    if (p < 0) continue;
    int pos = base[p] + rr[j];
    if (pos < PCAP) {
      parts[(size_t)p * PCAP + pos] = make_uint2((unsigned)ss[j], (unsigned)dd[j]);
    } else {
      int o = atomicAdd(ovf_cnt, 1);
      if (o < ovfcap) { ovf[2 * o] = dd[j]; ovf[2 * o + 1] = ss[j]; }
    }
  }
}

// ---------------- MFMA GEMM body (16 rows/wave, K=128) ----------------------
// XT=float (layer1) or __half (layer2: h already fp16, direct f16x8 loads).
template <int C, typename XT>
__device__ __forceinline__ void gemm_mfma_body(
    const XT* __restrict__ X, const _Float16* __restrict__ Wf,
    const float* __restrict__ atts, const float* __restrict__ attd,
    __half* __restrict__ XLh, float* __restrict__ a_s, float* __restrict__ a_d,
    int N, int bid) {
  constexpr int NCB = C / 16;
  const int lane = threadIdx.x & 63;
  const int wv = threadIdx.x >> 6;
  const int r0 = bid * 64 + wv * 16;
  const int arow = lane & 15;
  const int grp = lane >> 4;
  const int r = r0 + arow;
  const int rsafe = (r < N) ? r : (N - 1);

  float av[NCB], dv[NCB];
#pragma unroll
  for (int cb = 0; cb < NCB; ++cb) {
    av[cb] = atts[cb * 16 + arow];
    dv[cb] = attd[cb * 16 + arow];
  }

  f16x8 af[4];
  if constexpr (sizeof(XT) == 4) {
    const float* xr = (const float*)X + (size_t)rsafe * 128 + grp * 8;
#pragma unroll
    for (int kk = 0; kk < 4; ++kk) {
      float4 u0 = *(const float4*)(xr + kk * 32);
      float4 u1 = *(const float4*)(xr + kk * 32 + 4);
      af[kk][0] = (_Float16)u0.x; af[kk][1] = (_Float16)u0.y;
      af[kk][2] = (_Float16)u0.z; af[kk][3] = (_Float16)u0.w;
      af[kk][4] = (_Float16)u1.x; af[kk][5] = (_Float16)u1.y;
      af[kk][6] = (_Float16)u1.z; af[kk][7] = (_Float16)u1.w;
    }
  } else {
    const __half* xr = (const __half*)X + (size_t)rsafe * 128 + grp * 8;
#pragma unroll
    for (int kk = 0; kk < 4; ++kk)
      af[kk] = *(const f16x8*)(xr + kk * 32);
  }

  float ps[4] = {0.f, 0.f, 0.f, 0.f};
  float pd[4] = {0.f, 0.f, 0.f, 0.f};

#pragma unroll
  for (int cb = 0; cb < NCB; ++cb) {
    f32x4 acc = {0.f, 0.f, 0.f, 0.f};
#pragma unroll
    for (int kk = 0; kk < 4; ++kk) {
      f16x8 bf = *(const f16x8*)(Wf + ((size_t)(cb * 4 + kk) * 64 + lane) * 8);
      acc = __builtin_amdgcn_mfma_f32_16x16x32_f16(af[kk], bf, acc, 0, 0, 0);
    }
    const int ocol = cb * 16 + arow;
#pragma unroll
    for (int i = 0; i < 4; ++i) {
      const int orow = r0 + grp * 4 + i;
      if (orow < N) XLh[(size_t)orow * C + ocol] = (__half)(_Float16)acc[i];
      ps[i] = fmaf(acc[i], av[cb], ps[i]);
      pd[i] = fmaf(acc[i], dv[cb], pd[i]);
    }
  }
#pragma unroll
  for (int m = 1; m < 16; m <<= 1) {
#pragma unroll
    for (int i = 0; i < 4; ++i) {
      ps[i] += __shfl_xor(ps[i], m);
      pd[i] += __shfl_xor(pd[i], m);
    }
  }
  if (arow == 0) {
#pragma unroll
    for (int i = 0; i < 4; ++i) {
      const int orow = r0 + grp * 4 + i;
      if (orow < N) { a_s[orow] = ps[i]; a_d[orow] = pd[i]; }
    }
  }
}

// ---------------- K2: gemm_l1 (blocks < gb) || CSR place+scan (last 256) ----
struct PlaceSmem {
  int sc[NPARTS];
  int l_cnt[DPPMAX];
  int l_off[DPPMAX];
  int l_out[PCAP];
};

__global__ __launch_bounds__(256) void k_gemm1_place(
    const float* __restrict__ X, const _Float16* __restrict__ Wf,
    const float* __restrict__ atts, const float* __restrict__ attd,
    __half* __restrict__ XLh, float* __restrict__ a_s, float* __restrict__ a_d,
    int N, const uint2* __restrict__ parts, const int* __restrict__ pcur,
    int* __restrict__ rowptr, int* __restrict__ seidx,
    int DPP, int nparts, int gb) {
  __shared__ PlaceSmem sm;
  if ((int)blockIdx.x < gb) {
    gemm_mfma_body<128, float>(X, Wf, atts, attd, XLh, a_s, a_d, N, blockIdx.x);
    return;
  }
  const int p = (int)blockIdx.x - gb;
  const int t = threadIdx.x;
  sm.sc[t] = min(pcur[t], PCAP);
  __syncthreads();
  for (int o = 1; o < NPARTS; o <<= 1) {
    int x = (t >= o) ? sm.sc[t - o] : 0;
    __syncthreads();
    sm.sc[t] += x;
    __syncthreads();
  }
  const int base = (p == 0) ? 0 : sm.sc[p - 1];
  const int n = sm.sc[p] - base;
  const int d0 = p * DPP;
  const int ndst = min(DPP, N - d0);
  const uint2* pe = parts + (size_t)p * PCAP;

  for (int i = t; i < ndst; i += 256) sm.l_cnt[i] = 0;
  __syncthreads();
  for (int i = t; i < n; i += 256) {
    uint2 e = pe[i];
    atomicAdd(&sm.l_cnt[(int)e.y - d0], 1);
  }
  __syncthreads();
  if (t == 0) {
    int run = 0;
    for (int i = 0; i < ndst; ++i) { sm.l_off[i] = run; run += sm.l_cnt[i]; }
  }
  __syncthreads();
  for (int i = t; i < ndst; i += 256) {
    rowptr[d0 + i] = base + sm.l_off[i];
    sm.l_cnt[i] = sm.l_off[i];
  }
  if (p == nparts - 1 && t == 0) rowptr[N] = sm.sc[nparts - 1];
  __syncthreads();
  for (int i = t; i < n; i += 256) {
    uint2 e = pe[i];
    int pos = atomicAdd(&sm.l_cnt[(int)e.y - d0], 1);
    sm.l_out[pos] = (int)e.x;
  }
  __syncthreads();
  for (int i = t; i < n; i += 256)
    seidx[base + i] = sm.l_out[i];
}

__global__ __launch_bounds__(256) void k_gemm_l2(
    const __half* __restrict__ X, const _Float16* __restrict__ Wf,
    const float* __restrict__ atts, const float* __restrict__ attd,
    __half* __restrict__ XLh, float* __restrict__ a_s, float* __restrict__ a_d,
    int N) {
  gemm_mfma_body<64, __half>(X, Wf, atts, attd, XLh, a_s, a_d, N, blockIdx.x);
}

// -------- aggr layer 1 (C=128): dual-edge readlane gather, fp16 h out -------
__global__ __launch_bounds__(256) void k_aggr_l1(
    const __half* __restrict__ XLh, const float* __restrict__ as_,
    const float* __restrict__ ad_, const int* __restrict__ rowptr,
    const int* __restrict__ seidx, const int* __restrict__ ovf,
    const int* __restrict__ ovf_cnt, const float* __restrict__ bias,
    __half* __restrict__ OUT, int N) {
  constexpr int C = 128;
  const int lane = threadIdx.x & 63;
  const int wid = threadIdx.x >> 6;
  const int grp = lane >> 5;          // which edge of the broadcast pair
  const int l5 = lane & 31;           // col group: cols 4*l5 .. 4*l5+3
  const int novf = *ovf_cnt;          // 0 in practice
  float bb[4];
#pragma unroll
  for (int j = 0; j < 4; ++j) bb[j] = bias[4 * l5 + j];

  for (int d = blockIdx.x * 4 + wid; d < N; d += gridDim.x * 4) {
    const int beg = rowptr[d], end = rowptr[d + 1];
    const int nb = end - beg;
    const float adst = ad_[d];

    // softmax denominator (max-free: logits bounded)
    float s;
    int sv = 0; float ev = 0.f;
    if (nb <= 64) {
      if (lane < nb) {
        sv = seidx[beg + lane];
        float t = as_[sv] + adst;
        t = t > 0.f ? t : 0.2f * t;
        ev = __expf(t);
      }
      s = ev;
    } else {
      s = 0.f;
      for (int i = beg + lane; i < end; i += 64) {
        int s2 = seidx[i];
        float t = as_[s2] + adst;
        t = t > 0.f ? t : 0.2f * t;
        s += __expf(t);
      }
    }
#pragma unroll
    for (int o = 32; o; o >>= 1) s += __shfl_xor(s, o);

    if (novf > 0) {
      float so = 0.f;
      for (int i = lane; i < novf; i += 64) {
        if (ovf[2 * i] == d) {
          float t = as_[ovf[2 * i + 1]] + adst;
          t = t > 0.f ? t : 0.2f * t;
          so += __expf(t);
        }
      }
#pragma unroll
      for (int o = 32; o; o >>= 1) so += __shfl_xor(so, o);
      s += so;
    }
    const float inv = 1.f / (s + 1e-16f);

    float a0 = 0.f, a1 = 0.f, a2 = 0.f, a3 = 0.f;
    // dual-edge pair body: uniform readlane (SGPR) x2, half-wave cndmask select
    auto pair = [&](int vsrc, float vw, int j, int cnt) {
      const int j0 = 2 * j, j1 = 2 * j + 1;
      const int s0 = bcasti(vsrc, j0);
      const float w0 = bcastf(vw, j0);
      int s1 = s0; float w1 = 0.f;
      if (j1 < cnt) { s1 = bcasti(vsrc, j1); w1 = bcastf(vw, j1); }
      const int sb = grp ? s1 : s0;
      const float wj = grp ? w1 : w0;
      const float2 raw = *(const float2*)(XLh + (size_t)sb * C + l5 * 4);
      float2 x0 = __half22float2(*(const __half2*)&raw.x);
      float2 x1 = __half22float2(*(const __half2*)&raw.y);
      a0 = fmaf(wj, x0.x, a0);
      a1 = fmaf(wj, x0.y, a1);
      a2 = fmaf(wj, x1.x, a2);
      a3 = fmaf(wj, x1.y, a3);
    };

    if (nb <= 64) {
      const float wv = ev * inv;
      const int np = (nb + 1) >> 1;
      int j = 0;
      for (; j + 4 <= np; j += 4) {
        pair(sv, wv, j, nb); pair(sv, wv, j + 1, nb);
        pair(sv, wv, j + 2, nb); pair(sv, wv, j + 3, nb);
      }
      for (; j < np; ++j) pair(sv, wv, j, nb);
    } else {
      for (int i0 = beg; i0 < end; i0 += 64) {
        const int nc = min(64, end - i0);
        int sc = 0; float wc = 0.f;
        if (lane < nc) {
          sc = seidx[i0 + lane];
          float t = as_[sc] + adst;
          t = t > 0.f ? t : 0.2f * t;
          wc = __expf(t) * inv;
        }
        const int np = (nc + 1) >> 1;
        for (int j = 0; j < np; ++j) pair(sc, wc, j, nc);
      }
    }

    // merge the two half-wave edge partials
    a0 += __shfl_xor(a0, 32);
    a1 += __shfl_xor(a1, 32);
    a2 += __shfl_xor(a2, 32);
    a3 += __shfl_xor(a3, 32);

    if (novf > 0) {  // cold overflow adds, post-merge (uniform address)
      for (int i = 0; i < novf; ++i) {
        if (ovf[2 * i] != d) continue;
        int os = ovf[2 * i + 1];
        float t = as_[os] + adst;
        t = t > 0.f ? t : 0.2f * t;
        float wj = __expf(t) * inv;
        const float2 raw = *(const float2*)(XLh + (size_t)os * C + l5 * 4);
        float2 x0 = __half22float2(*(const __half2*)&raw.x);
        float2 x1 = __half22float2(*(const __half2*)&raw.y);
        a0 = fmaf(wj, x0.x, a0);
        a1 = fmaf(wj, x0.y, a1);
        a2 = fmaf(wj, x1.x, a2);
        a3 = fmaf(wj, x1.y, a3);
      }
    }

    if (grp == 0) {
      float o0 = a0 + bb[0], o1 = a1 + bb[1];
      float o2 = a2 + bb[2], o3 = a3 + bb[3];
      o0 = o0 > 0.f ? o0 : 0.01f * o0;   // inter-layer leaky relu
      o1 = o1 > 0.f ? o1 : 0.01f * o1;
      o2 = o2 > 0.f ? o2 : 0.01f * o2;
      o3 = o3 > 0.f ? o3 : 0.01f * o3;
      __half2 p0 = __floats2half2_rn(o0, o1);
      __half2 p1 = __floats2half2_rn(o2, o3);
      uint2 u;
      u.x = *(unsigned*)&p0;
      u.y = *(unsigned*)&p1;
      *(uint2*)(OUT + (size_t)d * C + l5 * 4) = u;
    }
  }
}

// ---- aggr layer 2 (C=64): dual-edge readlane gather + fused column sums ----
__global__ __launch_bounds__(256) void k_aggr2(
    const __half* __restrict__ XLh, const float* __restrict__ as_,
    const float* __restrict__ ad_, const int* __restrict__ rowptr,
    const int* __restrict__ seidx, const int* __restrict__ ovf,
    const int* __restrict__ ovf_cnt, const float* __restrict__ bias,
    float* __restrict__ OUT, float* __restrict__ csum8, int N) {
  constexpr int C = 64;
  const int lane = threadIdx.x & 63;
  const int wid = threadIdx.x >> 6;
  const int grp = lane >> 5;
  const int l5 = lane & 31;           // cols 2*l5, 2*l5+1
  const int novf = *ovf_cnt;
  const float bb0 = bias[2 * l5], bb1 = bias[2 * l5 + 1];
  float cs0 = 0.f, cs1 = 0.f;

  for (int d = blockIdx.x * 4 + wid; d < N; d += gridDim.x * 4) {
    const int beg = rowptr[d], end = rowptr[d + 1];
    const int nb = end - beg;
    const float adst = ad_[d];

    float s;
    int sv = 0; float ev = 0.f;
    if (nb <= 64) {
      if (lane < nb) {
        sv = seidx[beg + lane];
        float t = as_[sv] + adst;
        t = t > 0.f ? t : 0.2f * t;
        ev = __expf(t);
      }
      s = ev;
    } else {
      s = 0.f;
      for (int i = beg + lane; i < end; i += 64) {
        int s2 = seidx[i];
        float t = as_[s2] + adst;
        t = t > 0.f ? t : 0.2f * t;
        s += __expf(t);
      }
    }
#pragma unroll
    for (int o = 32; o; o >>= 1) s += __shfl_xor(s, o);

    if (novf > 0) {
      float so = 0.f;
      for (int i = lane; i < novf; i += 64) {
        if (ovf[2 * i] == d) {
          float t = as_[ovf[2 * i + 1]] + adst;
          t = t > 0.f ? t : 0.2f * t;
          so += __expf(t);
        }
      }
#pragma unroll
      for (int o = 32; o; o >>= 1) so += __shfl_xor(so, o);
      s += so;
    }
    const float inv = 1.f / (s + 1e-16f);

    float a0 = 0.f, a1 = 0.f;
    auto pair = [&](int vsrc, float vw, int j, int cnt) {
      const int j0 = 2 * j, j1 = 2 * j + 1;
      const int s0 = bcasti(vsrc, j0);
      const float w0 = bcastf(vw, j0);
      int s1 = s0; float w1 = 0.f;
      if (j1 < cnt) { s1 = bcasti(vsrc, j1); w1 = bcastf(vw, j1); }
      const int sb = grp ? s1 : s0;
      const float wj = grp ? w1 : w0;
      const __half2 hv = *(const __half2*)(XLh + (size_t)sb * C + l5 * 2);
      float2 xv = __half22float2(hv);
      a0 = fmaf(wj, xv.x, a0);
      a1 = fmaf(wj, xv.y, a1);
    };

    if (nb <= 64) {
      const float wv = ev * inv;
      const int np = (nb + 1) >> 1;
      int j = 0;
      for (; j + 4 <= np; j += 4) {
        pair(sv, wv, j, nb); pair(sv, wv, j + 1, nb);
        pair(sv, wv, j + 2, nb); pair(sv, wv, j + 3, nb);
      }
      for (; j < np; ++j) pair(sv, wv, j, nb);
    } else {
      for (int i0 = beg; i0 < end; i0 += 64) {
        const int nc = min(64, end - i0);
        int sc = 0; float wc = 0.f;
        if (lane < nc) {
          sc = seidx[i0 + lane];
          float t = as_[sc] + adst;
          t = t > 0.f ? t : 0.2f * t;
          wc = __expf(t) * inv;
        }
        const int np = (nc + 1) >> 1;
        for (int j = 0; j < np; ++j) pair(sc, wc, j, nc);
      }
    }

    a0 += __shfl_xor(a0, 32);
    a1 += __shfl_xor(a1, 32);

    if (novf > 0) {
      for (int i = 0; i < novf; ++i) {
        if (ovf[2 * i] != d) continue;
        int os = ovf[2 * i + 1];
        float t = as_[os] + adst;
        t = t > 0.f ? t : 0.2f * t;
        float wj = __expf(t) * inv;
        const __half2 hv = *(const __half2*)(XLh + (size_t)os * C + l5 * 2);
        float2 xv = __half22float2(hv);
        a0 = fmaf(wj, xv.x, a0);
        a1 = fmaf(wj, xv.y, a1);
      }
    }

    if (grp == 0) {
      float o0 = a0 + bb0;
      float o1 = a1 + bb1;
      *(float2*)&OUT[(size_t)d * C + 2 * l5] = make_float2(o0, o1);
      cs0 += __expf(o0);
      cs1 += __expf(o1);
    }
  }

  // block-level reduce of fused column sums -> one atomic per col per block
  __shared__ float csA[4][64];
  if (grp == 0) { csA[wid][2 * l5] = cs0; csA[wid][2 * l5 + 1] = cs1; }
  __syncthreads();
  if (threadIdx.x < 64) {
    float tot = csA[0][threadIdx.x] + csA[1][threadIdx.x] +
                csA[2][threadIdx.x] + csA[3][threadIdx.x];
    if (tot != 0.f)
      atomicAdd(&csum8[((int)blockIdx.x & 7) * 64 + (int)threadIdx.x], tot);
  }
}

// ---------------- normalize: OUT = exp(OUT)/colsum ----------------
__global__ void k_norm(float* __restrict__ O, const float* __restrict__ csum8,
                       size_t tot4) {
  __shared__ float cs[64];
  if (threadIdx.x < 64) {
    float s = 0.f;
#pragma unroll
    for (int r = 0; r < 8; ++r) s += csum8[r * 64 + (int)threadIdx.x];
    cs[threadIdx.x] = s;
  }
  __syncthreads();
  for (size_t i = blockIdx.x * (size_t)blockDim.x + threadIdx.x; i < tot4;
       i += (size_t)gridDim.x * blockDim.x) {
    float4 v = ((float4*)O)[i];
    int c0 = (int)((i * 4) & 63);
    v.x = __expf(v.x) / cs[c0];
    v.y = __expf(v.y) / cs[c0 + 1];
    v.z = __expf(v.z) / cs[c0 + 2];
    v.w = __expf(v.w) / cs[c0 + 3];
    ((float4*)O)[i] = v;
  }
}

// ---------------------------------------------------------------------------
extern "C" void kernel_launch(void* const* d_in, const int* in_sizes, int n_in,
                              void* d_out, int out_size, void* d_ws, size_t ws_size,
                              hipStream_t stream) {
  const float* x   = (const float*)d_in[0];
  const int*   ei  = (const int*)d_in[1];
  const float* W1  = (const float*)d_in[2];
  const float* as1 = (const float*)d_in[3];
  const float* ad1 = (const float*)d_in[4];
  const float* b1  = (const float*)d_in[5];
  const float* W2  = (const float*)d_in[6];
  const float* as2 = (const float*)d_in[7];
  const float* ad2 = (const float*)d_in[8];
  const float* b2  = (const float*)d_in[9];
  float* out = (float*)d_out;

  const int N = in_sizes[0] / 128;
  const int E = in_sizes[1] / 2;
  const int Etot = E + N;
  const int* srcA = ei;
  const int* dstA = ei + E;
  const int DPP = (N + NPARTS - 1) / NPARTS;          // 391
  const int nparts = (N + DPP - 1) / DPP;             // 256

  char* w = (char*)d_ws;
  auto take = [&](size_t bytes) -> void* {
    void* p = (void*)w;
    w += (bytes + 255) & ~(size_t)255;
    return p;
  };
  __half*    xlh   = (__half*)take((size_t)N * 128 * 2);  // layer-1 XL (fp16)
  __half*    xl2h  = (__half*)take((size_t)N * 64 * 2);   // layer-2 XL (fp16)
  __half*    h     = (__half*)take((size_t)N * 128 * 2);  // layer-1 out (fp16)
  float*     a_s   = (float*)take((size_t)N * 4);
  float*     a_d   = (float*)take((size_t)N * 4);
  int*       zeroB = (int*)take((size_t)(1 + NPARTS + 512) * 4); // ovf_cnt|pcur|csum8
  int*       ovf_cnt = zeroB;
  int*       pcur    = zeroB + 1;
  float*     csum8   = (float*)(zeroB + 1 + NPARTS);
  int*       rowptr = (int*)take((size_t)(N + 1) * 4);
  int*       seidx  = (int*)take((size_t)Etot * 4);
  int*       ovf    = (int*)take((size_t)Etot * 2 * 4);
  uint2*     parts  = (uint2*)take((size_t)NPARTS * PCAP * 8);
  _Float16*  wf1    = (_Float16*)take((size_t)8 * 4 * 64 * 8 * 2);
  _Float16*  wf2    = (_Float16*)take((size_t)4 * 4 * 64 * 8 * 2);

  hipMemsetAsync(zeroB, 0, (size_t)(1 + NPARTS + 512) * 4, stream);

  const int nch = (Etot + CHUNK - 1) / CHUNK;
  const int gb = (N + 63) / 64;

  k_build1<<<nch + 8, 256, 0, stream>>>(srcA, dstA, pcur, parts, ovf, ovf_cnt,
                                        W1, W2, wf1, wf2, E, N, DPP, nch, Etot);
  k_gemm1_place<<<gb + NPARTS, 256, 0, stream>>>(
      x, wf1, as1, ad1, xlh, a_s, a_d, N, parts, pcur, rowptr, seidx,
      DPP, nparts, gb);
  k_aggr_l1<<<8192, 256, 0, stream>>>(xlh, a_s, a_d, rowptr, seidx, ovf, ovf_cnt,
                                      b1, h, N);
  k_gemm_l2<<<gb, 256, 0, stream>>>(h, wf2, as2, ad2, xl2h, a_s, a_d, N);
  k_aggr2<<<8192, 256, 0, stream>>>(xl2h, a_s, a_d, rowptr, seidx, ovf, ovf_cnt,
                                    b2, out, csum8, N);
  const size_t tot4 = (size_t)N * 64 / 4;
  k_norm<<<2048, 256, 0, stream>>>(out, csum8, tot4);
}

// Round 13
// 221.961 us; speedup vs baseline: 1.8895x; 1.0151x over previous
//
#include <hip/hip_runtime.h>
#include <hip/hip_fp16.h>
#include <math.h>

// ---------------------------------------------------------------------------
// GAT 2-layer network. MFMA fp16 GEMMs (fp32 accum); fp16 gathered features;
// max-free edge softmax; CSR via binned counting-sort. Dual-edge gathers with
// pk_fma_f16 accumulation and 32-bit voffset addressing.
// N=100000, E=1600000 (+N self-loops), d_in=h1=128, h2=64.
// ---------------------------------------------------------------------------

constexpr int NPARTS = 256;   // fixed-width dst partitions
constexpr int PCAP = 8192;    // entries per partition (avg 6640, +19 sigma)
constexpr int CHUNK = 4096;   // edges per phase-A block-chunk
constexpr int DPPMAX = 400;   // max dsts per partition

typedef _Float16 f16x8 __attribute__((ext_vector_type(8)));
typedef float f32x4 __attribute__((ext_vector_type(4)));

__device__ __forceinline__ int bcasti(int v, int j) {
  return __builtin_amdgcn_readlane(v, j);
}
__device__ __forceinline__ float bcastf(float v, int j) {
  return __uint_as_float((unsigned)__builtin_amdgcn_readlane((int)__float_as_uint(v), j));
}
__device__ __forceinline__ __half2 xor32h(__half2 v) {
  int i = *(int*)&v;
  i = __shfl_xor(i, 32);
  return *(__half2*)&i;
}

// ---------------- K1: edge binning (blocks < nch) || W-prep (last 8) --------
__global__ __launch_bounds__(256) void k_build1(
    const int* __restrict__ srcA, const int* __restrict__ dstA,
    int* __restrict__ pcur, uint2* __restrict__ parts,
    int* __restrict__ ovf, int* __restrict__ ovf_cnt,
    const float* __restrict__ W1, const float* __restrict__ W2,
    _Float16* __restrict__ Wf1, _Float16* __restrict__ Wf2,
    int E, int N, int DPP, int nch, int ovfcap) {
  if ((int)blockIdx.x >= nch) {
    int t = ((int)blockIdx.x - nch) * 256 + (int)threadIdx.x;
    const int stride = 8 * 256;
    for (int i = t; i < 8 * 4 * 64 * 8; i += stride) {
      int j = i & 7, l = (i >> 3) & 63, kk = (i >> 9) & 3, cb = i >> 11;
      int k = kk * 32 + (l >> 4) * 8 + j, c = cb * 16 + (l & 15);
      Wf1[i] = (_Float16)W1[k * 128 + c];
    }
    for (int i = t; i < 4 * 4 * 64 * 8; i += stride) {
      int j = i & 7, l = (i >> 3) & 63, kk = (i >> 9) & 3, cb = i >> 11;
      int k = kk * 32 + (l >> 4) * 8 + j, c = cb * 16 + (l & 15);
      Wf2[i] = (_Float16)W2[k * 64 + c];
    }
    return;
  }
  __shared__ int hist[NPARTS];
  __shared__ int base[NPARTS];
  const int tot = E + N;
  const int c = blockIdx.x;
  hist[threadIdx.x] = 0;
  __syncthreads();
  const int beg = c * CHUNK;
  int pp[16], rr[16], ss[16], dd[16];
#pragma unroll
  for (int j = 0; j < 16; ++j) {
    int e = beg + j * 256 + (int)threadIdx.x;
    int d = -1, s = 0;
    if (e < tot) {
      if (e < E) { d = dstA[e]; s = srcA[e]; } else { d = s = e - E; }
    }
    dd[j] = d; ss[j] = s;
    int p = (d >= 0) ? (d / DPP) : -1;
    pp[j] = p;
    rr[j] = (p >= 0) ? atomicAdd(&hist[p], 1) : 0;
  }
  __syncthreads();
  base[threadIdx.x] = atomicAdd(&pcur[threadIdx.x], hist[threadIdx.x]);
  __syncthreads();
#pragma unroll
  for (int j = 0; j < 16; ++j) {
    int p = pp[j];
    if (p < 0) continue;
    int pos = base[p] + rr[j];
    if (pos < PCAP) {
      parts[(size_t)p * PCAP + pos] = make_uint2((unsigned)ss[j], (unsigned)dd[j]);
    } else {
      int o = atomicAdd(ovf_cnt, 1);
      if (o < ovfcap) { ovf[2 * o] = dd[j]; ovf[2 * o + 1] = ss[j]; }
    }
  }
}

// ---------------- MFMA GEMM body (16 rows/wave, K=128) ----------------------
template <int C, typename XT>
__device__ __forceinline__ void gemm_mfma_body(
    const XT* __restrict__ X, const _Float16* __restrict__ Wf,
    const float* __restrict__ atts, const float* __restrict__ attd,
    __half* __restrict__ XLh, float* __restrict__ a_s, float* __restrict__ a_d,
    int N, int bid) {
  constexpr int NCB = C / 16;
  const int lane = threadIdx.x & 63;
  const int wv = threadIdx.x >> 6;
  const int r0 = bid * 64 + wv * 16;
  const int arow = lane & 15;
  const int grp = lane >> 4;
  const int r = r0 + arow;
  const int rsafe = (r < N) ? r : (N - 1);

  float av[NCB], dv[NCB];
#pragma unroll
  for (int cb = 0; cb < NCB; ++cb) {
    av[cb] = atts[cb * 16 + arow];
    dv[cb] = attd[cb * 16 + arow];
  }

  f16x8 af[4];
  if constexpr (sizeof(XT) == 4) {
    const float* xr = (const float*)X + (size_t)rsafe * 128 + grp * 8;
#pragma unroll
    for (int kk = 0; kk < 4; ++kk) {
      float4 u0 = *(const float4*)(xr + kk * 32);
      float4 u1 = *(const float4*)(xr + kk * 32 + 4);
      af[kk][0] = (_Float16)u0.x; af[kk][1] = (_Float16)u0.y;
      af[kk][2] = (_Float16)u0.z; af[kk][3] = (_Float16)u0.w;
      af[kk][4] = (_Float16)u1.x; af[kk][5] = (_Float16)u1.y;
      af[kk][6] = (_Float16)u1.z; af[kk][7] = (_Float16)u1.w;
    }
  } else {
    const __half* xr = (const __half*)X + (size_t)rsafe * 128 + grp * 8;
#pragma unroll
    for (int kk = 0; kk < 4; ++kk)
      af[kk] = *(const f16x8*)(xr + kk * 32);
  }

  float ps[4] = {0.f, 0.f, 0.f, 0.f};
  float pd[4] = {0.f, 0.f, 0.f, 0.f};

#pragma unroll
  for (int cb = 0; cb < NCB; ++cb) {
    f32x4 acc = {0.f, 0.f, 0.f, 0.f};
#pragma unroll
    for (int kk = 0; kk < 4; ++kk) {
      f16x8 bf = *(const f16x8*)(Wf + ((size_t)(cb * 4 + kk) * 64 + lane) * 8);
      acc = __builtin_amdgcn_mfma_f32_16x16x32_f16(af[kk], bf, acc, 0, 0, 0);
    }
    const int ocol = cb * 16 + arow;
#pragma unroll
    for (int i = 0; i < 4; ++i) {
      const int orow = r0 + grp * 4 + i;
      if (orow < N) XLh[(size_t)orow * C + ocol] = (__half)(_Float16)acc[i];
      ps[i] = fmaf(acc[i], av[cb], ps[i]);
      pd[i] = fmaf(acc[i], dv[cb], pd[i]);
    }
  }
#pragma unroll
  for (int m = 1; m < 16; m <<= 1) {
#pragma unroll
    for (int i = 0; i < 4; ++i) {
      ps[i] += __shfl_xor(ps[i], m);
      pd[i] += __shfl_xor(pd[i], m);
    }
  }
  if (arow == 0) {
#pragma unroll
    for (int i = 0; i < 4; ++i) {
      const int orow = r0 + grp * 4 + i;
      if (orow < N) { a_s[orow] = ps[i]; a_d[orow] = pd[i]; }
    }
  }
}

// ---------------- K2: gemm_l1 (blocks < gb) || CSR place+scan (last 256) ----
struct PlaceSmem {
  int sc[NPARTS];
  int l_cnt[DPPMAX];
  int l_off[DPPMAX];
  int l_out[PCAP];
};

__global__ __launch_bounds__(256) void k_gemm1_place(
    const float* __restrict__ X, const _Float16* __restrict__ Wf,
    const float* __restrict__ atts, const float* __restrict__ attd,
    __half* __restrict__ XLh, float* __restrict__ a_s, float* __restrict__ a_d,
    int N, const uint2* __restrict__ parts, const int* __restrict__ pcur,
    int* __restrict__ rowptr, int* __restrict__ seidx,
    int DPP, int nparts, int gb) {
  __shared__ PlaceSmem sm;
  if ((int)blockIdx.x < gb) {
    gemm_mfma_body<128, float>(X, Wf, atts, attd, XLh, a_s, a_d, N, blockIdx.x);
    return;
  }
  const int p = (int)blockIdx.x - gb;
  const int t = threadIdx.x;
  sm.sc[t] = min(pcur[t], PCAP);
  __syncthreads();
  for (int o = 1; o < NPARTS; o <<= 1) {
    int x = (t >= o) ? sm.sc[t - o] : 0;
    __syncthreads();
    sm.sc[t] += x;
    __syncthreads();
  }
  const int base = (p == 0) ? 0 : sm.sc[p - 1];
  const int n = sm.sc[p] - base;
  const int d0 = p * DPP;
  const int ndst = min(DPP, N - d0);
  const uint2* pe = parts + (size_t)p * PCAP;

  for (int i = t; i < ndst; i += 256) sm.l_cnt[i] = 0;
  __syncthreads();
  for (int i = t; i < n; i += 256) {
    uint2 e = pe[i];
    atomicAdd(&sm.l_cnt[(int)e.y - d0], 1);
  }
  __syncthreads();
  if (t == 0) {
    int run = 0;
    for (int i = 0; i < ndst; ++i) { sm.l_off[i] = run; run += sm.l_cnt[i]; }
  }
  __syncthreads();
  for (int i = t; i < ndst; i += 256) {
    rowptr[d0 + i] = base + sm.l_off[i];
    sm.l_cnt[i] = sm.l_off[i];
  }
  if (p == nparts - 1 && t == 0) rowptr[N] = sm.sc[nparts - 1];
  __syncthreads();
  for (int i = t; i < n; i += 256) {
    uint2 e = pe[i];
    int pos = atomicAdd(&sm.l_cnt[(int)e.y - d0], 1);
    sm.l_out[pos] = (int)e.x;
  }
  __syncthreads();
  for (int i = t; i < n; i += 256)
    seidx[base + i] = sm.l_out[i];
}

__global__ __launch_bounds__(256) void k_gemm_l2(
    const __half* __restrict__ X, const _Float16* __restrict__ Wf,
    const float* __restrict__ atts, const float* __restrict__ attd,
    __half* __restrict__ XLh, float* __restrict__ a_s, float* __restrict__ a_d,
    int N) {
  gemm_mfma_body<64, __half>(X, Wf, atts, attd, XLh, a_s, a_d, N, blockIdx.x);
}

// -------- aggr layer 1 (C=128): dual-edge, pk_fma_f16 accum, fp16 h out -----
__global__ __launch_bounds__(256) void k_aggr_l1(
    const __half* __restrict__ XLh, const float* __restrict__ as_,
    const float* __restrict__ ad_, const int* __restrict__ rowptr,
    const int* __restrict__ seidx, const int* __restrict__ ovf,
    const int* __restrict__ ovf_cnt, const float* __restrict__ bias,
    __half* __restrict__ OUT, int N) {
  constexpr int C = 128;
  const int lane = threadIdx.x & 63;
  const int wid = threadIdx.x >> 6;
  const int grp = lane >> 5;          // which edge of the broadcast pair
  const int l5 = lane & 31;           // col group: cols 4*l5 .. 4*l5+3
  const int novf = *ovf_cnt;          // 0 in practice
  float bb[4];
#pragma unroll
  for (int j = 0; j < 4; ++j) bb[j] = bias[4 * l5 + j];

  for (int d = blockIdx.x * 4 + wid; d < N; d += gridDim.x * 4) {
    const int beg = rowptr[d], end = rowptr[d + 1];
    const int nb = end - beg;
    const float adst = ad_[d];

    // softmax denominator (max-free: logits bounded)
    float s;
    int sv = 0; float ev = 0.f;
    if (nb <= 64) {
      if (lane < nb) {
        sv = seidx[beg + lane];
        float t = as_[sv] + adst;
        t = t > 0.f ? t : 0.2f * t;
        ev = __expf(t);
      }
      s = ev;
    } else {
      s = 0.f;
      for (int i = beg + lane; i < end; i += 64) {
        int s2 = seidx[i];
        float t = as_[s2] + adst;
        t = t > 0.f ? t : 0.2f * t;
        s += __expf(t);
      }
    }
#pragma unroll
    for (int o = 32; o; o >>= 1) s += __shfl_xor(s, o);

    if (novf > 0) {
      float so = 0.f;
      for (int i = lane; i < novf; i += 64) {
        if (ovf[2 * i] == d) {
          float t = as_[ovf[2 * i + 1]] + adst;
          t = t > 0.f ? t : 0.2f * t;
          so += __expf(t);
        }
      }
#pragma unroll
      for (int o = 32; o; o >>= 1) so += __shfl_xor(so, o);
      s += so;
    }
    const float inv = 1.f / (s + 1e-16f);

    __half2 ac01 = __floats2half2_rn(0.f, 0.f);
    __half2 ac23 = __floats2half2_rn(0.f, 0.f);
    // dual-edge pair: uniform readlane (SGPR) x2, half-wave cndmask select,
    // 32-bit voffset, packed-fp16 FMA accumulation.
    auto pair = [&](int vsrc, float vw, int j, int cnt) {
      const int j0 = 2 * j, j1 = 2 * j + 1;
      const int s0 = bcasti(vsrc, j0);
      const float w0 = bcastf(vw, j0);
      int s1 = s0; float w1 = 0.f;
      if (j1 < cnt) { s1 = bcasti(vsrc, j1); w1 = bcastf(vw, j1); }
      const int sb = grp ? s1 : s0;
      const float wj = grp ? w1 : w0;
      const unsigned off = ((unsigned)sb << 8) + ((unsigned)l5 << 3);
      const uint2 raw = *(const uint2*)((const char*)XLh + off);
      const __half2 wh = __float2half2_rn(wj);
      ac01 = __hfma2(wh, *(const __half2*)&raw.x, ac01);
      ac23 = __hfma2(wh, *(const __half2*)&raw.y, ac23);
    };

    if (nb <= 64) {
      const float wv = ev * inv;
      const int np = (nb + 1) >> 1;
      int j = 0;
      for (; j + 4 <= np; j += 4) {
        pair(sv, wv, j, nb); pair(sv, wv, j + 1, nb);
        pair(sv, wv, j + 2, nb); pair(sv, wv, j + 3, nb);
      }
      for (; j < np; ++j) pair(sv, wv, j, nb);
    } else {
      for (int i0 = beg; i0 < end; i0 += 64) {
        const int nc = min(64, end - i0);
        int sc = 0; float wc = 0.f;
        if (lane < nc) {
          sc = seidx[i0 + lane];
          float t = as_[sc] + adst;
          t = t > 0.f ? t : 0.2f * t;
          wc = __expf(t) * inv;
        }
        const int np = (nc + 1) >> 1;
        for (int j = 0; j < np; ++j) pair(sc, wc, j, nc);
      }
    }

    // merge the two half-wave edge partials (packed)
    ac01 = __hadd2(ac01, xor32h(ac01));
    ac23 = __hadd2(ac23, xor32h(ac23));
    float2 f01 = __half22float2(ac01);
    float2 f23 = __half22float2(ac23);
    float a0 = f01.x, a1 = f01.y, a2 = f23.x, a3 = f23.y;

    if (novf > 0) {  // cold overflow adds, post-merge, fp32
      for (int i = 0; i < novf; ++i) {
        if (ovf[2 * i] != d) continue;
        int os = ovf[2 * i + 1];
        float t = as_[os] + adst;
        t = t > 0.f ? t : 0.2f * t;
        float wj = __expf(t) * inv;
        const float2 raw = *(const float2*)(XLh + (size_t)os * C + l5 * 4);
        float2 x0 = __half22float2(*(const __half2*)&raw.x);
        float2 x1 = __half22float2(*(const __half2*)&raw.y);
        a0 = fmaf(wj, x0.x, a0);
        a1 = fmaf(wj, x0.y, a1);
        a2 = fmaf(wj, x1.x, a2);
        a3 = fmaf(wj, x1.y, a3);
      }
    }

    if (grp == 0) {
      float o0 = a0 + bb[0], o1 = a1 + bb[1];
      float o2 = a2 + bb[2], o3 = a3 + bb[3];
      o0 = o0 > 0.f ? o0 : 0.01f * o0;   // inter-layer leaky relu
      o1 = o1 > 0.f ? o1 : 0.01f * o1;
      o2 = o2 > 0.f ? o2 : 0.01f * o2;
      o3 = o3 > 0.f ? o3 : 0.01f * o3;
      __half2 p0 = __floats2half2_rn(o0, o1);
      __half2 p1 = __floats2half2_rn(o2, o3);
      uint2 u;
      u.x = *(unsigned*)&p0;
      u.y = *(unsigned*)&p1;
      *(uint2*)(OUT + (size_t)d * C + l5 * 4) = u;
    }
  }
}

// ---- aggr layer 2 (C=64): dual-edge pk_fma gather + fused column sums ------
__global__ __launch_bounds__(256) void k_aggr2(
    const __half* __restrict__ XLh, const float* __restrict__ as_,
    const float* __restrict__ ad_, const int* __restrict__ rowptr,
    const int* __restrict__ seidx, const int* __restrict__ ovf,
    const int* __restrict__ ovf_cnt, const float* __restrict__ bias,
    float* __restrict__ OUT, float* __restrict__ csum8, int N) {
  constexpr int C = 64;
  const int lane = threadIdx.x & 63;
  const int wid = threadIdx.x >> 6;
  const int grp = lane >> 5;
  const int l5 = lane & 31;           // cols 2*l5, 2*l5+1
  const int novf = *ovf_cnt;
  const float bb0 = bias[2 * l5], bb1 = bias[2 * l5 + 1];
  float cs0 = 0.f, cs1 = 0.f;

  for (int d = blockIdx.x * 4 + wid; d < N; d += gridDim.x * 4) {
    const int beg = rowptr[d], end = rowptr[d + 1];
    const int nb = end - beg;
    const float adst = ad_[d];

    float s;
    int sv = 0; float ev = 0.f;
    if (nb <= 64) {
      if (lane < nb) {
        sv = seidx[beg + lane];
        float t = as_[sv] + adst;
        t = t > 0.f ? t : 0.2f * t;
        ev = __expf(t);
      }
      s = ev;
    } else {
      s = 0.f;
      for (int i = beg + lane; i < end; i += 64) {
        int s2 = seidx[i];
        float t = as_[s2] + adst;
        t = t > 0.f ? t : 0.2f * t;
        s += __expf(t);
      }
    }
#pragma unroll
    for (int o = 32; o; o >>= 1) s += __shfl_xor(s, o);

    if (novf > 0) {
      float so = 0.f;
      for (int i = lane; i < novf; i += 64) {
        if (ovf[2 * i] == d) {
          float t = as_[ovf[2 * i + 1]] + adst;
          t = t > 0.f ? t : 0.2f * t;
          so += __expf(t);
        }
      }
#pragma unroll
      for (int o = 32; o; o >>= 1) so += __shfl_xor(so, o);
      s += so;
    }
    const float inv = 1.f / (s + 1e-16f);

    __half2 ac = __floats2half2_rn(0.f, 0.f);
    auto pair = [&](int vsrc, float vw, int j, int cnt) {
      const int j0 = 2 * j, j1 = 2 * j + 1;
      const int s0 = bcasti(vsrc, j0);
      const float w0 = bcastf(vw, j0);
      int s1 = s0; float w1 = 0.f;
      if (j1 < cnt) { s1 = bcasti(vsrc, j1); w1 = bcastf(vw, j1); }
      const int sb = grp ? s1 : s0;
      const float wj = grp ? w1 : w0;
      const unsigned off = ((unsigned)sb << 7) + ((unsigned)l5 << 2);
      const __half2 hv = *(const __half2*)((const char*)XLh + off);
      ac = __hfma2(__float2half2_rn(wj), hv, ac);
    };

    if (nb <= 64) {
      const float wv = ev * inv;
      const int np = (nb + 1) >> 1;
      int j = 0;
      for (; j + 4 <= np; j += 4) {
        pair(sv, wv, j, nb); pair(sv, wv, j + 1, nb);
        pair(sv, wv, j + 2, nb); pair(sv, wv, j + 3, nb);
      }
      for (; j < np; ++j) pair(sv, wv, j, nb);
    } else {
      for (int i0 = beg; i0 < end; i0 += 64) {
        const int nc = min(64, end - i0);
        int sc = 0; float wc = 0.f;
        if (lane < nc) {
          sc = seidx[i0 + lane];
          float t = as_[sc] + adst;
          t = t > 0.f ? t : 0.2f * t;
          wc = __expf(t) * inv;
        }
        const int np = (nc + 1) >> 1;
        for (int j = 0; j < np; ++j) pair(sc, wc, j, nc);
      }
    }

    ac = __hadd2(ac, xor32h(ac));
    float2 fa = __half22float2(ac);
    float a0 = fa.x, a1 = fa.y;

    if (novf > 0) {
      for (int i = 0; i < novf; ++i) {
        if (ovf[2 * i] != d) continue;
        int os = ovf[2 * i + 1];
        float t = as_[os] + adst;
        t = t > 0.f ? t : 0.2f * t;
        float wj = __expf(t) * inv;
        const __half2 hv = *(const __half2*)(XLh + (size_t)os * C + l5 * 2);
        float2 xv = __half22float2(hv);
        a0 = fmaf(wj, xv.x, a0);
        a1 = fmaf(wj, xv.y, a1);
      }
    }

    if (grp == 0) {
      float o0 = a0 + bb0;
      float o1 = a1 + bb1;
      *(float2*)&OUT[(size_t)d * C + 2 * l5] = make_float2(o0, o1);
      cs0 += __expf(o0);
      cs1 += __expf(o1);
    }
  }

  // block-level reduce of fused column sums -> one atomic per col per block
  __shared__ float csA[4][64];
  if (grp == 0) { csA[wid][2 * l5] = cs0; csA[wid][2 * l5 + 1] = cs1; }
  __syncthreads();
  if (threadIdx.x < 64) {
    float tot = csA[0][threadIdx.x] + csA[1][threadIdx.x] +
                csA[2][threadIdx.x] + csA[3][threadIdx.x];
    if (tot != 0.f)
      atomicAdd(&csum8[((int)blockIdx.x & 7) * 64 + (int)threadIdx.x], tot);
  }
}

// ---------------- normalize: OUT = exp(OUT)/colsum ----------------
__global__ void k_norm(float* __restrict__ O, const float* __restrict__ csum8,
                       size_t tot4) {
  __shared__ float cs[64];
  if (threadIdx.x < 64) {
    float s = 0.f;
#pragma unroll
    for (int r = 0; r < 8; ++r) s += csum8[r * 64 + (int)threadIdx.x];
    cs[threadIdx.x] = s;
  }
  __syncthreads();
  for (size_t i = blockIdx.x * (size_t)blockDim.x + threadIdx.x; i < tot4;
       i += (size_t)gridDim.x * blockDim.x) {
    float4 v = ((float4*)O)[i];
    int c0 = (int)((i * 4) & 63);
    v.x = __expf(v.x) / cs[c0];
    v.y = __expf(v.y) / cs[c0 + 1];
    v.z = __expf(v.z) / cs[c0 + 2];
    v.w = __expf(v.w) / cs[c0 + 3];
    ((float4*)O)[i] = v;
  }
}

// ---------------------------------------------------------------------------
extern "C" void kernel_launch(void* const* d_in, const int* in_sizes, int n_in,
                              void* d_out, int out_size, void* d_ws, size_t ws_size,
                              hipStream_t stream) {
  const float* x   = (const float*)d_in[0];
  const int*   ei  = (const int*)d_in[1];
  const float* W1  = (const float*)d_in[2];
  const float* as1 = (const float*)d_in[3];
  const float* ad1 = (const float*)d_in[4];
  const float* b1  = (const float*)d_in[5];
  const float* W2  = (const float*)d_in[6];
  const float* as2 = (const float*)d_in[7];
  const float* ad2 = (const float*)d_in[8];
  const float* b2  = (const float*)d_in[9];
  float* out = (float*)d_out;

  const int N = in_sizes[0] / 128;
  const int E = in_sizes[1] / 2;
  const int Etot = E + N;
  const int* srcA = ei;
  const int* dstA = ei + E;
  const int DPP = (N + NPARTS - 1) / NPARTS;          // 391
  const int nparts = (N + DPP - 1) / DPP;             // 256

  char* w = (char*)d_ws;
  auto take = [&](size_t bytes) -> void* {
    void* p = (void*)w;
    w += (bytes + 255) & ~(size_t)255;
    return p;
  };
  __half*    xlh   = (__half*)take((size_t)N * 128 * 2);  // layer-1 XL (fp16)
  __half*    xl2h  = (__half*)take((size_t)N * 64 * 2);   // layer-2 XL (fp16)
  __half*    h     = (__half*)take((size_t)N * 128 * 2);  // layer-1 out (fp16)
  float*     a_s   = (float*)take((size_t)N * 4);
  float*     a_d   = (float*)take((size_t)N * 4);
  int*       zeroB = (int*)take((size_t)(1 + NPARTS + 512) * 4); // ovf_cnt|pcur|csum8
  int*       ovf_cnt = zeroB;
  int*       pcur    = zeroB + 1;
  float*     csum8   = (float*)(zeroB + 1 + NPARTS);
  int*       rowptr = (int*)take((size_t)(N + 1) * 4);
  int*       seidx  = (int*)take((size_t)Etot * 4);
  int*       ovf    = (int*)take((size_t)Etot * 2 * 4);
  uint2*     parts  = (uint2*)take((size_t)NPARTS * PCAP * 8);
  _Float16*  wf1    = (_Float16*)take((size_t)8 * 4 * 64 * 8 * 2);
  _Float16*  wf2    = (_Float16*)take((size_t)4 * 4 * 64 * 8 * 2);

  hipMemsetAsync(zeroB, 0, (size_t)(1 + NPARTS + 512) * 4, stream);

  const int nch = (Etot + CHUNK - 1) / CHUNK;
  const int gb = (N + 63) / 64;

  k_build1<<<nch + 8, 256, 0, stream>>>(srcA, dstA, pcur, parts, ovf, ovf_cnt,
                                        W1, W2, wf1, wf2, E, N, DPP, nch, Etot);
  k_gemm1_place<<<gb + NPARTS, 256, 0, stream>>>(
      x, wf1, as1, ad1, xlh, a_s, a_d, N, parts, pcur, rowptr, seidx,
      DPP, nparts, gb);
  k_aggr_l1<<<8192, 256, 0, stream>>>(xlh, a_s, a_d, rowptr, seidx, ovf, ovf_cnt,
                                      b1, h, N);
  k_gemm_l2<<<gb, 256, 0, stream>>>(h, wf2, as2, ad2, xl2h, a_s, a_d, N);
  k_aggr2<<<8192, 256, 0, stream>>>(xl2h, a_s, a_d, rowptr, seidx, ovf, ovf_cnt,
                                    b2, out, csum8, N);
  const size_t tot4 = (size_t)N * 64 / 4;
  k_norm<<<2048, 256, 0, stream>>>(out, csum8, tot4);
}

// Round 14
// 218.406 us; speedup vs baseline: 1.9202x; 1.0163x over previous
//
#include <hip/hip_runtime.h>
#include <hip/hip_fp16.h>
#include <math.h>

// ---------------------------------------------------------------------------
// GAT 2-layer network. MFMA fp16 GEMMs (fp32 accum); fp16 gathered features;
// max-free edge softmax; CSR via binned counting-sort (packed uint32 entries:
// dloc<<17|src). Dual-edge (l1) / quad-edge (l2) gathers: uniform readlane
// broadcasts (SGPR), half/quarter-wave cndmask select, pk_fma_f16 accum.
// N=100000, E=1600000 (+N self-loops), d_in=h1=128, h2=64.
// ---------------------------------------------------------------------------

constexpr int NPARTS = 256;   // fixed-width dst partitions
constexpr int PCAP = 8192;    // entries per partition (avg 6640, +19 sigma)
constexpr int CHUNK = 4096;   // edges per phase-A block-chunk
constexpr int DPPMAX = 400;   // max dsts per partition (391) -> dloc < 2^15
constexpr int SRCB = 17;      // src id bits (N=100000 < 2^17)

typedef _Float16 f16x8 __attribute__((ext_vector_type(8)));
typedef float f32x4 __attribute__((ext_vector_type(4)));

__device__ __forceinline__ int bcasti(int v, int j) {
  return __builtin_amdgcn_readlane(v, j);
}
__device__ __forceinline__ float bcastf(float v, int j) {
  return __uint_as_float((unsigned)__builtin_amdgcn_readlane((int)__float_as_uint(v), j));
}
__device__ __forceinline__ __half2 xorh(__half2 v, int m) {
  int i = *(int*)&v;
  i = __shfl_xor(i, m);
  return *(__half2*)&i;
}

// ---------------- K1: edge binning (blocks < nch) || W-prep (last 8) --------
__global__ __launch_bounds__(256) void k_build1(
    const int* __restrict__ srcA, const int* __restrict__ dstA,
    int* __restrict__ pcur, unsigned* __restrict__ parts,
    int* __restrict__ ovf, int* __restrict__ ovf_cnt,
    const float* __restrict__ W1, const float* __restrict__ W2,
    _Float16* __restrict__ Wf1, _Float16* __restrict__ Wf2,
    int E, int N, int DPP, int nch, int ovfcap) {
  if ((int)blockIdx.x >= nch) {
    int t = ((int)blockIdx.x - nch) * 256 + (int)threadIdx.x;
    const int stride = 8 * 256;
    for (int i = t; i < 8 * 4 * 64 * 8; i += stride) {
      int j = i & 7, l = (i >> 3) & 63, kk = (i >> 9) & 3, cb = i >> 11;
      int k = kk * 32 + (l >> 4) * 8 + j, c = cb * 16 + (l & 15);
      Wf1[i] = (_Float16)W1[k * 128 + c];
    }
    for (int i = t; i < 4 * 4 * 64 * 8; i += stride) {
      int j = i & 7, l = (i >> 3) & 63, kk = (i >> 9) & 3, cb = i >> 11;
      int k = kk * 32 + (l >> 4) * 8 + j, c = cb * 16 + (l & 15);
      Wf2[i] = (_Float16)W2[k * 64 + c];
    }
    return;
  }
  __shared__ int hist[NPARTS];
  __shared__ int base[NPARTS];
  const int tot = E + N;
  const int c = blockIdx.x;
  hist[threadIdx.x] = 0;
  __syncthreads();
  const int beg = c * CHUNK;
  int pp[16], rr[16];
  unsigned pk[16];
  int dd[16], ss[16];
#pragma unroll
  for (int j = 0; j < 16; ++j) {
    int e = beg + j * 256 + (int)threadIdx.x;
    int d = -1, s = 0;
    if (e < tot) {
      if (e < E) { d = dstA[e]; s = srcA[e]; } else { d = s = e - E; }
    }
    int p = (d >= 0) ? (d / DPP) : -1;
    pp[j] = p;
    dd[j] = d; ss[j] = s;
    pk[j] = (p >= 0) ? (((unsigned)(d - p * DPP) << SRCB) | (unsigned)s) : 0u;
    rr[j] = (p >= 0) ? atomicAdd(&hist[p], 1) : 0;
  }
  __syncthreads();
  base[threadIdx.x] = atomicAdd(&pcur[threadIdx.x], hist[threadIdx.x]);
  __syncthreads();
#pragma unroll
  for (int j = 0; j < 16; ++j) {
    int p = pp[j];
    if (p < 0) continue;
    int pos = base[p] + rr[j];
    if (pos < PCAP) {
      parts[(size_t)p * PCAP + pos] = pk[j];
    } else {
      int o = atomicAdd(ovf_cnt, 1);
      if (o < ovfcap) { ovf[2 * o] = dd[j]; ovf[2 * o + 1] = ss[j]; }
    }
  }
}

// ---------------- MFMA GEMM body (16 rows/wave, K=128) ----------------------
template <int C, typename XT>
__device__ __forceinline__ void gemm_mfma_body(
    const XT* __restrict__ X, const _Float16* __restrict__ Wf,
    const float* __restrict__ atts, const float* __restrict__ attd,
    __half* __restrict__ XLh, float* __restrict__ a_s, float* __restrict__ a_d,
    int N, int bid) {
  constexpr int NCB = C / 16;
  const int lane = threadIdx.x & 63;
  const int wv = threadIdx.x >> 6;
  const int r0 = bid * 64 + wv * 16;
  const int arow = lane & 15;
  const int grp = lane >> 4;
  const int r = r0 + arow;
  const int rsafe = (r < N) ? r : (N - 1);

  float av[NCB], dv[NCB];
#pragma unroll
  for (int cb = 0; cb < NCB; ++cb) {
    av[cb] = atts[cb * 16 + arow];
    dv[cb] = attd[cb * 16 + arow];
  }

  f16x8 af[4];
  if constexpr (sizeof(XT) == 4) {
    const float* xr = (const float*)X + (size_t)rsafe * 128 + grp * 8;
#pragma unroll
    for (int kk = 0; kk < 4; ++kk) {
      float4 u0 = *(const float4*)(xr + kk * 32);
      float4 u1 = *(const float4*)(xr + kk * 32 + 4);
      af[kk][0] = (_Float16)u0.x; af[kk][1] = (_Float16)u0.y;
      af[kk][2] = (_Float16)u0.z; af[kk][3] = (_Float16)u0.w;
      af[kk][4] = (_Float16)u1.x; af[kk][5] = (_Float16)u1.y;
      af[kk][6] = (_Float16)u1.z; af[kk][7] = (_Float16)u1.w;
    }
  } else {
    const __half* xr = (const __half*)X + (size_t)rsafe * 128 + grp * 8;
#pragma unroll
    for (int kk = 0; kk < 4; ++kk)
      af[kk] = *(const f16x8*)(xr + kk * 32);
  }

  float ps[4] = {0.f, 0.f, 0.f, 0.f};
  float pd[4] = {0.f, 0.f, 0.f, 0.f};

#pragma unroll
  for (int cb = 0; cb < NCB; ++cb) {
    f32x4 acc = {0.f, 0.f, 0.f, 0.f};
#pragma unroll
    for (int kk = 0; kk < 4; ++kk) {
      f16x8 bf = *(const f16x8*)(Wf + ((size_t)(cb * 4 + kk) * 64 + lane) * 8);
      acc = __builtin_amdgcn_mfma_f32_16x16x32_f16(af[kk], bf, acc, 0, 0, 0);
    }
    const int ocol = cb * 16 + arow;
#pragma unroll
    for (int i = 0; i < 4; ++i) {
      const int orow = r0 + grp * 4 + i;
      if (orow < N) XLh[(size_t)orow * C + ocol] = (__half)(_Float16)acc[i];
      ps[i] = fmaf(acc[i], av[cb], ps[i]);
      pd[i] = fmaf(acc[i], dv[cb], pd[i]);
    }
  }
#pragma unroll
  for (int m = 1; m < 16; m <<= 1) {
#pragma unroll
    for (int i = 0; i < 4; ++i) {
      ps[i] += __shfl_xor(ps[i], m);
      pd[i] += __shfl_xor(pd[i], m);
    }
  }
  if (arow == 0) {
#pragma unroll
    for (int i = 0; i < 4; ++i) {
      const int orow = r0 + grp * 4 + i;
      if (orow < N) { a_s[orow] = ps[i]; a_d[orow] = pd[i]; }
    }
  }
}

// ---------------- K2: gemm_l1 (blocks < gb) || CSR place+scan (last 256) ----
struct PlaceSmem {
  int sc[NPARTS];
  int l_cnt[DPPMAX];
  int l_off[DPPMAX];
  int l_out[PCAP];
};

__global__ __launch_bounds__(256) void k_gemm1_place(
    const float* __restrict__ X, const _Float16* __restrict__ Wf,
    const float* __restrict__ atts, const float* __restrict__ attd,
    __half* __restrict__ XLh, float* __restrict__ a_s, float* __restrict__ a_d,
    int N, const unsigned* __restrict__ parts, const int* __restrict__ pcur,
    int* __restrict__ rowptr, int* __restrict__ seidx,
    int DPP, int nparts, int gb) {
  __shared__ PlaceSmem sm;
  if ((int)blockIdx.x < gb) {
    gemm_mfma_body<128, float>(X, Wf, atts, attd, XLh, a_s, a_d, N, blockIdx.x);
    return;
  }
  const int p = (int)blockIdx.x - gb;
  const int t = threadIdx.x;
  sm.sc[t] = min(pcur[t], PCAP);
  __syncthreads();
  for (int o = 1; o < NPARTS; o <<= 1) {
    int x = (t >= o) ? sm.sc[t - o] : 0;
    __syncthreads();
    sm.sc[t] += x;
    __syncthreads();
  }
  const int base = (p == 0) ? 0 : sm.sc[p - 1];
  const int n = sm.sc[p] - base;
  const int d0 = p * DPP;
  const int ndst = min(DPP, N - d0);
  const unsigned* pe = parts + (size_t)p * PCAP;

  for (int i = t; i < ndst; i += 256) sm.l_cnt[i] = 0;
  __syncthreads();
  for (int i = t; i < n; i += 256) {
    unsigned e = pe[i];
    atomicAdd(&sm.l_cnt[e >> SRCB], 1);
  }
  __syncthreads();
  if (t == 0) {
    int run = 0;
    for (int i = 0; i < ndst; ++i) { sm.l_off[i] = run; run += sm.l_cnt[i]; }
  }
  __syncthreads();
  for (int i = t; i < ndst; i += 256) {
    rowptr[d0 + i] = base + sm.l_off[i];
    sm.l_cnt[i] = sm.l_off[i];
  }
  if (p == nparts - 1 && t == 0) rowptr[N] = sm.sc[nparts - 1];
  __syncthreads();
  for (int i = t; i < n; i += 256) {
    unsigned e = pe[i];
    int pos = atomicAdd(&sm.l_cnt[e >> SRCB], 1);
    sm.l_out[pos] = (int)(e & ((1u << SRCB) - 1u));
  }
  __syncthreads();
  for (int i = t; i < n; i += 256)
    seidx[base + i] = sm.l_out[i];
}

__global__ __launch_bounds__(256) void k_gemm_l2(
    const __half* __restrict__ X, const _Float16* __restrict__ Wf,
    const float* __restrict__ atts, const float* __restrict__ attd,
    __half* __restrict__ XLh, float* __restrict__ a_s, float* __restrict__ a_d,
    int N) {
  gemm_mfma_body<64, __half>(X, Wf, atts, attd, XLh, a_s, a_d, N, blockIdx.x);
}

// -------- aggr layer 1 (C=128): dual-edge, pk_fma_f16 accum, fp16 h out -----
__global__ __launch_bounds__(256) void k_aggr_l1(
    const __half* __restrict__ XLh, const float* __restrict__ as_,
    const float* __restrict__ ad_, const int* __restrict__ rowptr,
    const int* __restrict__ seidx, const int* __restrict__ ovf,
    const int* __restrict__ ovf_cnt, const float* __restrict__ bias,
    __half* __restrict__ OUT, int N) {
  constexpr int C = 128;
  const int lane = threadIdx.x & 63;
  const int wid = threadIdx.x >> 6;
  const int grp = lane >> 5;          // which edge of the broadcast pair
  const int l5 = lane & 31;           // col group: cols 4*l5 .. 4*l5+3
  const int novf = *ovf_cnt;          // 0 in practice
  float bb[4];
#pragma unroll
  for (int j = 0; j < 4; ++j) bb[j] = bias[4 * l5 + j];

  for (int d = blockIdx.x * 4 + wid; d < N; d += gridDim.x * 4) {
    const int beg = rowptr[d], end = rowptr[d + 1];
    const int nb = end - beg;
    const float adst = ad_[d];

    // softmax denominator (max-free: logits bounded)
    float s;
    int sv = 0; float ev = 0.f;
    if (nb <= 64) {
      if (lane < nb) {
        sv = seidx[beg + lane];
        float t = as_[sv] + adst;
        t = t > 0.f ? t : 0.2f * t;
        ev = __expf(t);
      }
      s = ev;
    } else {
      s = 0.f;
      for (int i = beg + lane; i < end; i += 64) {
        int s2 = seidx[i];
        float t = as_[s2] + adst;
        t = t > 0.f ? t : 0.2f * t;
        s += __expf(t);
      }
    }
#pragma unroll
    for (int o = 32; o; o >>= 1) s += __shfl_xor(s, o);

    if (novf > 0) {
      float so = 0.f;
      for (int i = lane; i < novf; i += 64) {
        if (ovf[2 * i] == d) {
          float t = as_[ovf[2 * i + 1]] + adst;
          t = t > 0.f ? t : 0.2f * t;
          so += __expf(t);
        }
      }
#pragma unroll
      for (int o = 32; o; o >>= 1) so += __shfl_xor(so, o);
      s += so;
    }
    const float inv = 1.f / (s + 1e-16f);

    __half2 ac01 = __floats2half2_rn(0.f, 0.f);
    __half2 ac23 = __floats2half2_rn(0.f, 0.f);
    auto pair = [&](int vsrc, float vw, int j, int cnt) {
      const int j0 = 2 * j, j1 = 2 * j + 1;
      const int s0 = bcasti(vsrc, j0);
      const float w0 = bcastf(vw, j0);
      int s1 = s0; float w1 = 0.f;
      if (j1 < cnt) { s1 = bcasti(vsrc, j1); w1 = bcastf(vw, j1); }
      const int sb = grp ? s1 : s0;
      const float wj = grp ? w1 : w0;
      const unsigned off = ((unsigned)sb << 8) + ((unsigned)l5 << 3);
      const uint2 raw = *(const uint2*)((const char*)XLh + off);
      const __half2 wh = __float2half2_rn(wj);
      ac01 = __hfma2(wh, *(const __half2*)&raw.x, ac01);
      ac23 = __hfma2(wh, *(const __half2*)&raw.y, ac23);
    };

    if (nb <= 64) {
      const float wv = ev * inv;
      const int np = (nb + 1) >> 1;
      int j = 0;
      for (; j + 4 <= np; j += 4) {
        pair(sv, wv, j, nb); pair(sv, wv, j + 1, nb);
        pair(sv, wv, j + 2, nb); pair(sv, wv, j + 3, nb);
      }
      for (; j < np; ++j) pair(sv, wv, j, nb);
    } else {
      for (int i0 = beg; i0 < end; i0 += 64) {
        const int nc = min(64, end - i0);
        int sc = 0; float wc = 0.f;
        if (lane < nc) {
          sc = seidx[i0 + lane];
          float t = as_[sc] + adst;
          t = t > 0.f ? t : 0.2f * t;
          wc = __expf(t) * inv;
        }
        const int np = (nc + 1) >> 1;
        for (int j = 0; j < np; ++j) pair(sc, wc, j, nc);
      }
    }

    // merge the two half-wave edge partials (packed)
    ac01 = __hadd2(ac01, xorh(ac01, 32));
    ac23 = __hadd2(ac23, xorh(ac23, 32));
    float2 f01 = __half22float2(ac01);
    float2 f23 = __half22float2(ac23);
    float a0 = f01.x, a1 = f01.y, a2 = f23.x, a3 = f23.y;

    if (novf > 0) {  // cold overflow adds, post-merge, fp32
      for (int i = 0; i < novf; ++i) {
        if (ovf[2 * i] != d) continue;
        int os = ovf[2 * i + 1];
        float t = as_[os] + adst;
        t = t > 0.f ? t : 0.2f * t;
        float wj = __expf(t) * inv;
        const float2 raw = *(const float2*)(XLh + (size_t)os * C + l5 * 4);
        float2 x0 = __half22float2(*(const __half2*)&raw.x);
        float2 x1 = __half22float2(*(const __half2*)&raw.y);
        a0 = fmaf(wj, x0.x, a0);
        a1 = fmaf(wj, x0.y, a1);
        a2 = fmaf(wj, x1.x, a2);
        a3 = fmaf(wj, x1.y, a3);
      }
    }

    if (grp == 0) {
      float o0 = a0 + bb[0], o1 = a1 + bb[1];
      float o2 = a2 + bb[2], o3 = a3 + bb[3];
      o0 = o0 > 0.f ? o0 : 0.01f * o0;   // inter-layer leaky relu
      o1 = o1 > 0.f ? o1 : 0.01f * o1;
      o2 = o2 > 0.f ? o2 : 0.01f * o2;
      o3 = o3 > 0.f ? o3 : 0.01f * o3;
      __half2 p0 = __floats2half2_rn(o0, o1);
      __half2 p1 = __floats2half2_rn(o2, o3);
      uint2 u;
      u.x = *(unsigned*)&p0;
      u.y = *(unsigned*)&p1;
      *(uint2*)(OUT + (size_t)d * C + l5 * 4) = u;
    }
  }
}

// ---- aggr layer 2 (C=64): quad-edge pk_fma gather + fused column sums ------
__global__ __launch_bounds__(256) void k_aggr2(
    const __half* __restrict__ XLh, const float* __restrict__ as_,
    const float* __restrict__ ad_, const int* __restrict__ rowptr,
    const int* __restrict__ seidx, const int* __restrict__ ovf,
    const int* __restrict__ ovf_cnt, const float* __restrict__ bias,
    float* __restrict__ OUT, float* __restrict__ csum8, int N) {
  constexpr int C = 64;
  const int lane = threadIdx.x & 63;
  const int wid = threadIdx.x >> 6;
  const int q = lane >> 4;            // quarter-wave: which edge of the quad
  const int li = lane & 15;           // cols 4*li .. 4*li+3
  const int novf = *ovf_cnt;
  float bb[4];
#pragma unroll
  for (int j = 0; j < 4; ++j) bb[j] = bias[4 * li + j];
  float cs0 = 0.f, cs1 = 0.f, cs2 = 0.f, cs3 = 0.f;

  for (int d = blockIdx.x * 4 + wid; d < N; d += gridDim.x * 4) {
    const int beg = rowptr[d], end = rowptr[d + 1];
    const int nb = end - beg;
    const float adst = ad_[d];

    float s;
    int sv = 0; float ev = 0.f;
    if (nb <= 64) {
      if (lane < nb) {
        sv = seidx[beg + lane];
        float t = as_[sv] + adst;
        t = t > 0.f ? t : 0.2f * t;
        ev = __expf(t);
      }
      s = ev;
    } else {
      s = 0.f;
      for (int i = beg + lane; i < end; i += 64) {
        int s2 = seidx[i];
        float t = as_[s2] + adst;
        t = t > 0.f ? t : 0.2f * t;
        s += __expf(t);
      }
    }
#pragma unroll
    for (int o = 32; o; o >>= 1) s += __shfl_xor(s, o);

    if (novf > 0) {
      float so = 0.f;
      for (int i = lane; i < novf; i += 64) {
        if (ovf[2 * i] == d) {
          float t = as_[ovf[2 * i + 1]] + adst;
          t = t > 0.f ? t : 0.2f * t;
          so += __expf(t);
        }
      }
#pragma unroll
      for (int o = 32; o; o >>= 1) so += __shfl_xor(so, o);
      s += so;
    }
    const float inv = 1.f / (s + 1e-16f);

    __half2 ac01 = __floats2half2_rn(0.f, 0.f);
    __half2 ac23 = __floats2half2_rn(0.f, 0.f);
    // quad-edge: 4 uniform readlane pairs, 2-level cndmask select by quarter
    auto quad = [&](int vsrc, float vw, int j, int cnt) {
      const int j0 = 4 * j;
      const int s0 = bcasti(vsrc, j0);
      const float w0 = bcastf(vw, j0);
      int s1 = s0, s2 = s0, s3 = s0;
      float w1 = 0.f, w2 = 0.f, w3 = 0.f;
      if (j0 + 1 < cnt) { s1 = bcasti(vsrc, j0 + 1); w1 = bcastf(vw, j0 + 1); }
      if (j0 + 2 < cnt) { s2 = bcasti(vsrc, j0 + 2); w2 = bcastf(vw, j0 + 2); }
      if (j0 + 3 < cnt) { s3 = bcasti(vsrc, j0 + 3); w3 = bcastf(vw, j0 + 3); }
      const int sA = (q & 1) ? s1 : s0;
      const int sB = (q & 1) ? s3 : s2;
      const int sb = (q & 2) ? sB : sA;
      const float wA = (q & 1) ? w1 : w0;
      const float wB = (q & 1) ? w3 : w2;
      const float wj = (q & 2) ? wB : wA;
      const unsigned off = ((unsigned)sb << 7) + ((unsigned)li << 3);
      const uint2 raw = *(const uint2*)((const char*)XLh + off);
      const __half2 wh = __float2half2_rn(wj);
      ac01 = __hfma2(wh, *(const __half2*)&raw.x, ac01);
      ac23 = __hfma2(wh, *(const __half2*)&raw.y, ac23);
    };

    if (nb <= 64) {
      const float wv = ev * inv;
      const int np = (nb + 3) >> 2;
      int j = 0;
      for (; j + 4 <= np; j += 4) {
        quad(sv, wv, j, nb); quad(sv, wv, j + 1, nb);
        quad(sv, wv, j + 2, nb); quad(sv, wv, j + 3, nb);
      }
      for (; j < np; ++j) quad(sv, wv, j, nb);
    } else {
      for (int i0 = beg; i0 < end; i0 += 64) {
        const int nc = min(64, end - i0);
        int sc = 0; float wc = 0.f;
        if (lane < nc) {
          sc = seidx[i0 + lane];
          float t = as_[sc] + adst;
          t = t > 0.f ? t : 0.2f * t;
          wc = __expf(t) * inv;
        }
        const int np = (nc + 3) >> 2;
        for (int j = 0; j < np; ++j) quad(sc, wc, j, nc);
      }
    }

    // merge the four quarter-wave edge partials (packed)
    ac01 = __hadd2(ac01, xorh(ac01, 16));
    ac01 = __hadd2(ac01, xorh(ac01, 32));
    ac23 = __hadd2(ac23, xorh(ac23, 16));
    ac23 = __hadd2(ac23, xorh(ac23, 32));
    float2 f01 = __half22float2(ac01);
    float2 f23 = __half22float2(ac23);
    float a0 = f01.x, a1 = f01.y, a2 = f23.x, a3 = f23.y;

    if (novf > 0) {
      for (int i = 0; i < novf; ++i) {
        if (ovf[2 * i] != d) continue;
        int os = ovf[2 * i + 1];
        float t = as_[os] + adst;
        t = t > 0.f ? t : 0.2f * t;
        float wj = __expf(t) * inv;
        const float2 raw = *(const float2*)(XLh + (size_t)os * C + li * 4);
        float2 x0 = __half22float2(*(const __half2*)&raw.x);
        float2 x1 = __half22float2(*(const __half2*)&raw.y);
        a0 = fmaf(wj, x0.x, a0);
        a1 = fmaf(wj, x0.y, a1);
        a2 = fmaf(wj, x1.x, a2);
        a3 = fmaf(wj, x1.y, a3);
      }
    }

    if (q == 0) {
      float o0 = a0 + bb[0], o1 = a1 + bb[1];
      float o2 = a2 + bb[2], o3 = a3 + bb[3];
      float4 ov = make_float4(o0, o1, o2, o3);
      *(float4*)&OUT[(size_t)d * C + 4 * li] = ov;
      cs0 += __expf(o0);
      cs1 += __expf(o1);
      cs2 += __expf(o2);
      cs3 += __expf(o3);
    }
  }

  // block-level reduce of fused column sums -> one atomic per col per block
  __shared__ float csA[4][64];
  if (q == 0) {
    csA[wid][4 * li + 0] = cs0;
    csA[wid][4 * li + 1] = cs1;
    csA[wid][4 * li + 2] = cs2;
    csA[wid][4 * li + 3] = cs3;
  }
  __syncthreads();
  if (threadIdx.x < 64) {
    float tot = csA[0][threadIdx.x] + csA[1][threadIdx.x] +
                csA[2][threadIdx.x] + csA[3][threadIdx.x];
    if (tot != 0.f)
      atomicAdd(&csum8[((int)blockIdx.x & 7) * 64 + (int)threadIdx.x], tot);
  }
}

// ---------------- normalize: OUT = exp(OUT)/colsum ----------------
__global__ void k_norm(float* __restrict__ O, const float* __restrict__ csum8,
                       size_t tot4) {
  __shared__ float cs[64];
  if (threadIdx.x < 64) {
    float s = 0.f;
#pragma unroll
    for (int r = 0; r < 8; ++r) s += csum8[r * 64 + (int)threadIdx.x];
    cs[threadIdx.x] = s;
  }
  __syncthreads();
  for (size_t i = blockIdx.x * (size_t)blockDim.x + threadIdx.x; i < tot4;
       i += (size_t)gridDim.x * blockDim.x) {
    float4 v = ((float4*)O)[i];
    int c0 = (int)((i * 4) & 63);
    v.x = __expf(v.x) / cs[c0];
    v.y = __expf(v.y) / cs[c0 + 1];
    v.z = __expf(v.z) / cs[c0 + 2];
    v.w = __expf(v.w) / cs[c0 + 3];
    ((float4*)O)[i] = v;
  }
}

// ---------------------------------------------------------------------------
extern "C" void kernel_launch(void* const* d_in, const int* in_sizes, int n_in,
                              void* d_out, int out_size, void* d_ws, size_t ws_size,
                              hipStream_t stream) {
  const float* x   = (const float*)d_in[0];
  const int*   ei  = (const int*)d_in[1];
  const float* W1  = (const float*)d_in[2];
  const float* as1 = (const float*)d_in[3];
  const float* ad1 = (const float*)d_in[4];
  const float* b1  = (const float*)d_in[5];
  const float* W2  = (const float*)d_in[6];
  const float* as2 = (const float*)d_in[7];
  const float* ad2 = (const float*)d_in[8];
  const float* b2  = (const float*)d_in[9];
  float* out = (float*)d_out;

  const int N = in_sizes[0] / 128;
  const int E = in_sizes[1] / 2;
  const int Etot = E + N;
  const int* srcA = ei;
  const int* dstA = ei + E;
  const int DPP = (N + NPARTS - 1) / NPARTS;          // 391
  const int nparts = (N + DPP - 1) / DPP;             // 256

  char* w = (char*)d_ws;
  auto take = [&](size_t bytes) -> void* {
    void* p = (void*)w;
    w += (bytes + 255) & ~(size_t)255;
    return p;
  };
  __half*    xlh   = (__half*)take((size_t)N * 128 * 2);  // layer-1 XL (fp16)
  __half*    xl2h  = (__half*)take((size_t)N * 64 * 2);   // layer-2 XL (fp16)
  __half*    h     = (__half*)take((size_t)N * 128 * 2);  // layer-1 out (fp16)
  float*     a_s   = (float*)take((size_t)N * 4);
  float*     a_d   = (float*)take((size_t)N * 4);
  int*       zeroB = (int*)take((size_t)(1 + NPARTS + 512) * 4); // ovf_cnt|pcur|csum8
  int*       ovf_cnt = zeroB;
  int*       pcur    = zeroB + 1;
  float*     csum8   = (float*)(zeroB + 1 + NPARTS);
  int*       rowptr = (int*)take((size_t)(N + 1) * 4);
  int*       seidx  = (int*)take((size_t)Etot * 4);
  int*       ovf    = (int*)take((size_t)Etot * 2 * 4);
  unsigned*  parts  = (unsigned*)take((size_t)NPARTS * PCAP * 4);
  _Float16*  wf1    = (_Float16*)take((size_t)8 * 4 * 64 * 8 * 2);
  _Float16*  wf2    = (_Float16*)take((size_t)4 * 4 * 64 * 8 * 2);

  hipMemsetAsync(zeroB, 0, (size_t)(1 + NPARTS + 512) * 4, stream);

  const int nch = (Etot + CHUNK - 1) / CHUNK;
  const int gb = (N + 63) / 64;

  k_build1<<<nch + 8, 256, 0, stream>>>(srcA, dstA, pcur, parts, ovf, ovf_cnt,
                                        W1, W2, wf1, wf2, E, N, DPP, nch, Etot);
  k_gemm1_place<<<gb + NPARTS, 256, 0, stream>>>(
      x, wf1, as1, ad1, xlh, a_s, a_d, N, parts, pcur, rowptr, seidx,
      DPP, nparts, gb);
  k_aggr_l1<<<8192, 256, 0, stream>>>(xlh, a_s, a_d, rowptr, seidx, ovf, ovf_cnt,
                                      b1, h, N);
  k_gemm_l2<<<gb, 256, 0, stream>>>(h, wf2, as2, ad2, xl2h, a_s, a_d, N);
  k_aggr2<<<8192, 256, 0, stream>>>(xl2h, a_s, a_d, rowptr, seidx, ovf, ovf_cnt,
                                    b2, out, csum8, N);
  const size_t tot4 = (size_t)N * 64 / 4;
  k_norm<<<2048, 256, 0, stream>>>(out, csum8, tot4);
}